// Round 1
// baseline (11384.792 us; speedup 1.0000x reference)
//
#include <hip/hip_runtime.h>
#include <math.h>

#define BB 4

// ---------------- elementwise: xnow = x2*m + x*(1-m) ----------------
__global__ void k_xnow(const float* __restrict__ x, const float* __restrict__ x2,
                       const float* __restrict__ mask, float* __restrict__ xnow) {
  int idx = blockIdx.x * 256 + threadIdx.x;
  if (idx >= BB * 3 * 65536) return;
  int b = idx / (3 * 65536);
  int r = idx % 65536;
  float m = mask[b * 65536 + r];
  xnow[idx] = x2[idx] * m + x[idx] * (1.f - m);
}

// ---------------- generic direct conv (gated / plain+tanh) ----------------
// act: 0 = gated ELU, 1 = gated ReLU, 2 = plain + tanh
__global__ void conv_gated(const float* __restrict__ in1, const float* __restrict__ in2,
                           int c1, int c2,
                           const float* __restrict__ w, const float* __restrict__ bias,
                           float* __restrict__ out,
                           int Hin, int Win, int Hout, int Wout,
                           int K, int stride, int upsample, int coutTotal, int act) {
  extern __shared__ float sw[];
  int cin = c1 + c2;
  int n = cin * K * K;
  int gated = (act < 2);
  int coutEff = gated ? (coutTotal >> 1) : coutTotal;
  int co = blockIdx.y, b = blockIdx.z;
  for (int i = threadIdx.x; i < n; i += blockDim.x) sw[i] = w[(size_t)co * n + i];
  if (gated)
    for (int i = threadIdx.x; i < n; i += blockDim.x) sw[n + i] = w[(size_t)(co + coutEff) * n + i];
  __syncthreads();
  int p = blockIdx.x * blockDim.x + threadIdx.x;
  if (p >= Hout * Wout) return;
  int y = p / Wout, x = p % Wout;
  int pad = (K - 1) >> 1;
  int HinU = upsample ? (Hin << 1) : Hin;
  int WinU = upsample ? (Win << 1) : Win;
  float accA = 0.f, accG = 0.f;
  for (int ci = 0; ci < cin; ci++) {
    const float* src = (ci < c1) ? (in1 + (size_t)(b * c1 + ci) * Hin * Win)
                                 : (in2 + (size_t)(b * c2 + (ci - c1)) * Hin * Win);
    int wbase = ci * K * K;
    for (int kh = 0; kh < K; kh++) {
      int iy = y * stride + kh - pad;
      if (iy < 0 || iy >= HinU) continue;
      int iyr = upsample ? (iy >> 1) : iy;
      const float* srow = src + (size_t)iyr * Win;
      for (int kw = 0; kw < K; kw++) {
        int ix = x * stride + kw - pad;
        if (ix < 0 || ix >= WinU) continue;
        int ixr = upsample ? (ix >> 1) : ix;
        float v = srow[ixr];
        accA += v * sw[wbase + kh * K + kw];
        if (gated) accG += v * sw[n + wbase + kh * K + kw];
      }
    }
  }
  accA += bias[co];
  float o;
  if (act == 0) {
    accG += bias[co + coutEff];
    float a = accA > 0.f ? accA : expm1f(accA);
    o = a * (1.f / (1.f + expf(-accG)));
  } else if (act == 1) {
    accG += bias[co + coutEff];
    float a = fmaxf(accA, 0.f);
    o = a * (1.f / (1.f + expf(-accG)));
  } else {
    o = tanhf(accA);
  }
  out[(((size_t)b * coutEff + co) * Hout + y) * Wout + x] = o;
}

// ---------------- cp1 helpers ----------------
// mask_s = 4x4 avgpool of mask : (B,1,64,64)
__global__ void k_mask_s(const float* __restrict__ mask, float* __restrict__ mask_s) {
  int idx = blockIdx.x * 256 + threadIdx.x;
  if (idx >= BB * 4096) return;
  int b = idx >> 12, r = idx & 4095;
  int i = r >> 6, j = r & 63;
  float s = 0.f;
  for (int u = 0; u < 4; u++)
    for (int v = 0; v < 4; v++)
      s += mask[(size_t)b * 65536 + (i * 4 + u) * 256 + (j * 4 + v)];
  mask_s[idx] = s * (1.f / 16.f);
}

// mm[b,l] = (sum of padded-mask_s 4x4 window == 0) ? 1 : 0
__global__ void k_mm(const float* __restrict__ mask_s, float* __restrict__ mm) {
  int idx = blockIdx.x * 256 + threadIdx.x;
  if (idx >= BB * 1024) return;
  int b = idx >> 10, l = idx & 1023;
  int li = l >> 5, lj = l & 31;
  float s = 0.f;
  for (int dy = 0; dy < 4; dy++) {
    int row = 2 * li + dy - 1;
    if (row < 0 || row >= 64) continue;
    for (int dx = 0; dx < 4; dx++) {
      int col = 2 * lj + dx - 1;
      if (col < 0 || col >= 64) continue;
      s += mask_s[((size_t)b << 12) + row * 64 + col];
    }
  }
  mm[idx] = (s == 0.f) ? 1.f : 0.f;
}

// P[b][l][p], p = c*16 + dy*4 + dx ; src padded (pad=1) 64x64
__global__ void extract_patches(const float* __restrict__ xsim, float* __restrict__ P) {
  size_t idx = (size_t)blockIdx.x * 256 + threadIdx.x;
  if (idx >= (size_t)BB * 1024 * 1536) return;
  int p = (int)(idx % 1536);
  size_t t = idx / 1536;
  int l = (int)(t % 1024);
  int b = (int)(t / 1024);
  int c = p >> 4, r = p & 15, dy = r >> 2, dx = r & 3;
  int li = l >> 5, lj = l & 31;
  int row = 2 * li + dy - 1, col = 2 * lj + dx - 1;
  float v = 0.f;
  if (row >= 0 && row < 64 && col >= 0 && col < 64)
    v = xsim[(((size_t)b * 96 + c) * 64 + row) * 64 + col];
  P[idx] = v;
}

// scale[b,l] = mm[b,l] / max(||P[b,l,:]||, 1e-4)
__global__ void k_scale(const float* __restrict__ P, const float* __restrict__ mm,
                        float* __restrict__ scale) {
  int bl = blockIdx.x;  // 4096
  const float* row = P + (size_t)bl * 1536;
  int tid = threadIdx.x;
  float s = 0.f;
  for (int i = 0; i < 6; i++) { float v = row[tid + i * 256]; s += v * v; }
  __shared__ float red[256];
  red[tid] = s; __syncthreads();
  for (int t = 128; t > 0; t >>= 1) { if (tid < t) red[tid] += red[tid + t]; __syncthreads(); }
  if (tid == 0) scale[bl] = mm[bl] / fmaxf(sqrtf(red[0]), 1e-4f);
}

// S[b][q][l] = scale[b][l] * sum_k P[b][q][k]*P[b][l][k]
__global__ void gemm_qk(const float* __restrict__ P, const float* __restrict__ scale,
                        float* __restrict__ S) {
  int b = blockIdx.z;
  int qTile = blockIdx.y * 64, lTile = blockIdx.x * 64;
  const float* Pb = P + (size_t)b * 1024 * 1536;
  __shared__ float As[64][17];
  __shared__ float Bs[64][17];
  int tid = threadIdx.x;
  int tx = tid % 16, ty = tid / 16;
  float acc[4][4] = {};
  for (int k0 = 0; k0 < 1536; k0 += 16) {
    for (int i = 0; i < 4; i++) {
      int idx = tid + i * 256;
      int r = idx >> 4, c = idx & 15;
      As[r][c] = Pb[(size_t)(qTile + r) * 1536 + k0 + c];
      Bs[r][c] = Pb[(size_t)(lTile + r) * 1536 + k0 + c];
    }
    __syncthreads();
    for (int kk = 0; kk < 16; kk++) {
      float a[4], bv[4];
      for (int i = 0; i < 4; i++) a[i] = As[ty * 4 + i][kk];
      for (int j = 0; j < 4; j++) bv[j] = Bs[tx * 4 + j][kk];
      for (int i = 0; i < 4; i++)
        for (int j = 0; j < 4; j++) acc[i][j] += a[i] * bv[j];
    }
    __syncthreads();
  }
  for (int i = 0; i < 4; i++)
    for (int j = 0; j < 4; j++) {
      int q = qTile + ty * 4 + i, l = lTile + tx * 4 + j;
      S[((size_t)b * 1024 + q) * 1024 + l] = acc[i][j] * scale[b * 1024 + l];
    }
}

// softmax over l (contiguous) with scale 10, then * mm[l]; in-place on S[b][q][:]
__global__ void softmax_rows(float* __restrict__ S, const float* __restrict__ mm) {
  int q = blockIdx.x, b = blockIdx.y;
  float* row = S + ((size_t)b * 1024 + q) * 1024;
  int tid = threadIdx.x;
  float v[4];
  float mx = -1e30f;
  for (int i = 0; i < 4; i++) { v[i] = row[tid + i * 256]; mx = fmaxf(mx, v[i]); }
  __shared__ float red[256];
  red[tid] = mx; __syncthreads();
  for (int s = 128; s > 0; s >>= 1) { if (tid < s) red[tid] = fmaxf(red[tid], red[tid + s]); __syncthreads(); }
  mx = red[0]; __syncthreads();
  float sum = 0.f;
  for (int i = 0; i < 4; i++) { v[i] = expf(10.f * (v[i] - mx)); sum += v[i]; }
  red[tid] = sum; __syncthreads();
  for (int s = 128; s > 0; s >>= 1) { if (tid < s) red[tid] += red[tid + s]; __syncthreads(); }
  sum = red[0];
  float inv = 1.f / sum;
  for (int i = 0; i < 4; i++) {
    int l = tid + i * 256;
    row[l] = v[i] * inv * mm[b * 1024 + l];
  }
}

// ---------------- cp2 ----------------
// contrib[q][p] = sum_l simT[b][q][l] * W[l][p]; W from padded (pad=4) xb (B,24,256,256)
// p = c*256 + u*16 + v
__global__ void gemm_cp2(const float* __restrict__ simT, const float* __restrict__ xb,
                         float* __restrict__ contrib, int b) {
  int pTile = blockIdx.x * 64, qTile = blockIdx.y * 64;
  const float* Ab = simT + (size_t)b * 1024 * 1024;
  const float* xbb = xb + (size_t)b * 24 * 65536;
  __shared__ float As[64][17];
  __shared__ float Bs[16][65];
  int tid = threadIdx.x;
  int tx = tid % 16, ty = tid / 16;
  float acc[4][4] = {};
  for (int l0 = 0; l0 < 1024; l0 += 16) {
    for (int i = 0; i < 4; i++) {
      int idx = tid + i * 256;
      int r = idx >> 4, c = idx & 15;
      As[r][c] = Ab[(size_t)(qTile + r) * 1024 + l0 + c];
    }
    for (int i = 0; i < 4; i++) {
      int idx = tid + i * 256;
      int lr = idx >> 6, pc = idx & 63;
      int l = l0 + lr, p = pTile + pc;
      int li = l >> 5, lj = l & 31;
      int c = p >> 8, u = (p >> 4) & 15, v = p & 15;
      int row = 8 * li + u - 4, col = 8 * lj + v - 4;
      float val = 0.f;
      if (row >= 0 && row < 256 && col >= 0 && col < 256)
        val = xbb[((size_t)c * 256 + row) * 256 + col];
      Bs[lr][pc] = val;
    }
    __syncthreads();
    for (int kk = 0; kk < 16; kk++) {
      float a[4], bv[4];
      for (int i = 0; i < 4; i++) a[i] = As[ty * 4 + i][kk];
      for (int j = 0; j < 4; j++) bv[j] = Bs[kk][tx * 4 + j];
      for (int i = 0; i < 4; i++)
        for (int j = 0; j < 4; j++) acc[i][j] += a[i] * bv[j];
    }
    __syncthreads();
  }
  for (int i = 0; i < 4; i++)
    for (int j = 0; j < 4; j++) {
      int q = qTile + ty * 4 + i, p = pTile + tx * 4 + j;
      contrib[(size_t)q * 6144 + p] = acc[i][j];
    }
}

// fold contrib back, divide by count, crop, blend with mask
__global__ void k_fold(const float* __restrict__ contrib, const float* __restrict__ t16,
                       const float* __restrict__ mask, float* __restrict__ out, int b) {
  int idx = blockIdx.x * 256 + threadIdx.x;
  if (idx >= 24 * 65536) return;
  int c = idx >> 16, r = idx & 65535;
  int Y = r >> 8, X = r & 255;
  int yp = Y + 4, xp = X + 4;
  int qis[2], qjs[2];
  int cy = 0, cx = 0;
  int qi1 = yp >> 3;
  if (qi1 - 1 >= 0) qis[cy++] = qi1 - 1;
  if (qi1 < 32) qis[cy++] = qi1;
  int qj1 = xp >> 3;
  if (qj1 - 1 >= 0) qjs[cx++] = qj1 - 1;
  if (qj1 < 32) qjs[cx++] = qj1;
  float sum = 0.f;
  for (int a = 0; a < cy; a++)
    for (int d = 0; d < cx; d++) {
      int qi = qis[a], qj = qjs[d];
      int u = yp - 8 * qi, v = xp - 8 * qj;
      sum += contrib[(size_t)(qi * 32 + qj) * 6144 + c * 256 + u * 16 + v];
    }
  float cnt = (float)(cy * cx);
  float o = sum / fmaxf(cnt, 1e-8f);
  float m = mask[(size_t)b * 65536 + r % 65536];
  size_t srci = (size_t)(b * 24 + c) * 65536 + r;
  out[srci] = o * m + t16[srci] * (1.f - m);
}

// ---------------- launch ----------------
extern "C" void kernel_launch(void* const* d_in, const int* in_sizes, int n_in,
                              void* d_out, int out_size, void* d_ws, size_t ws_size,
                              hipStream_t stream) {
  const float* x      = (const float*)d_in[0];
  const float* mask   = (const float*)d_in[1];
  const float* x_st1  = (const float*)d_in[2];
  const float* x_st2  = (const float*)d_in[3];
  const float* pm     = (const float*)d_in[4];
  const float* w_sconv1 = (const float*)d_in[5];  const float* b_sconv1 = (const float*)d_in[6];
  const float* w_sconv2 = (const float*)d_in[7];  const float* b_sconv2 = (const float*)d_in[8];
  const float* w_bconv1 = (const float*)d_in[9];  const float* b_bconv1 = (const float*)d_in[10];
  const float* w_bconv2 = (const float*)d_in[11]; const float* b_bconv2 = (const float*)d_in[12];
  const float* w_bconv3 = (const float*)d_in[13]; const float* b_bconv3 = (const float*)d_in[14];
  const float* w_bconv4 = (const float*)d_in[15]; const float* b_bconv4 = (const float*)d_in[16];
  const float* w_conv13 = (const float*)d_in[17]; const float* b_conv13 = (const float*)d_in[18];
  const float* w_conv14 = (const float*)d_in[19]; const float* b_conv14 = (const float*)d_in[20];
  const float* w_conv15 = (const float*)d_in[21]; const float* b_conv15 = (const float*)d_in[22];
  const float* w_conv16 = (const float*)d_in[23]; const float* b_conv16 = (const float*)d_in[24];
  const float* w_conv16_2 = (const float*)d_in[25]; const float* b_conv16_2 = (const float*)d_in[26];
  const float* w_conv17 = (const float*)d_in[27]; const float* b_conv17 = (const float*)d_in[28];
  float* out = (float*)d_out;
  float* ws = (float*)d_ws;

  // workspace layout (floats), with slot reuse
  const size_t o_sim     = 0;         // 4*1024*1024
  const size_t o_xnow    = 4194304;   // 786432
  const size_t o_xs      = 4980736;   // 1572864
  const size_t o_xsim    = 6553600;   // 1572864
  const size_t o_masks   = 8126464;   // 16384
  const size_t o_mm      = 8142848;   // 4096
  const size_t o_scale   = 8146944;   // 4096
  const size_t o_P       = 8151040;   // 6291456  (later: t15)
  const size_t o_skip1   = 14442496;  // 6291456  (later: cp2out)
  const size_t o_t2      = 20733952;  // 3145728  (later: t14)
  const size_t o_skip2   = 23879680;  // 3145728
  const size_t o_t4      = 27025408;  // 1572864
  const size_t o_t13     = 28598272;  // 3145728
  const size_t o_t16     = 31744000;  // 6291456
  const size_t o_contrib = 38035456;  // 6291456  (later: t16_2)
  (void)in_sizes; (void)n_in; (void)out_size; (void)ws_size;

  // outputs 0,1: pass-through copies
  hipMemcpyAsync(out, x_st1, (size_t)786432 * 4, hipMemcpyDeviceToDevice, stream);
  hipMemcpyAsync(out + 786432, x_st2, (size_t)786432 * 4, hipMemcpyDeviceToDevice, stream);

  // xnow
  k_xnow<<<3072, 256, 0, stream>>>(x, x_st2, mask, ws + o_xnow);

  // similarity branch
  conv_gated<<<dim3(16, 96, BB), 256, 96 * 25 * 2 * 4, stream>>>(
      pm, nullptr, 96, 0, w_sconv1, b_sconv1, ws + o_xs, 64, 64, 64, 64, 5, 1, 0, 192, 0);
  conv_gated<<<dim3(16, 96, BB), 256, 96 * 9 * 2 * 4, stream>>>(
      ws + o_xs, nullptr, 96, 0, w_sconv2, b_sconv2, ws + o_xsim, 64, 64, 64, 64, 3, 1, 0, 192, 1);
  k_mask_s<<<64, 256, 0, stream>>>(mask, ws + o_masks);
  k_mm<<<16, 256, 0, stream>>>(ws + o_masks, ws + o_mm);
  extract_patches<<<24576, 256, 0, stream>>>(ws + o_xsim, ws + o_P);
  k_scale<<<4096, 256, 0, stream>>>(ws + o_P, ws + o_mm, ws + o_scale);
  gemm_qk<<<dim3(16, 16, BB), 256, 0, stream>>>(ws + o_P, ws + o_scale, ws + o_sim);
  softmax_rows<<<dim3(1024, BB), 256, 0, stream>>>(ws + o_sim, ws + o_mm);

  // main branch
  conv_gated<<<dim3(256, 24, BB), 256, 3 * 25 * 2 * 4, stream>>>(
      ws + o_xnow, nullptr, 3, 0, w_bconv1, b_bconv1, ws + o_skip1, 256, 256, 256, 256, 5, 1, 0, 48, 0);
  conv_gated<<<dim3(64, 48, BB), 256, 24 * 9 * 2 * 4, stream>>>(
      ws + o_skip1, nullptr, 24, 0, w_bconv2, b_bconv2, ws + o_t2, 256, 256, 128, 128, 3, 2, 0, 96, 0);
  conv_gated<<<dim3(64, 48, BB), 256, 48 * 9 * 2 * 4, stream>>>(
      ws + o_t2, nullptr, 48, 0, w_bconv3, b_bconv3, ws + o_skip2, 128, 128, 128, 128, 3, 1, 0, 96, 0);
  conv_gated<<<dim3(16, 96, BB), 256, 48 * 9 * 2 * 4, stream>>>(
      ws + o_skip2, nullptr, 48, 0, w_bconv4, b_bconv4, ws + o_t4, 128, 128, 64, 64, 3, 2, 0, 192, 0);
  conv_gated<<<dim3(64, 48, BB), 256, 96 * 9 * 2 * 4, stream>>>(
      ws + o_t4, nullptr, 96, 0, w_conv13, b_conv13, ws + o_t13, 64, 64, 128, 128, 3, 1, 1, 96, 0);
  conv_gated<<<dim3(64, 48, BB), 256, 96 * 9 * 2 * 4, stream>>>(
      ws + o_t13, ws + o_skip2, 48, 48, w_conv14, b_conv14, ws + o_t2, 128, 128, 128, 128, 3, 1, 0, 96, 0);
  conv_gated<<<dim3(256, 24, BB), 256, 48 * 9 * 2 * 4, stream>>>(
      ws + o_t2, nullptr, 48, 0, w_conv15, b_conv15, ws + o_P, 128, 128, 256, 256, 3, 1, 1, 48, 0);
  conv_gated<<<dim3(256, 24, BB), 256, 48 * 9 * 2 * 4, stream>>>(
      ws + o_P, ws + o_skip1, 24, 24, w_conv16, b_conv16, ws + o_t16, 256, 256, 256, 256, 3, 1, 0, 48, 0);

  // cp2: per-batch GEMM + fold (contrib buffer reused)
  for (int b = 0; b < BB; b++) {
    gemm_cp2<<<dim3(96, 16), 256, 0, stream>>>(ws + o_sim, ws + o_t16, ws + o_contrib, b);
    k_fold<<<6144, 256, 0, stream>>>(ws + o_contrib, ws + o_t16, mask, ws + o_skip1, b);
  }

  // tail convs
  conv_gated<<<dim3(256, 24, BB), 256, 24 * 9 * 2 * 4, stream>>>(
      ws + o_skip1, nullptr, 24, 0, w_conv16_2, b_conv16_2, ws + o_contrib, 256, 256, 256, 256, 3, 1, 0, 48, 0);
  conv_gated<<<dim3(256, 3, BB), 256, 24 * 9 * 1 * 4, stream>>>(
      ws + o_contrib, nullptr, 24, 0, w_conv17, b_conv17, out + 2 * 786432, 256, 256, 256, 256, 3, 1, 0, 3, 2);
}

// Round 2
// 3370.284 us; speedup vs baseline: 3.3780x; 3.3780x over previous
//
#include <hip/hip_runtime.h>
#include <math.h>

#define BB 4

// ---------------- elementwise: xnow = x2*m + x*(1-m) ----------------
__global__ void k_xnow(const float* __restrict__ x, const float* __restrict__ x2,
                       const float* __restrict__ mask, float* __restrict__ xnow) {
  int idx = blockIdx.x * 256 + threadIdx.x;
  if (idx >= BB * 3 * 65536) return;
  int b = idx / (3 * 65536);
  int r = idx % 65536;
  float m = mask[b * 65536 + r];
  xnow[idx] = x2[idx] * m + x[idx] * (1.f - m);
}

// ---------------- tiled conv: 16x8 pixel tile x 32 cout, register tiled ----
// act: 0 = gated ELU, 1 = gated ReLU, 2 = plain + tanh
// upsample: input is nearest-2x-upsampled during LDS staging.
template <int K, int STRIDE, int CC>
__global__ __launch_bounds__(256) void conv_tile(
    const float* __restrict__ in1, const float* __restrict__ in2,
    int c1, int c2,
    const float* __restrict__ w, const float* __restrict__ bias,
    float* __restrict__ out,
    int Hin, int Win, int Hout, int Wout,
    int coutEff, int act, int upsample, int tilesX) {
  constexpr int TW = 16, TH = 8;
  constexpr int IW = (TW - 1) * STRIDE + K;
  constexpr int IH = (TH - 1) * STRIDE + K;
  constexpr int WIN = (8 - 1) * STRIDE + K;
  __shared__ float sIn[CC * IH * IW];
  __shared__ float sWA[CC * K * K * 32];
  __shared__ float sWG[CC * K * K * 32];

  const int tid = threadIdx.x;
  const int tx = tid & 15, ty = tid >> 4;
  const int rr = tx >> 1, c0 = (tx & 1) * 8;
  const int tX = blockIdx.x % tilesX, tY = blockIdx.x / tilesX;
  const int b = blockIdx.z;
  const int mBase = blockIdx.y * 32;
  const int cin = c1 + c2;
  const int pad = (K - 1) / 2;
  const int HinU = Hin << upsample;
  const int WinU = Win << upsample;
  const int oy0 = tY * TH * STRIDE - pad;
  const int ox0 = tX * TW * STRIDE - pad;

  float accA[2][8] = {};
  float accG[2][8] = {};

  for (int ci0 = 0; ci0 < cin; ci0 += CC) {
    __syncthreads();
    // stage input halo tile (upsample handled by >>1 gather)
    for (int idx = tid; idx < CC * IH * IW; idx += 256) {
      int ci = idx / (IH * IW);
      int rem = idx % (IH * IW);
      int r = rem / IW, c = rem % IW;
      int gy = oy0 + r, gx = ox0 + c;
      int cg = ci0 + ci;
      float v = 0.f;
      if (cg < cin && gy >= 0 && gy < HinU && gx >= 0 && gx < WinU) {
        int sy = gy >> upsample, sx = gx >> upsample;
        const float* src = (cg < c1) ? in1 + (size_t)(b * c1 + cg) * Hin * Win
                                     : in2 + (size_t)(b * c2 + (cg - c1)) * Hin * Win;
        v = src[(size_t)sy * Win + sx];
      }
      sIn[idx] = v;
    }
    // stage weights [ci][kh][kw][32]
    for (int idx = tid; idx < CC * K * K * 32; idx += 256) {
      int mm = idx & 31;
      int t = idx >> 5;
      int ci = t / (K * K);
      int kk = t % (K * K);
      int cg = ci0 + ci, co = mBase + mm;
      float va = 0.f, vg = 0.f;
      if (cg < cin && co < coutEff) {
        size_t base = ((size_t)co * cin + cg) * (K * K) + kk;
        va = w[base];
        if (act != 2) vg = w[base + (size_t)coutEff * cin * (K * K)];
      }
      sWA[idx] = va;
      sWG[idx] = vg;
    }
    __syncthreads();
    // compute
#pragma unroll
    for (int ci = 0; ci < CC; ci++) {
#pragma unroll
      for (int kh = 0; kh < K; kh++) {
        float win[WIN];
        int base = (ci * IH + (rr * STRIDE + kh)) * IW + c0 * STRIDE;
#pragma unroll
        for (int i = 0; i < WIN; i++) win[i] = sIn[base + i];
#pragma unroll
        for (int kw = 0; kw < K; kw++) {
          int wi = ((ci * K + kh) * K + kw) * 32 + 2 * ty;
          float wa0 = sWA[wi], wa1 = sWA[wi + 1];
          float wg0 = sWG[wi], wg1 = sWG[wi + 1];
#pragma unroll
          for (int i = 0; i < 8; i++) {
            float v = win[i * STRIDE + kw];
            accA[0][i] += v * wa0;
            accA[1][i] += v * wa1;
            accG[0][i] += v * wg0;
            accG[1][i] += v * wg1;
          }
        }
      }
    }
  }

  int y = tY * TH + rr;
  int xb_ = tX * TW + c0;
#pragma unroll
  for (int mi = 0; mi < 2; mi++) {
    int m = mBase + ty * 2 + mi;
    if (m >= coutEff) continue;
    float bA = bias[m];
    float bG = (act != 2) ? bias[m + coutEff] : 0.f;
    float o[8];
#pragma unroll
    for (int i = 0; i < 8; i++) {
      float a = accA[mi][i] + bA;
      if (act == 2) {
        o[i] = tanhf(a);
      } else {
        float g = accG[mi][i] + bG;
        float aa = (act == 1) ? fmaxf(a, 0.f) : (a > 0.f ? a : expm1f(a));
        o[i] = aa * (1.f / (1.f + expf(-g)));
      }
    }
    float* dst = out + (((size_t)b * coutEff + m) * Hout + y) * Wout + xb_;
    *(float4*)dst = make_float4(o[0], o[1], o[2], o[3]);
    *(float4*)(dst + 4) = make_float4(o[4], o[5], o[6], o[7]);
  }
}

// ---------------- cp1 helpers ----------------
__global__ void k_mask_s(const float* __restrict__ mask, float* __restrict__ mask_s) {
  int idx = blockIdx.x * 256 + threadIdx.x;
  if (idx >= BB * 4096) return;
  int b = idx >> 12, r = idx & 4095;
  int i = r >> 6, j = r & 63;
  float s = 0.f;
  for (int u = 0; u < 4; u++)
    for (int v = 0; v < 4; v++)
      s += mask[(size_t)b * 65536 + (i * 4 + u) * 256 + (j * 4 + v)];
  mask_s[idx] = s * (1.f / 16.f);
}

__global__ void k_mm(const float* __restrict__ mask_s, float* __restrict__ mm) {
  int idx = blockIdx.x * 256 + threadIdx.x;
  if (idx >= BB * 1024) return;
  int b = idx >> 10, l = idx & 1023;
  int li = l >> 5, lj = l & 31;
  float s = 0.f;
  for (int dy = 0; dy < 4; dy++) {
    int row = 2 * li + dy - 1;
    if (row < 0 || row >= 64) continue;
    for (int dx = 0; dx < 4; dx++) {
      int col = 2 * lj + dx - 1;
      if (col < 0 || col >= 64) continue;
      s += mask_s[((size_t)b << 12) + row * 64 + col];
    }
  }
  mm[idx] = (s == 0.f) ? 1.f : 0.f;
}

__global__ void extract_patches(const float* __restrict__ xsim, float* __restrict__ P) {
  size_t idx = (size_t)blockIdx.x * 256 + threadIdx.x;
  if (idx >= (size_t)BB * 1024 * 1536) return;
  int p = (int)(idx % 1536);
  size_t t = idx / 1536;
  int l = (int)(t % 1024);
  int b = (int)(t / 1024);
  int c = p >> 4, r = p & 15, dy = r >> 2, dx = r & 3;
  int li = l >> 5, lj = l & 31;
  int row = 2 * li + dy - 1, col = 2 * lj + dx - 1;
  float v = 0.f;
  if (row >= 0 && row < 64 && col >= 0 && col < 64)
    v = xsim[(((size_t)b * 96 + c) * 64 + row) * 64 + col];
  P[idx] = v;
}

__global__ void k_scale(const float* __restrict__ P, const float* __restrict__ mm,
                        float* __restrict__ scale) {
  int bl = blockIdx.x;
  const float* row = P + (size_t)bl * 1536;
  int tid = threadIdx.x;
  float s = 0.f;
  for (int i = 0; i < 6; i++) { float v = row[tid + i * 256]; s += v * v; }
  __shared__ float red[256];
  red[tid] = s; __syncthreads();
  for (int t = 128; t > 0; t >>= 1) { if (tid < t) red[tid] += red[tid + t]; __syncthreads(); }
  if (tid == 0) scale[bl] = mm[bl] / fmaxf(sqrtf(red[0]), 1e-4f);
}

// S[b][q][l] = scale[b][l] * sum_k P[b][q][k]*P[b][l][k]
__global__ __launch_bounds__(256) void gemm_qk(const float* __restrict__ P,
                                               const float* __restrict__ scale,
                                               float* __restrict__ S) {
  int b = blockIdx.z;
  int qTile = blockIdx.y * 64, lTile = blockIdx.x * 64;
  const float* Pb = P + (size_t)b * 1024 * 1536;
  __shared__ __align__(16) float As[16 * 68];
  __shared__ __align__(16) float Bs[16 * 68];
  int tid = threadIdx.x;
  int tx = tid & 15, ty = tid >> 4;
  float acc[4][4] = {};
  for (int k0 = 0; k0 < 1536; k0 += 16) {
#pragma unroll
    for (int i = 0; i < 4; i++) {
      int idx = tid + i * 256;
      int kk = idx & 15, r = idx >> 4;
      As[kk * 68 + r] = Pb[(size_t)(qTile + r) * 1536 + k0 + kk];
      Bs[kk * 68 + r] = Pb[(size_t)(lTile + r) * 1536 + k0 + kk];
    }
    __syncthreads();
#pragma unroll
    for (int kk = 0; kk < 16; kk++) {
      float4 a = *(float4*)&As[kk * 68 + ty * 4];
      float4 bv = *(float4*)&Bs[kk * 68 + tx * 4];
      float av[4] = {a.x, a.y, a.z, a.w};
      float bb[4] = {bv.x, bv.y, bv.z, bv.w};
#pragma unroll
      for (int i = 0; i < 4; i++)
#pragma unroll
        for (int j = 0; j < 4; j++) acc[i][j] += av[i] * bb[j];
    }
    __syncthreads();
  }
  float4 sc = *(const float4*)&scale[b * 1024 + lTile + tx * 4];
  float scv[4] = {sc.x, sc.y, sc.z, sc.w};
#pragma unroll
  for (int i = 0; i < 4; i++) {
    int q = qTile + ty * 4 + i;
    float4 o = make_float4(acc[i][0] * scv[0], acc[i][1] * scv[1],
                           acc[i][2] * scv[2], acc[i][3] * scv[3]);
    *(float4*)&S[((size_t)b * 1024 + q) * 1024 + lTile + tx * 4] = o;
  }
}

__global__ void softmax_rows(float* __restrict__ S, const float* __restrict__ mm) {
  int q = blockIdx.x, b = blockIdx.y;
  float* row = S + ((size_t)b * 1024 + q) * 1024;
  int tid = threadIdx.x;
  float v[4];
  float mx = -1e30f;
  for (int i = 0; i < 4; i++) { v[i] = row[tid + i * 256]; mx = fmaxf(mx, v[i]); }
  __shared__ float red[256];
  red[tid] = mx; __syncthreads();
  for (int s = 128; s > 0; s >>= 1) { if (tid < s) red[tid] = fmaxf(red[tid], red[tid + s]); __syncthreads(); }
  mx = red[0]; __syncthreads();
  float sum = 0.f;
  for (int i = 0; i < 4; i++) { v[i] = expf(10.f * (v[i] - mx)); sum += v[i]; }
  red[tid] = sum; __syncthreads();
  for (int s = 128; s > 0; s >>= 1) { if (tid < s) red[tid] += red[tid + s]; __syncthreads(); }
  sum = red[0];
  float inv = 1.f / sum;
  for (int i = 0; i < 4; i++) {
    int l = tid + i * 256;
    row[l] = v[i] * inv * mm[b * 1024 + l];
  }
}

// ---------------- cp2 ----------------
__global__ __launch_bounds__(256) void gemm_cp2(const float* __restrict__ simT,
                                                const float* __restrict__ xb,
                                                float* __restrict__ contrib, int b) {
  int pTile = blockIdx.x * 64, qTile = blockIdx.y * 64;
  const float* Ab = simT + (size_t)b * 1024 * 1024;
  const float* xbb = xb + (size_t)b * 24 * 65536;
  __shared__ __align__(16) float As[16 * 68];
  __shared__ __align__(16) float Bs[16 * 68];
  int tid = threadIdx.x;
  int tx = tid & 15, ty = tid >> 4;
  float acc[4][4] = {};
  for (int l0 = 0; l0 < 1024; l0 += 16) {
#pragma unroll
    for (int i = 0; i < 4; i++) {
      int idx = tid + i * 256;
      int kk = idx & 15, r = idx >> 4;
      As[kk * 68 + r] = Ab[(size_t)(qTile + r) * 1024 + l0 + kk];
    }
#pragma unroll
    for (int i = 0; i < 4; i++) {
      int idx = tid + i * 256;
      int lr = idx >> 6, pc = idx & 63;
      int l = l0 + lr, p = pTile + pc;
      int li = l >> 5, lj = l & 31;
      int c = p >> 8, u = (p >> 4) & 15, v = p & 15;
      int row = 8 * li + u - 4, col = 8 * lj + v - 4;
      float val = 0.f;
      if (row >= 0 && row < 256 && col >= 0 && col < 256)
        val = xbb[((size_t)c * 256 + row) * 256 + col];
      Bs[lr * 68 + pc] = val;
    }
    __syncthreads();
#pragma unroll
    for (int kk = 0; kk < 16; kk++) {
      float4 a = *(float4*)&As[kk * 68 + ty * 4];
      float4 bv = *(float4*)&Bs[kk * 68 + tx * 4];
      float av[4] = {a.x, a.y, a.z, a.w};
      float bb[4] = {bv.x, bv.y, bv.z, bv.w};
#pragma unroll
      for (int i = 0; i < 4; i++)
#pragma unroll
        for (int j = 0; j < 4; j++) acc[i][j] += av[i] * bb[j];
    }
    __syncthreads();
  }
#pragma unroll
  for (int i = 0; i < 4; i++) {
    int q = qTile + ty * 4 + i;
    *(float4*)&contrib[(size_t)q * 6144 + pTile + tx * 4] =
        make_float4(acc[i][0], acc[i][1], acc[i][2], acc[i][3]);
  }
}

__global__ void k_fold(const float* __restrict__ contrib, const float* __restrict__ t16,
                       const float* __restrict__ mask, float* __restrict__ out, int b) {
  int idx = blockIdx.x * 256 + threadIdx.x;
  if (idx >= 24 * 65536) return;
  int c = idx >> 16, r = idx & 65535;
  int Y = r >> 8, X = r & 255;
  int yp = Y + 4, xp = X + 4;
  int qis[2], qjs[2];
  int cy = 0, cx = 0;
  int qi1 = yp >> 3;
  if (qi1 - 1 >= 0) qis[cy++] = qi1 - 1;
  if (qi1 < 32) qis[cy++] = qi1;
  int qj1 = xp >> 3;
  if (qj1 - 1 >= 0) qjs[cx++] = qj1 - 1;
  if (qj1 < 32) qjs[cx++] = qj1;
  float sum = 0.f;
  for (int a = 0; a < cy; a++)
    for (int d = 0; d < cx; d++) {
      int qi = qis[a], qj = qjs[d];
      int u = yp - 8 * qi, v = xp - 8 * qj;
      sum += contrib[(size_t)(qi * 32 + qj) * 6144 + c * 256 + u * 16 + v];
    }
  float cnt = (float)(cy * cx);
  float o = sum / fmaxf(cnt, 1e-8f);
  float m = mask[(size_t)b * 65536 + r % 65536];
  size_t srci = (size_t)(b * 24 + c) * 65536 + r;
  out[srci] = o * m + t16[srci] * (1.f - m);
}

// ---------------- launch ----------------
extern "C" void kernel_launch(void* const* d_in, const int* in_sizes, int n_in,
                              void* d_out, int out_size, void* d_ws, size_t ws_size,
                              hipStream_t stream) {
  const float* x      = (const float*)d_in[0];
  const float* mask   = (const float*)d_in[1];
  const float* x_st1  = (const float*)d_in[2];
  const float* x_st2  = (const float*)d_in[3];
  const float* pm     = (const float*)d_in[4];
  const float* w_sconv1 = (const float*)d_in[5];  const float* b_sconv1 = (const float*)d_in[6];
  const float* w_sconv2 = (const float*)d_in[7];  const float* b_sconv2 = (const float*)d_in[8];
  const float* w_bconv1 = (const float*)d_in[9];  const float* b_bconv1 = (const float*)d_in[10];
  const float* w_bconv2 = (const float*)d_in[11]; const float* b_bconv2 = (const float*)d_in[12];
  const float* w_bconv3 = (const float*)d_in[13]; const float* b_bconv3 = (const float*)d_in[14];
  const float* w_bconv4 = (const float*)d_in[15]; const float* b_bconv4 = (const float*)d_in[16];
  const float* w_conv13 = (const float*)d_in[17]; const float* b_conv13 = (const float*)d_in[18];
  const float* w_conv14 = (const float*)d_in[19]; const float* b_conv14 = (const float*)d_in[20];
  const float* w_conv15 = (const float*)d_in[21]; const float* b_conv15 = (const float*)d_in[22];
  const float* w_conv16 = (const float*)d_in[23]; const float* b_conv16 = (const float*)d_in[24];
  const float* w_conv16_2 = (const float*)d_in[25]; const float* b_conv16_2 = (const float*)d_in[26];
  const float* w_conv17 = (const float*)d_in[27]; const float* b_conv17 = (const float*)d_in[28];
  float* out = (float*)d_out;
  float* ws = (float*)d_ws;

  const size_t o_sim     = 0;         // 4*1024*1024
  const size_t o_xnow    = 4194304;   // 786432
  const size_t o_xs      = 4980736;   // 1572864
  const size_t o_xsim    = 6553600;   // 1572864
  const size_t o_masks   = 8126464;   // 16384
  const size_t o_mm      = 8142848;   // 4096
  const size_t o_scale   = 8146944;   // 4096
  const size_t o_P       = 8151040;   // 6291456  (later: t15)
  const size_t o_skip1   = 14442496;  // 6291456  (later: cp2out)
  const size_t o_t2      = 20733952;  // 3145728  (later: t14)
  const size_t o_skip2   = 23879680;  // 3145728
  const size_t o_t4      = 27025408;  // 1572864
  const size_t o_t13     = 28598272;  // 3145728
  const size_t o_t16     = 31744000;  // 6291456
  const size_t o_contrib = 38035456;  // 6291456  (later: t16_2)
  (void)in_sizes; (void)n_in; (void)out_size; (void)ws_size;

  // outputs 0,1: pass-through copies
  hipMemcpyAsync(out, x_st1, (size_t)786432 * 4, hipMemcpyDeviceToDevice, stream);
  hipMemcpyAsync(out + 786432, x_st2, (size_t)786432 * 4, hipMemcpyDeviceToDevice, stream);

  k_xnow<<<3072, 256, 0, stream>>>(x, x_st2, mask, ws + o_xnow);

  // similarity branch: 64x64 -> tilesX=4, tiles=32
  conv_tile<5, 1, 4><<<dim3(32, 3, BB), 256, 0, stream>>>(
      pm, nullptr, 96, 0, w_sconv1, b_sconv1, ws + o_xs, 64, 64, 64, 64, 96, 0, 0, 4);
  conv_tile<3, 1, 8><<<dim3(32, 3, BB), 256, 0, stream>>>(
      ws + o_xs, nullptr, 96, 0, w_sconv2, b_sconv2, ws + o_xsim, 64, 64, 64, 64, 96, 1, 0, 4);
  k_mask_s<<<64, 256, 0, stream>>>(mask, ws + o_masks);
  k_mm<<<16, 256, 0, stream>>>(ws + o_masks, ws + o_mm);
  extract_patches<<<24576, 256, 0, stream>>>(ws + o_xsim, ws + o_P);
  k_scale<<<4096, 256, 0, stream>>>(ws + o_P, ws + o_mm, ws + o_scale);
  gemm_qk<<<dim3(16, 16, BB), 256, 0, stream>>>(ws + o_P, ws + o_scale, ws + o_sim);
  softmax_rows<<<dim3(1024, BB), 256, 0, stream>>>(ws + o_sim, ws + o_mm);

  // main branch
  conv_tile<5, 1, 4><<<dim3(512, 1, BB), 256, 0, stream>>>(
      ws + o_xnow, nullptr, 3, 0, w_bconv1, b_bconv1, ws + o_skip1, 256, 256, 256, 256, 24, 0, 0, 16);
  conv_tile<3, 2, 8><<<dim3(128, 2, BB), 256, 0, stream>>>(
      ws + o_skip1, nullptr, 24, 0, w_bconv2, b_bconv2, ws + o_t2, 256, 256, 128, 128, 48, 0, 0, 8);
  conv_tile<3, 1, 8><<<dim3(128, 2, BB), 256, 0, stream>>>(
      ws + o_t2, nullptr, 48, 0, w_bconv3, b_bconv3, ws + o_skip2, 128, 128, 128, 128, 48, 0, 0, 8);
  conv_tile<3, 2, 8><<<dim3(32, 3, BB), 256, 0, stream>>>(
      ws + o_skip2, nullptr, 48, 0, w_bconv4, b_bconv4, ws + o_t4, 128, 128, 64, 64, 96, 0, 0, 4);
  conv_tile<3, 1, 8><<<dim3(128, 2, BB), 256, 0, stream>>>(
      ws + o_t4, nullptr, 96, 0, w_conv13, b_conv13, ws + o_t13, 64, 64, 128, 128, 48, 0, 1, 8);
  conv_tile<3, 1, 8><<<dim3(128, 2, BB), 256, 0, stream>>>(
      ws + o_t13, ws + o_skip2, 48, 48, w_conv14, b_conv14, ws + o_t2, 128, 128, 128, 128, 48, 0, 0, 8);
  conv_tile<3, 1, 8><<<dim3(512, 1, BB), 256, 0, stream>>>(
      ws + o_t2, nullptr, 48, 0, w_conv15, b_conv15, ws + o_P, 128, 128, 256, 256, 24, 0, 1, 16);
  conv_tile<3, 1, 8><<<dim3(512, 1, BB), 256, 0, stream>>>(
      ws + o_P, ws + o_skip1, 24, 24, w_conv16, b_conv16, ws + o_t16, 256, 256, 256, 256, 24, 0, 0, 16);

  // cp2
  for (int b = 0; b < BB; b++) {
    gemm_cp2<<<dim3(96, 16), 256, 0, stream>>>(ws + o_sim, ws + o_t16, ws + o_contrib, b);
    k_fold<<<6144, 256, 0, stream>>>(ws + o_contrib, ws + o_t16, mask, ws + o_skip1, b);
  }

  // tail convs
  conv_tile<3, 1, 8><<<dim3(512, 1, BB), 256, 0, stream>>>(
      ws + o_skip1, nullptr, 24, 0, w_conv16_2, b_conv16_2, ws + o_contrib, 256, 256, 256, 256, 24, 0, 0, 16);
  conv_tile<3, 1, 8><<<dim3(512, 1, BB), 256, 0, stream>>>(
      ws + o_contrib, nullptr, 24, 0, w_conv17, b_conv17, out + 2 * 786432, 256, 256, 256, 256, 3, 2, 0, 16);
}

// Round 3
// 3082.970 us; speedup vs baseline: 3.6928x; 1.0932x over previous
//
#include <hip/hip_runtime.h>
#include <math.h>

#define BB 4

typedef __bf16 bf16x8 __attribute__((ext_vector_type(8)));
typedef float f32x4 __attribute__((ext_vector_type(4)));

__device__ inline ushort f2bf(float x) {
  uint u = __float_as_uint(x);
  uint r = (u + 0x7fffu + ((u >> 16) & 1u)) >> 16;
  return (ushort)r;
}
__device__ inline float bf2f(ushort h) { return __uint_as_float(((uint)h) << 16); }
__device__ inline bf16x8 as_bf(uint4 u) {
  union { uint4 u; bf16x8 b; } c;
  c.u = u;
  return c.b;
}

// ---------------- elementwise: xnow = x2*m + x*(1-m) ----------------
__global__ void k_xnow(const float* __restrict__ x, const float* __restrict__ x2,
                       const float* __restrict__ mask, float* __restrict__ xnow) {
  int idx = blockIdx.x * 256 + threadIdx.x;
  if (idx >= BB * 3 * 65536) return;
  int b = idx / (3 * 65536);
  int r = idx % 65536;
  float m = mask[b * 65536 + r];
  xnow[idx] = x2[idx] * m + x[idx] * (1.f - m);
}

// ---------------- tiled conv (unchanged from round 2) ----------------
template <int K, int STRIDE, int CC>
__global__ __launch_bounds__(256) void conv_tile(
    const float* __restrict__ in1, const float* __restrict__ in2,
    int c1, int c2,
    const float* __restrict__ w, const float* __restrict__ bias,
    float* __restrict__ out,
    int Hin, int Win, int Hout, int Wout,
    int coutEff, int act, int upsample, int tilesX) {
  constexpr int TW = 16, TH = 8;
  constexpr int IW = (TW - 1) * STRIDE + K;
  constexpr int IH = (TH - 1) * STRIDE + K;
  constexpr int WIN = (8 - 1) * STRIDE + K;
  __shared__ float sIn[CC * IH * IW];
  __shared__ float sWA[CC * K * K * 32];
  __shared__ float sWG[CC * K * K * 32];

  const int tid = threadIdx.x;
  const int tx = tid & 15, ty = tid >> 4;
  const int rr = tx >> 1, c0 = (tx & 1) * 8;
  const int tX = blockIdx.x % tilesX, tY = blockIdx.x / tilesX;
  const int b = blockIdx.z;
  const int mBase = blockIdx.y * 32;
  const int cin = c1 + c2;
  const int pad = (K - 1) / 2;
  const int HinU = Hin << upsample;
  const int WinU = Win << upsample;
  const int oy0 = tY * TH * STRIDE - pad;
  const int ox0 = tX * TW * STRIDE - pad;

  float accA[2][8] = {};
  float accG[2][8] = {};

  for (int ci0 = 0; ci0 < cin; ci0 += CC) {
    __syncthreads();
    for (int idx = tid; idx < CC * IH * IW; idx += 256) {
      int ci = idx / (IH * IW);
      int rem = idx % (IH * IW);
      int r = rem / IW, c = rem % IW;
      int gy = oy0 + r, gx = ox0 + c;
      int cg = ci0 + ci;
      float v = 0.f;
      if (cg < cin && gy >= 0 && gy < HinU && gx >= 0 && gx < WinU) {
        int sy = gy >> upsample, sx = gx >> upsample;
        const float* src = (cg < c1) ? in1 + (size_t)(b * c1 + cg) * Hin * Win
                                     : in2 + (size_t)(b * c2 + (cg - c1)) * Hin * Win;
        v = src[(size_t)sy * Win + sx];
      }
      sIn[idx] = v;
    }
    for (int idx = tid; idx < CC * K * K * 32; idx += 256) {
      int mm = idx & 31;
      int t = idx >> 5;
      int ci = t / (K * K);
      int kk = t % (K * K);
      int cg = ci0 + ci, co = mBase + mm;
      float va = 0.f, vg = 0.f;
      if (cg < cin && co < coutEff) {
        size_t base = ((size_t)co * cin + cg) * (K * K) + kk;
        va = w[base];
        if (act != 2) vg = w[base + (size_t)coutEff * cin * (K * K)];
      }
      sWA[idx] = va;
      sWG[idx] = vg;
    }
    __syncthreads();
#pragma unroll
    for (int ci = 0; ci < CC; ci++) {
#pragma unroll
      for (int kh = 0; kh < K; kh++) {
        float win[WIN];
        int base = (ci * IH + (rr * STRIDE + kh)) * IW + c0 * STRIDE;
#pragma unroll
        for (int i = 0; i < WIN; i++) win[i] = sIn[base + i];
#pragma unroll
        for (int kw = 0; kw < K; kw++) {
          int wi = ((ci * K + kh) * K + kw) * 32 + 2 * ty;
          float wa0 = sWA[wi], wa1 = sWA[wi + 1];
          float wg0 = sWG[wi], wg1 = sWG[wi + 1];
#pragma unroll
          for (int i = 0; i < 8; i++) {
            float v = win[i * STRIDE + kw];
            accA[0][i] += v * wa0;
            accA[1][i] += v * wa1;
            accG[0][i] += v * wg0;
            accG[1][i] += v * wg1;
          }
        }
      }
    }
  }

  int y = tY * TH + rr;
  int xb_ = tX * TW + c0;
#pragma unroll
  for (int mi = 0; mi < 2; mi++) {
    int m = mBase + ty * 2 + mi;
    if (m >= coutEff) continue;
    float bA = bias[m];
    float bG = (act != 2) ? bias[m + coutEff] : 0.f;
    float o[8];
#pragma unroll
    for (int i = 0; i < 8; i++) {
      float a = accA[mi][i] + bA;
      if (act == 2) {
        o[i] = tanhf(a);
      } else {
        float g = accG[mi][i] + bG;
        float aa = (act == 1) ? fmaxf(a, 0.f) : (a > 0.f ? a : expm1f(a));
        o[i] = aa * (1.f / (1.f + expf(-g)));
      }
    }
    float* dst = out + (((size_t)b * coutEff + m) * Hout + y) * Wout + xb_;
    *(float4*)dst = make_float4(o[0], o[1], o[2], o[3]);
    *(float4*)(dst + 4) = make_float4(o[4], o[5], o[6], o[7]);
  }
}

// ---------------- cp1 helpers ----------------
__global__ void k_mask_s(const float* __restrict__ mask, float* __restrict__ mask_s) {
  int idx = blockIdx.x * 256 + threadIdx.x;
  if (idx >= BB * 4096) return;
  int b = idx >> 12, r = idx & 4095;
  int i = r >> 6, j = r & 63;
  float s = 0.f;
  for (int u = 0; u < 4; u++)
    for (int v = 0; v < 4; v++)
      s += mask[(size_t)b * 65536 + (i * 4 + u) * 256 + (j * 4 + v)];
  mask_s[idx] = s * (1.f / 16.f);
}

__global__ void k_mm(const float* __restrict__ mask_s, float* __restrict__ mm) {
  int idx = blockIdx.x * 256 + threadIdx.x;
  if (idx >= BB * 1024) return;
  int b = idx >> 10, l = idx & 1023;
  int li = l >> 5, lj = l & 31;
  float s = 0.f;
  for (int dy = 0; dy < 4; dy++) {
    int row = 2 * li + dy - 1;
    if (row < 0 || row >= 64) continue;
    for (int dx = 0; dx < 4; dx++) {
      int col = 2 * lj + dx - 1;
      if (col < 0 || col >= 64) continue;
      s += mask_s[((size_t)b << 12) + row * 64 + col];
    }
  }
  mm[idx] = (s == 0.f) ? 1.f : 0.f;
}

// P -> hi/lo bf16 split; P[b][l][p], p = c*16 + dy*4 + dx
__global__ void extract_patches_bf(const float* __restrict__ xsim,
                                   ushort* __restrict__ Phi, ushort* __restrict__ Plo) {
  size_t idx = (size_t)blockIdx.x * 256 + threadIdx.x;
  if (idx >= (size_t)BB * 1024 * 1536) return;
  int p = (int)(idx % 1536);
  size_t t = idx / 1536;
  int l = (int)(t % 1024);
  int b = (int)(t / 1024);
  int c = p >> 4, r = p & 15, dy = r >> 2, dx = r & 3;
  int li = l >> 5, lj = l & 31;
  int row = 2 * li + dy - 1, col = 2 * lj + dx - 1;
  float v = 0.f;
  if (row >= 0 && row < 64 && col >= 0 && col < 64)
    v = xsim[(((size_t)b * 96 + c) * 64 + row) * 64 + col];
  ushort h = f2bf(v);
  Phi[idx] = h;
  Plo[idx] = f2bf(v - bf2f(h));
}

__global__ void k_scale_bf(const ushort* __restrict__ Phi, const ushort* __restrict__ Plo,
                           const float* __restrict__ mm, float* __restrict__ scale) {
  int bl = blockIdx.x;
  const ushort* rh = Phi + (size_t)bl * 1536;
  const ushort* rl = Plo + (size_t)bl * 1536;
  int tid = threadIdx.x;
  float s = 0.f;
  for (int i = 0; i < 6; i++) {
    float v = bf2f(rh[tid + i * 256]) + bf2f(rl[tid + i * 256]);
    s += v * v;
  }
  __shared__ float red[256];
  red[tid] = s; __syncthreads();
  for (int t = 128; t > 0; t >>= 1) { if (tid < t) red[tid] += red[tid + t]; __syncthreads(); }
  if (tid == 0) scale[bl] = mm[bl] / fmaxf(sqrtf(red[0]), 1e-4f);
}

// ---------------- MFMA GEMM: S[b][q][l] = scale[l] * P[q].P[l] ----------------
__global__ __launch_bounds__(256) void gemm_qk_mfma(
    const ushort* __restrict__ Phi, const ushort* __restrict__ Plo,
    const float* __restrict__ scale, float* __restrict__ S) {
  int b = blockIdx.z;
  int qTile = blockIdx.y * 128, lTile = blockIdx.x * 128;
  __shared__ uint4 sAh[512], sAl[512], sBh[512], sBl[512];  // 128 rows x 4 x 16B

  int tid = threadIdx.x;
  int lane = tid & 63, w = tid >> 6;
  int wy = w >> 1, wx = w & 1;
  int m = lane & 15, gg = lane >> 4;

  f32x4 acc[4][4];
#pragma unroll
  for (int i = 0; i < 4; i++)
#pragma unroll
    for (int j = 0; j < 4; j++) acc[i][j] = (f32x4){0.f, 0.f, 0.f, 0.f};

  for (int k0 = 0; k0 < 1536; k0 += 32) {
    __syncthreads();
    for (int t = tid; t < 512; t += 256) {
      int r = t >> 2, g = t & 3;
      int slot = (r << 2) + (g ^ (r & 3));
      size_t aoff = ((size_t)(b * 1024 + qTile + r)) * 1536 + k0;
      size_t boff = ((size_t)(b * 1024 + lTile + r)) * 1536 + k0;
      sAh[slot] = ((const uint4*)(Phi + aoff))[g];
      sAl[slot] = ((const uint4*)(Plo + aoff))[g];
      sBh[slot] = ((const uint4*)(Phi + boff))[g];
      sBl[slot] = ((const uint4*)(Plo + boff))[g];
    }
    __syncthreads();
    bf16x8 ah[4], al[4], bh[4], bl[4];
#pragma unroll
    for (int i = 0; i < 4; i++) {
      int ra = wy * 64 + i * 16 + m;
      int rb = wx * 64 + i * 16 + m;
      int sa = (ra << 2) + (gg ^ (ra & 3));
      int sb = (rb << 2) + (gg ^ (rb & 3));
      ah[i] = as_bf(sAh[sa]);
      al[i] = as_bf(sAl[sa]);
      bh[i] = as_bf(sBh[sb]);
      bl[i] = as_bf(sBl[sb]);
    }
#pragma unroll
    for (int mi = 0; mi < 4; mi++)
#pragma unroll
      for (int ni = 0; ni < 4; ni++) {
        acc[mi][ni] = __builtin_amdgcn_mfma_f32_16x16x32_bf16(ah[mi], bh[ni], acc[mi][ni], 0, 0, 0);
        acc[mi][ni] = __builtin_amdgcn_mfma_f32_16x16x32_bf16(ah[mi], bl[ni], acc[mi][ni], 0, 0, 0);
        acc[mi][ni] = __builtin_amdgcn_mfma_f32_16x16x32_bf16(al[mi], bh[ni], acc[mi][ni], 0, 0, 0);
      }
  }

#pragma unroll
  for (int ni = 0; ni < 4; ni++) {
    int l = lTile + wx * 64 + ni * 16 + m;
    float sc = scale[b * 1024 + l];
#pragma unroll
    for (int mi = 0; mi < 4; mi++) {
      int q0 = qTile + wy * 64 + mi * 16 + gg * 4;
#pragma unroll
      for (int r = 0; r < 4; r++)
        S[((size_t)b * 1024 + q0 + r) * 1024 + l] = acc[mi][ni][r] * sc;
    }
  }
}

// softmax over l, *mm, emit hi/lo bf16 probs
__global__ void softmax_rows_bf(const float* __restrict__ S, const float* __restrict__ mm,
                                ushort* __restrict__ Shi, ushort* __restrict__ Slo) {
  int q = blockIdx.x, b = blockIdx.y;
  const float* row = S + ((size_t)b * 1024 + q) * 1024;
  int tid = threadIdx.x;
  float v[4];
  float mx = -1e30f;
  for (int i = 0; i < 4; i++) { v[i] = row[tid + i * 256]; mx = fmaxf(mx, v[i]); }
  __shared__ float red[256];
  red[tid] = mx; __syncthreads();
  for (int s = 128; s > 0; s >>= 1) { if (tid < s) red[tid] = fmaxf(red[tid], red[tid + s]); __syncthreads(); }
  mx = red[0]; __syncthreads();
  float sum = 0.f;
  for (int i = 0; i < 4; i++) { v[i] = expf(10.f * (v[i] - mx)); sum += v[i]; }
  red[tid] = sum; __syncthreads();
  for (int s = 128; s > 0; s >>= 1) { if (tid < s) red[tid] += red[tid + s]; __syncthreads(); }
  sum = red[0];
  float inv = 1.f / sum;
  for (int i = 0; i < 4; i++) {
    int l = tid + i * 256;
    float p = v[i] * inv * mm[b * 1024 + l];
    ushort h = f2bf(p);
    size_t o = ((size_t)b * 1024 + q) * 1024 + l;
    Shi[o] = h;
    Slo[o] = f2bf(p - bf2f(h));
  }
}

// ---------------- MFMA GEMM cp2: contrib[q][p] = sum_l sim[q][l]*W[l][p] ----------------
__global__ __launch_bounds__(256) void gemm_cp2_mfma(
    const ushort* __restrict__ Shi, const ushort* __restrict__ Slo,
    const float* __restrict__ xb, float* __restrict__ contrib, int b) {
  int qTile = blockIdx.y * 128, pTile = blockIdx.x * 128;
  __shared__ uint4 sAh[512], sAl[512];
  __shared__ ushort sBh[4096], sBl[4096];
  const float* xbb = xb + (size_t)b * 24 * 65536;

  int tid = threadIdx.x;
  int lane = tid & 63, w = tid >> 6;
  int wy = w >> 1, wx = w & 1;
  int m = lane & 15, gg = lane >> 4;

  f32x4 acc[4][4];
#pragma unroll
  for (int i = 0; i < 4; i++)
#pragma unroll
    for (int j = 0; j < 4; j++) acc[i][j] = (f32x4){0.f, 0.f, 0.f, 0.f};

  for (int l0 = 0; l0 < 1024; l0 += 32) {
    __syncthreads();
    for (int t = tid; t < 512; t += 256) {
      int r = t >> 2, g = t & 3;
      int slot = (r << 2) + (g ^ (r & 3));
      size_t off = ((size_t)(b * 1024 + qTile + r)) * 1024 + l0;
      sAh[slot] = ((const uint4*)(Shi + off))[g];
      sAl[slot] = ((const uint4*)(Slo + off))[g];
    }
    for (int t = tid; t < 4096; t += 256) {
      int pl = t >> 5, ll = t & 31;
      int p = pTile + pl, l = l0 + ll;
      int li = l >> 5, lj = l & 31;
      int c = p >> 8, u = (p >> 4) & 15, v = p & 15;
      int row = 8 * li + u - 4, col = 8 * lj + v - 4;
      float val = 0.f;
      if (row >= 0 && row < 256 && col >= 0 && col < 256)
        val = xbb[((size_t)c << 16) + (row << 8) + col];
      ushort h = f2bf(val);
      int idx = (pl << 5) + (((ll >> 3) ^ (pl & 3)) << 3) + (ll & 7);
      sBh[idx] = h;
      sBl[idx] = f2bf(val - bf2f(h));
    }
    __syncthreads();
    bf16x8 ah[4], al[4], bh[4], bl[4];
    const uint4* vBh = (const uint4*)sBh;
    const uint4* vBl = (const uint4*)sBl;
#pragma unroll
    for (int i = 0; i < 4; i++) {
      int ra = wy * 64 + i * 16 + m;
      int rb = wx * 64 + i * 16 + m;
      int sa = (ra << 2) + (gg ^ (ra & 3));
      int sb = (rb << 2) + (gg ^ (rb & 3));
      ah[i] = as_bf(sAh[sa]);
      al[i] = as_bf(sAl[sa]);
      bh[i] = as_bf(vBh[sb]);
      bl[i] = as_bf(vBl[sb]);
    }
#pragma unroll
    for (int mi = 0; mi < 4; mi++)
#pragma unroll
      for (int ni = 0; ni < 4; ni++) {
        acc[mi][ni] = __builtin_amdgcn_mfma_f32_16x16x32_bf16(ah[mi], bh[ni], acc[mi][ni], 0, 0, 0);
        acc[mi][ni] = __builtin_amdgcn_mfma_f32_16x16x32_bf16(ah[mi], bl[ni], acc[mi][ni], 0, 0, 0);
        acc[mi][ni] = __builtin_amdgcn_mfma_f32_16x16x32_bf16(al[mi], bh[ni], acc[mi][ni], 0, 0, 0);
      }
  }

#pragma unroll
  for (int ni = 0; ni < 4; ni++) {
    int p = pTile + wx * 64 + ni * 16 + m;
#pragma unroll
    for (int mi = 0; mi < 4; mi++) {
      int q0 = qTile + wy * 64 + mi * 16 + gg * 4;
#pragma unroll
      for (int r = 0; r < 4; r++)
        contrib[(size_t)(q0 + r) * 6144 + p] = acc[mi][ni][r];
    }
  }
}

__global__ void k_fold(const float* __restrict__ contrib, const float* __restrict__ t16,
                       const float* __restrict__ mask, float* __restrict__ out, int b) {
  int idx = blockIdx.x * 256 + threadIdx.x;
  if (idx >= 24 * 65536) return;
  int c = idx >> 16, r = idx & 65535;
  int Y = r >> 8, X = r & 255;
  int yp = Y + 4, xp = X + 4;
  int qis[2], qjs[2];
  int cy = 0, cx = 0;
  int qi1 = yp >> 3;
  if (qi1 - 1 >= 0) qis[cy++] = qi1 - 1;
  if (qi1 < 32) qis[cy++] = qi1;
  int qj1 = xp >> 3;
  if (qj1 - 1 >= 0) qjs[cx++] = qj1 - 1;
  if (qj1 < 32) qjs[cx++] = qj1;
  float sum = 0.f;
  for (int a = 0; a < cy; a++)
    for (int d = 0; d < cx; d++) {
      int qi = qis[a], qj = qjs[d];
      int u = yp - 8 * qi, v = xp - 8 * qj;
      sum += contrib[(size_t)(qi * 32 + qj) * 6144 + c * 256 + u * 16 + v];
    }
  float cnt = (float)(cy * cx);
  float o = sum / fmaxf(cnt, 1e-8f);
  float m = mask[(size_t)b * 65536 + r % 65536];
  size_t srci = (size_t)(b * 24 + c) * 65536 + r;
  out[srci] = o * m + t16[srci] * (1.f - m);
}

// ---------------- launch ----------------
extern "C" void kernel_launch(void* const* d_in, const int* in_sizes, int n_in,
                              void* d_out, int out_size, void* d_ws, size_t ws_size,
                              hipStream_t stream) {
  const float* x      = (const float*)d_in[0];
  const float* mask   = (const float*)d_in[1];
  const float* x_st1  = (const float*)d_in[2];
  const float* x_st2  = (const float*)d_in[3];
  const float* pm     = (const float*)d_in[4];
  const float* w_sconv1 = (const float*)d_in[5];  const float* b_sconv1 = (const float*)d_in[6];
  const float* w_sconv2 = (const float*)d_in[7];  const float* b_sconv2 = (const float*)d_in[8];
  const float* w_bconv1 = (const float*)d_in[9];  const float* b_bconv1 = (const float*)d_in[10];
  const float* w_bconv2 = (const float*)d_in[11]; const float* b_bconv2 = (const float*)d_in[12];
  const float* w_bconv3 = (const float*)d_in[13]; const float* b_bconv3 = (const float*)d_in[14];
  const float* w_bconv4 = (const float*)d_in[15]; const float* b_bconv4 = (const float*)d_in[16];
  const float* w_conv13 = (const float*)d_in[17]; const float* b_conv13 = (const float*)d_in[18];
  const float* w_conv14 = (const float*)d_in[19]; const float* b_conv14 = (const float*)d_in[20];
  const float* w_conv15 = (const float*)d_in[21]; const float* b_conv15 = (const float*)d_in[22];
  const float* w_conv16 = (const float*)d_in[23]; const float* b_conv16 = (const float*)d_in[24];
  const float* w_conv16_2 = (const float*)d_in[25]; const float* b_conv16_2 = (const float*)d_in[26];
  const float* w_conv17 = (const float*)d_in[27]; const float* b_conv17 = (const float*)d_in[28];
  float* out = (float*)d_out;
  float* ws = (float*)d_ws;

  // workspace layout (float offsets), sequential slot reuse
  const size_t o_xnow  = 0;         // 786432
  const size_t o_masks = 786432;    // 16384
  const size_t o_mm    = 802816;    // 4096
  const size_t o_scale = 806912;    // 4096
  const size_t o_xs    = 811008;    // 1572864
  const size_t o_xsim  = 2383872;   // 1572864
  const size_t o_Phi   = 3956736;   // 3145728 float-slots (bf16 x 6291456)
  const size_t o_Plo   = 7102464;   // 3145728
  const size_t o_S     = 10248192;  // 4194304
  const size_t o_Shi   = 14442496;  // 2097152 (bf16 x 4194304)
  const size_t o_Slo   = 16539648;  // 2097152
  const size_t o_skip1 = 18636800;  // 6291456  (later: cp2out)
  const size_t o_t2    = 24928256;  // 3145728  (later: t14)
  const size_t o_skip2 = 28073984;  // 3145728
  const size_t o_t4    = 31219712;  // 1572864
  const size_t o_t13   = 32792576;  // 3145728
  const size_t o_t16   = 35938304;  // 6291456  -> peak 42229760 floats (169 MB)
  const size_t o_t15   = 3956736;   // reuses Phi+Plo region (free after gemm_qk)
  const size_t o_contrib = 3956736; // reuses again (free after conv16... serialized)
  const size_t o_t16_2 = 3956736;   // reuses after fold loop
  (void)in_sizes; (void)n_in; (void)out_size; (void)ws_size;

  ushort* Phi = (ushort*)(ws + o_Phi);
  ushort* Plo = (ushort*)(ws + o_Plo);
  ushort* Shi = (ushort*)(ws + o_Shi);
  ushort* Slo = (ushort*)(ws + o_Slo);

  // outputs 0,1: pass-through copies
  hipMemcpyAsync(out, x_st1, (size_t)786432 * 4, hipMemcpyDeviceToDevice, stream);
  hipMemcpyAsync(out + 786432, x_st2, (size_t)786432 * 4, hipMemcpyDeviceToDevice, stream);

  k_xnow<<<3072, 256, 0, stream>>>(x, x_st2, mask, ws + o_xnow);

  // similarity branch
  conv_tile<5, 1, 4><<<dim3(32, 3, BB), 256, 0, stream>>>(
      pm, nullptr, 96, 0, w_sconv1, b_sconv1, ws + o_xs, 64, 64, 64, 64, 96, 0, 0, 4);
  conv_tile<3, 1, 8><<<dim3(32, 3, BB), 256, 0, stream>>>(
      ws + o_xs, nullptr, 96, 0, w_sconv2, b_sconv2, ws + o_xsim, 64, 64, 64, 64, 96, 1, 0, 4);
  k_mask_s<<<64, 256, 0, stream>>>(mask, ws + o_masks);
  k_mm<<<16, 256, 0, stream>>>(ws + o_masks, ws + o_mm);
  extract_patches_bf<<<24576, 256, 0, stream>>>(ws + o_xsim, Phi, Plo);
  k_scale_bf<<<4096, 256, 0, stream>>>(Phi, Plo, ws + o_mm, ws + o_scale);
  gemm_qk_mfma<<<dim3(8, 8, BB), 256, 0, stream>>>(Phi, Plo, ws + o_scale, ws + o_S);
  softmax_rows_bf<<<dim3(1024, BB), 256, 0, stream>>>(ws + o_S, ws + o_mm, Shi, Slo);

  // main branch
  conv_tile<5, 1, 4><<<dim3(512, 1, BB), 256, 0, stream>>>(
      ws + o_xnow, nullptr, 3, 0, w_bconv1, b_bconv1, ws + o_skip1, 256, 256, 256, 256, 24, 0, 0, 16);
  conv_tile<3, 2, 8><<<dim3(128, 2, BB), 256, 0, stream>>>(
      ws + o_skip1, nullptr, 24, 0, w_bconv2, b_bconv2, ws + o_t2, 256, 256, 128, 128, 48, 0, 0, 8);
  conv_tile<3, 1, 8><<<dim3(128, 2, BB), 256, 0, stream>>>(
      ws + o_t2, nullptr, 48, 0, w_bconv3, b_bconv3, ws + o_skip2, 128, 128, 128, 128, 48, 0, 0, 8);
  conv_tile<3, 2, 8><<<dim3(32, 3, BB), 256, 0, stream>>>(
      ws + o_skip2, nullptr, 48, 0, w_bconv4, b_bconv4, ws + o_t4, 128, 128, 64, 64, 96, 0, 0, 4);
  conv_tile<3, 1, 8><<<dim3(128, 2, BB), 256, 0, stream>>>(
      ws + o_t4, nullptr, 96, 0, w_conv13, b_conv13, ws + o_t13, 64, 64, 128, 128, 48, 0, 1, 8);
  conv_tile<3, 1, 8><<<dim3(128, 2, BB), 256, 0, stream>>>(
      ws + o_t13, ws + o_skip2, 48, 48, w_conv14, b_conv14, ws + o_t2, 128, 128, 128, 128, 48, 0, 0, 8);
  conv_tile<3, 1, 8><<<dim3(512, 1, BB), 256, 0, stream>>>(
      ws + o_t2, nullptr, 48, 0, w_conv15, b_conv15, ws + o_t15, 128, 128, 256, 256, 24, 0, 1, 16);
  conv_tile<3, 1, 8><<<dim3(512, 1, BB), 256, 0, stream>>>(
      ws + o_t15, ws + o_skip1, 24, 24, w_conv16, b_conv16, ws + o_t16, 256, 256, 256, 256, 24, 0, 0, 16);

  // cp2: per-batch MFMA GEMM + fold
  for (int b = 0; b < BB; b++) {
    gemm_cp2_mfma<<<dim3(48, 8), 256, 0, stream>>>(Shi, Slo, ws + o_t16, ws + o_contrib, b);
    k_fold<<<6144, 256, 0, stream>>>(ws + o_contrib, ws + o_t16, mask, ws + o_skip1, b);
  }

  // tail convs
  conv_tile<3, 1, 8><<<dim3(512, 1, BB), 256, 0, stream>>>(
      ws + o_skip1, nullptr, 24, 0, w_conv16_2, b_conv16_2, ws + o_t16_2, 256, 256, 256, 256, 24, 0, 0, 16);
  conv_tile<3, 1, 8><<<dim3(512, 1, BB), 256, 0, stream>>>(
      ws + o_t16_2, nullptr, 24, 0, w_conv17, b_conv17, out + 2 * 786432, 256, 256, 256, 256, 3, 2, 0, 16);
}

// Round 4
// 1908.129 us; speedup vs baseline: 5.9665x; 1.6157x over previous
//
#include <hip/hip_runtime.h>
#include <math.h>

#define BB 4

typedef __bf16 bf16x8 __attribute__((ext_vector_type(8)));
typedef float f32x4 __attribute__((ext_vector_type(4)));

__device__ inline ushort f2bf(float x) {
  uint u = __float_as_uint(x);
  uint r = (u + 0x7fffu + ((u >> 16) & 1u)) >> 16;
  return (ushort)r;
}
__device__ inline float bf2f(ushort h) { return __uint_as_float(((uint)h) << 16); }
__device__ inline bf16x8 as_bf(uint4 u) {
  union { uint4 u; bf16x8 b; } c;
  c.u = u;
  return c.b;
}

// ---------------- elementwise: xnow = x2*m + x*(1-m) ----------------
__global__ void k_xnow(const float* __restrict__ x, const float* __restrict__ x2,
                       const float* __restrict__ mask, float* __restrict__ xnow) {
  int idx = blockIdx.x * 256 + threadIdx.x;
  if (idx >= BB * 3 * 65536) return;
  int b = idx / (3 * 65536);
  int r = idx % 65536;
  float m = mask[b * 65536 + r];
  xnow[idx] = x2[idx] * m + x[idx] * (1.f - m);
}

// ---------------- MFMA implicit-GEMM conv ----------------
// M = output channels (gated: frag0=A half, frag1=G half of SAME 16 channels),
// N = pixels (16x16 tile, or 8x16 for stride 2), K = spatial x ci chunks.
// LDS input tile channel-last bf16 hi/lo; k-chunk of 32 = GS spatials x CC ci.
// act: 0 gated ELU, 1 gated ReLU, 2 plain tanh.
template <int K, int STRIDE, int UP, int CC, int TH, int TW, int SPAD>
__global__ __launch_bounds__(256) void conv_mfma(
    const float* __restrict__ in1, const float* __restrict__ in2,
    int c1, int c2,
    const float* __restrict__ wgt, const float* __restrict__ bias,
    float* __restrict__ outp,
    int Hin, int Win, int Hout, int Wout,
    int coutEff, int act, int tilesX) {
  constexpr int CH = CC / 8;                  // ci-subchunks of 8 per chunk
  constexpr int GS = 4 / CH;                  // spatial positions per k-chunk of 32
  constexpr int CCp = (CC == 16) ? 24 : 8;    // padded ci stride (16B-aligned, <=2-way banks)
  constexpr int IH = (TH - 1) * STRIDE + K;
  constexpr int IW = (TW - 1) * STRIDE + K;
  constexpr int NF = (TH * TW) / 64;          // N-frags per wave
  constexpr int NSC = SPAD / GS;              // k-chunks per ci-chunk

  __shared__ ushort sInH[IH * IW * CCp];
  __shared__ ushort sInL[IH * IW * CCp];
  __shared__ uint4 sWH[SPAD * CH * 32];
  __shared__ uint4 sWL[SPAD * CH * 32];

  const int tid = threadIdx.x;
  const int lane = tid & 63, wv = tid >> 6;
  const int m = lane & 15, gg = lane >> 4;
  const int b = blockIdx.z;
  const int yb = blockIdx.y;
  const int tX = blockIdx.x % tilesX, tY = blockIdx.x / tilesX;
  const int cin = c1 + c2;
  const int pad = (K - 1) / 2;
  const int HinU = Hin << UP, WinU = Win << UP;
  const int oy0 = tY * TH * STRIDE - pad;
  const int ox0 = tX * TW * STRIDE - pad;
  const int gated = (act != 2);
  const size_t HWin = (size_t)Hin * Win;

  f32x4 acc[2][NF];
#pragma unroll
  for (int i = 0; i < 2; i++)
#pragma unroll
    for (int j = 0; j < NF; j++) acc[i][j] = (f32x4){0.f, 0.f, 0.f, 0.f};

  for (int ci0 = 0; ci0 < cin; ci0 += CC) {
    __syncthreads();
    // ---- stage input tile, channel-last hi/lo bf16 ----
    for (int p = tid; p < IH * IW; p += 256) {
      int iy = p / IW, ix = p % IW;
      int gy = oy0 + iy, gx = ox0 + ix;
      bool inb = (gy >= 0 && gy < HinU && gx >= 0 && gx < WinU);
      int sy = gy >> UP, sx = gx >> UP;
      size_t poff = (size_t)sy * Win + sx;
      int base = p * CCp;
#pragma unroll
      for (int c = 0; c < CC; c += 2) {
        float v0 = 0.f, v1 = 0.f;
        int cg = ci0 + c;
        if (inb) {
          if (cg < c1) v0 = in1[(size_t)(b * c1 + cg) * HWin + poff];
          else if (cg < cin) v0 = in2[(size_t)(b * c2 + cg - c1) * HWin + poff];
          if (cg + 1 < c1) v1 = in1[(size_t)(b * c1 + cg + 1) * HWin + poff];
          else if (cg + 1 < cin) v1 = in2[(size_t)(b * c2 + cg + 1 - c1) * HWin + poff];
        }
        ushort h0 = f2bf(v0), h1 = f2bf(v1);
        ushort l0 = f2bf(v0 - bf2f(h0)), l1 = f2bf(v1 - bf2f(h1));
        *(uint*)&sInH[base + c] = (uint)h0 | ((uint)h1 << 16);
        *(uint*)&sInL[base + c] = (uint)l0 | ((uint)l1 << 16);
      }
    }
    // ---- stage weights: sW[(s*CH+h)*32 + co32] = 8 ci values ----
    for (int t = tid; t < SPAD * CH * 32; t += 256) {
      int co32 = t & 31;
      int sh = t >> 5;
      int s = sh / CH, hh = sh - s * CH;
      int fr;
      bool ok;
      if (gated) {
        int coL = yb * 16 + (co32 & 15);
        ok = coL < coutEff;
        fr = (co32 < 16) ? coL : coutEff + coL;
      } else {
        fr = yb * 32 + co32;
        ok = fr < coutEff;
      }
      ok = ok && (s < K * K);
      union { ushort u[8]; uint4 v; } th, tl;
#pragma unroll
      for (int j = 0; j < 8; j++) {
        int ci = ci0 + hh * 8 + j;
        float v = 0.f;
        if (ok && ci < cin) v = wgt[((size_t)fr * cin + ci) * (K * K) + s];
        ushort h = f2bf(v);
        th.u[j] = h;
        tl.u[j] = f2bf(v - bf2f(h));
      }
      sWH[t] = th.v;
      sWL[t] = tl.v;
    }
    __syncthreads();
    // ---- compute ----
#pragma unroll
    for (int sc = 0; sc < NSC; sc++) {
      int sg = sc * GS + gg / CH;
      int hh = gg - (gg / CH) * CH;
      int s = (sg < K * K) ? sg : 0;  // padded spatial: clamp addr (weights are 0)
      int kh = s / K, kw = s - kh * K;
      bf16x8 ah[2], al[2], bh[NF], bl[NF];
#pragma unroll
      for (int mi = 0; mi < 2; mi++) {
        int ai = (sc * 4 + gg) * 32 + mi * 16 + m;
        ah[mi] = as_bf(sWH[ai]);
        al[mi] = as_bf(sWL[ai]);
      }
#pragma unroll
      for (int ni = 0; ni < NF; ni++) {
        int pix = wv * (NF * 16) + ni * 16 + m;
        int py = pix >> 4, px = pix & 15;
        int li = ((py * STRIDE + kh) * IW + px * STRIDE + kw) * CCp + hh * 8;
        bh[ni] = as_bf(*(const uint4*)&sInH[li]);
        bl[ni] = as_bf(*(const uint4*)&sInL[li]);
      }
#pragma unroll
      for (int mi = 0; mi < 2; mi++)
#pragma unroll
        for (int ni = 0; ni < NF; ni++) {
          acc[mi][ni] = __builtin_amdgcn_mfma_f32_16x16x32_bf16(ah[mi], bh[ni], acc[mi][ni], 0, 0, 0);
          acc[mi][ni] = __builtin_amdgcn_mfma_f32_16x16x32_bf16(ah[mi], bl[ni], acc[mi][ni], 0, 0, 0);
          acc[mi][ni] = __builtin_amdgcn_mfma_f32_16x16x32_bf16(al[mi], bh[ni], acc[mi][ni], 0, 0, 0);
        }
    }
  }
  // ---- epilogue (fused gating) ----
  const size_t HWout = (size_t)Hout * Wout;
  if (gated) {
    float bA[4], bG[4];
#pragma unroll
    for (int r = 0; r < 4; r++) {
      int co = yb * 16 + gg * 4 + r;
      bA[r] = (co < coutEff) ? bias[co] : 0.f;
      bG[r] = (co < coutEff) ? bias[coutEff + co] : 0.f;
    }
#pragma unroll
    for (int ni = 0; ni < NF; ni++) {
      int pix = wv * (NF * 16) + ni * 16 + m;
      int py = pix >> 4, px = pix & 15;
      int gy = tY * TH + py, gx = tX * TW + px;
#pragma unroll
      for (int r = 0; r < 4; r++) {
        int co = yb * 16 + gg * 4 + r;
        if (co >= coutEff) continue;
        float a = acc[0][ni][r] + bA[r];
        float g = acc[1][ni][r] + bG[r];
        float aa = (act == 1) ? fmaxf(a, 0.f) : (a > 0.f ? a : expm1f(a));
        float o = aa * (1.f / (1.f + expf(-g)));
        outp[(size_t)(b * coutEff + co) * HWout + (size_t)gy * Wout + gx] = o;
      }
    }
  } else {
#pragma unroll
    for (int mi = 0; mi < 2; mi++)
#pragma unroll
      for (int ni = 0; ni < NF; ni++) {
        int pix = wv * (NF * 16) + ni * 16 + m;
        int py = pix >> 4, px = pix & 15;
        int gy = tY * TH + py, gx = tX * TW + px;
#pragma unroll
        for (int r = 0; r < 4; r++) {
          int co = yb * 32 + mi * 16 + gg * 4 + r;
          if (co >= coutEff) continue;
          float o = tanhf(acc[mi][ni][r] + bias[co]);
          outp[(size_t)(b * coutEff + co) * HWout + (size_t)gy * Wout + gx] = o;
        }
      }
  }
}

// ---------------- cp1 helpers ----------------
__global__ void k_mask_s(const float* __restrict__ mask, float* __restrict__ mask_s) {
  int idx = blockIdx.x * 256 + threadIdx.x;
  if (idx >= BB * 4096) return;
  int b = idx >> 12, r = idx & 4095;
  int i = r >> 6, j = r & 63;
  float s = 0.f;
  for (int u = 0; u < 4; u++)
    for (int v = 0; v < 4; v++)
      s += mask[(size_t)b * 65536 + (i * 4 + u) * 256 + (j * 4 + v)];
  mask_s[idx] = s * (1.f / 16.f);
}

__global__ void k_mm(const float* __restrict__ mask_s, float* __restrict__ mm) {
  int idx = blockIdx.x * 256 + threadIdx.x;
  if (idx >= BB * 1024) return;
  int b = idx >> 10, l = idx & 1023;
  int li = l >> 5, lj = l & 31;
  float s = 0.f;
  for (int dy = 0; dy < 4; dy++) {
    int row = 2 * li + dy - 1;
    if (row < 0 || row >= 64) continue;
    for (int dx = 0; dx < 4; dx++) {
      int col = 2 * lj + dx - 1;
      if (col < 0 || col >= 64) continue;
      s += mask_s[((size_t)b << 12) + row * 64 + col];
    }
  }
  mm[idx] = (s == 0.f) ? 1.f : 0.f;
}

// P -> hi/lo bf16 split; P[b][l][p], p = c*16 + dy*4 + dx
__global__ void extract_patches_bf(const float* __restrict__ xsim,
                                   ushort* __restrict__ Phi, ushort* __restrict__ Plo) {
  size_t idx = (size_t)blockIdx.x * 256 + threadIdx.x;
  if (idx >= (size_t)BB * 1024 * 1536) return;
  int p = (int)(idx % 1536);
  size_t t = idx / 1536;
  int l = (int)(t % 1024);
  int b = (int)(t / 1024);
  int c = p >> 4, r = p & 15, dy = r >> 2, dx = r & 3;
  int li = l >> 5, lj = l & 31;
  int row = 2 * li + dy - 1, col = 2 * lj + dx - 1;
  float v = 0.f;
  if (row >= 0 && row < 64 && col >= 0 && col < 64)
    v = xsim[(((size_t)b * 96 + c) * 64 + row) * 64 + col];
  ushort h = f2bf(v);
  Phi[idx] = h;
  Plo[idx] = f2bf(v - bf2f(h));
}

__global__ void k_scale_bf(const ushort* __restrict__ Phi, const ushort* __restrict__ Plo,
                           const float* __restrict__ mm, float* __restrict__ scale) {
  int bl = blockIdx.x;
  const ushort* rh = Phi + (size_t)bl * 1536;
  const ushort* rl = Plo + (size_t)bl * 1536;
  int tid = threadIdx.x;
  float s = 0.f;
  for (int i = 0; i < 6; i++) {
    float v = bf2f(rh[tid + i * 256]) + bf2f(rl[tid + i * 256]);
    s += v * v;
  }
  __shared__ float red[256];
  red[tid] = s; __syncthreads();
  for (int t = 128; t > 0; t >>= 1) { if (tid < t) red[tid] += red[tid + t]; __syncthreads(); }
  if (tid == 0) scale[bl] = mm[bl] / fmaxf(sqrtf(red[0]), 1e-4f);
}

// ---------------- MFMA GEMM: S[b][q][l] = scale[l] * P[q].P[l] ----------------
__global__ __launch_bounds__(256) void gemm_qk_mfma(
    const ushort* __restrict__ Phi, const ushort* __restrict__ Plo,
    const float* __restrict__ scale, float* __restrict__ S) {
  int b = blockIdx.z;
  int qTile = blockIdx.y * 128, lTile = blockIdx.x * 128;
  __shared__ uint4 sAh[512], sAl[512], sBh[512], sBl[512];

  int tid = threadIdx.x;
  int lane = tid & 63, w = tid >> 6;
  int wy = w >> 1, wx = w & 1;
  int m = lane & 15, gg = lane >> 4;

  f32x4 acc[4][4];
#pragma unroll
  for (int i = 0; i < 4; i++)
#pragma unroll
    for (int j = 0; j < 4; j++) acc[i][j] = (f32x4){0.f, 0.f, 0.f, 0.f};

  for (int k0 = 0; k0 < 1536; k0 += 32) {
    __syncthreads();
    for (int t = tid; t < 512; t += 256) {
      int r = t >> 2, g = t & 3;
      int slot = (r << 2) + (g ^ (r & 3));
      size_t aoff = ((size_t)(b * 1024 + qTile + r)) * 1536 + k0;
      size_t boff = ((size_t)(b * 1024 + lTile + r)) * 1536 + k0;
      sAh[slot] = ((const uint4*)(Phi + aoff))[g];
      sAl[slot] = ((const uint4*)(Plo + aoff))[g];
      sBh[slot] = ((const uint4*)(Phi + boff))[g];
      sBl[slot] = ((const uint4*)(Plo + boff))[g];
    }
    __syncthreads();
    bf16x8 ah[4], al[4], bh[4], bl[4];
#pragma unroll
    for (int i = 0; i < 4; i++) {
      int ra = wy * 64 + i * 16 + m;
      int rb = wx * 64 + i * 16 + m;
      int sa = (ra << 2) + (gg ^ (ra & 3));
      int sb = (rb << 2) + (gg ^ (rb & 3));
      ah[i] = as_bf(sAh[sa]);
      al[i] = as_bf(sAl[sa]);
      bh[i] = as_bf(sBh[sb]);
      bl[i] = as_bf(sBl[sb]);
    }
#pragma unroll
    for (int mi = 0; mi < 4; mi++)
#pragma unroll
      for (int ni = 0; ni < 4; ni++) {
        acc[mi][ni] = __builtin_amdgcn_mfma_f32_16x16x32_bf16(ah[mi], bh[ni], acc[mi][ni], 0, 0, 0);
        acc[mi][ni] = __builtin_amdgcn_mfma_f32_16x16x32_bf16(ah[mi], bl[ni], acc[mi][ni], 0, 0, 0);
        acc[mi][ni] = __builtin_amdgcn_mfma_f32_16x16x32_bf16(al[mi], bh[ni], acc[mi][ni], 0, 0, 0);
      }
  }

#pragma unroll
  for (int ni = 0; ni < 4; ni++) {
    int l = lTile + wx * 64 + ni * 16 + m;
    float sc = scale[b * 1024 + l];
#pragma unroll
    for (int mi = 0; mi < 4; mi++) {
      int q0 = qTile + wy * 64 + mi * 16 + gg * 4;
#pragma unroll
      for (int r = 0; r < 4; r++)
        S[((size_t)b * 1024 + q0 + r) * 1024 + l] = acc[mi][ni][r] * sc;
    }
  }
}

// softmax over l, *mm, emit hi/lo bf16 probs
__global__ void softmax_rows_bf(const float* __restrict__ S, const float* __restrict__ mm,
                                ushort* __restrict__ Shi, ushort* __restrict__ Slo) {
  int q = blockIdx.x, b = blockIdx.y;
  const float* row = S + ((size_t)b * 1024 + q) * 1024;
  int tid = threadIdx.x;
  float v[4];
  float mx = -1e30f;
  for (int i = 0; i < 4; i++) { v[i] = row[tid + i * 256]; mx = fmaxf(mx, v[i]); }
  __shared__ float red[256];
  red[tid] = mx; __syncthreads();
  for (int s = 128; s > 0; s >>= 1) { if (tid < s) red[tid] = fmaxf(red[tid], red[tid + s]); __syncthreads(); }
  mx = red[0]; __syncthreads();
  float sum = 0.f;
  for (int i = 0; i < 4; i++) { v[i] = expf(10.f * (v[i] - mx)); sum += v[i]; }
  red[tid] = sum; __syncthreads();
  for (int s = 128; s > 0; s >>= 1) { if (tid < s) red[tid] += red[tid + s]; __syncthreads(); }
  sum = red[0];
  float inv = 1.f / sum;
  for (int i = 0; i < 4; i++) {
    int l = tid + i * 256;
    float p = v[i] * inv * mm[b * 1024 + l];
    ushort h = f2bf(p);
    size_t o = ((size_t)b * 1024 + q) * 1024 + l;
    Shi[o] = h;
    Slo[o] = f2bf(p - bf2f(h));
  }
}

// ---------------- MFMA GEMM cp2 ----------------
__global__ __launch_bounds__(256) void gemm_cp2_mfma(
    const ushort* __restrict__ Shi, const ushort* __restrict__ Slo,
    const float* __restrict__ xb, float* __restrict__ contrib, int b) {
  int qTile = blockIdx.y * 128, pTile = blockIdx.x * 128;
  __shared__ uint4 sAh[512], sAl[512];
  __shared__ ushort sBh[4096], sBl[4096];
  const float* xbb = xb + (size_t)b * 24 * 65536;

  int tid = threadIdx.x;
  int lane = tid & 63, w = tid >> 6;
  int wy = w >> 1, wx = w & 1;
  int m = lane & 15, gg = lane >> 4;

  f32x4 acc[4][4];
#pragma unroll
  for (int i = 0; i < 4; i++)
#pragma unroll
    for (int j = 0; j < 4; j++) acc[i][j] = (f32x4){0.f, 0.f, 0.f, 0.f};

  for (int l0 = 0; l0 < 1024; l0 += 32) {
    __syncthreads();
    for (int t = tid; t < 512; t += 256) {
      int r = t >> 2, g = t & 3;
      int slot = (r << 2) + (g ^ (r & 3));
      size_t off = ((size_t)(b * 1024 + qTile + r)) * 1024 + l0;
      sAh[slot] = ((const uint4*)(Shi + off))[g];
      sAl[slot] = ((const uint4*)(Slo + off))[g];
    }
    for (int t = tid; t < 4096; t += 256) {
      int pl = t >> 5, ll = t & 31;
      int p = pTile + pl, l = l0 + ll;
      int li = l >> 5, lj = l & 31;
      int c = p >> 8, u = (p >> 4) & 15, v = p & 15;
      int row = 8 * li + u - 4, col = 8 * lj + v - 4;
      float val = 0.f;
      if (row >= 0 && row < 256 && col >= 0 && col < 256)
        val = xbb[((size_t)c << 16) + (row << 8) + col];
      ushort h = f2bf(val);
      int idx = (pl << 5) + (((ll >> 3) ^ (pl & 3)) << 3) + (ll & 7);
      sBh[idx] = h;
      sBl[idx] = f2bf(val - bf2f(h));
    }
    __syncthreads();
    bf16x8 ah[4], al[4], bh[4], bl[4];
    const uint4* vBh = (const uint4*)sBh;
    const uint4* vBl = (const uint4*)sBl;
#pragma unroll
    for (int i = 0; i < 4; i++) {
      int ra = wy * 64 + i * 16 + m;
      int rb = wx * 64 + i * 16 + m;
      int sa = (ra << 2) + (gg ^ (ra & 3));
      int sb = (rb << 2) + (gg ^ (rb & 3));
      ah[i] = as_bf(sAh[sa]);
      al[i] = as_bf(sAl[sa]);
      bh[i] = as_bf(vBh[sb]);
      bl[i] = as_bf(vBl[sb]);
    }
#pragma unroll
    for (int mi = 0; mi < 4; mi++)
#pragma unroll
      for (int ni = 0; ni < 4; ni++) {
        acc[mi][ni] = __builtin_amdgcn_mfma_f32_16x16x32_bf16(ah[mi], bh[ni], acc[mi][ni], 0, 0, 0);
        acc[mi][ni] = __builtin_amdgcn_mfma_f32_16x16x32_bf16(ah[mi], bl[ni], acc[mi][ni], 0, 0, 0);
        acc[mi][ni] = __builtin_amdgcn_mfma_f32_16x16x32_bf16(al[mi], bh[ni], acc[mi][ni], 0, 0, 0);
      }
  }

#pragma unroll
  for (int ni = 0; ni < 4; ni++) {
    int p = pTile + wx * 64 + ni * 16 + m;
#pragma unroll
    for (int mi = 0; mi < 4; mi++) {
      int q0 = qTile + wy * 64 + mi * 16 + gg * 4;
#pragma unroll
      for (int r = 0; r < 4; r++)
        contrib[(size_t)(q0 + r) * 6144 + p] = acc[mi][ni][r];
    }
  }
}

__global__ void k_fold(const float* __restrict__ contrib, const float* __restrict__ t16,
                       const float* __restrict__ mask, float* __restrict__ out, int b) {
  int idx = blockIdx.x * 256 + threadIdx.x;
  if (idx >= 24 * 65536) return;
  int c = idx >> 16, r = idx & 65535;
  int Y = r >> 8, X = r & 255;
  int yp = Y + 4, xp = X + 4;
  int qis[2], qjs[2];
  int cy = 0, cx = 0;
  int qi1 = yp >> 3;
  if (qi1 - 1 >= 0) qis[cy++] = qi1 - 1;
  if (qi1 < 32) qis[cy++] = qi1;
  int qj1 = xp >> 3;
  if (qj1 - 1 >= 0) qjs[cx++] = qj1 - 1;
  if (qj1 < 32) qjs[cx++] = qj1;
  float sum = 0.f;
  for (int a = 0; a < cy; a++)
    for (int d = 0; d < cx; d++) {
      int qi = qis[a], qj = qjs[d];
      int u = yp - 8 * qi, v = xp - 8 * qj;
      sum += contrib[(size_t)(qi * 32 + qj) * 6144 + c * 256 + u * 16 + v];
    }
  float cnt = (float)(cy * cx);
  float o = sum / fmaxf(cnt, 1e-8f);
  float m = mask[(size_t)b * 65536 + r % 65536];
  size_t srci = (size_t)(b * 24 + c) * 65536 + r;
  out[srci] = o * m + t16[srci] * (1.f - m);
}

// ---------------- launch ----------------
extern "C" void kernel_launch(void* const* d_in, const int* in_sizes, int n_in,
                              void* d_out, int out_size, void* d_ws, size_t ws_size,
                              hipStream_t stream) {
  const float* x      = (const float*)d_in[0];
  const float* mask   = (const float*)d_in[1];
  const float* x_st1  = (const float*)d_in[2];
  const float* x_st2  = (const float*)d_in[3];
  const float* pm     = (const float*)d_in[4];
  const float* w_sconv1 = (const float*)d_in[5];  const float* b_sconv1 = (const float*)d_in[6];
  const float* w_sconv2 = (const float*)d_in[7];  const float* b_sconv2 = (const float*)d_in[8];
  const float* w_bconv1 = (const float*)d_in[9];  const float* b_bconv1 = (const float*)d_in[10];
  const float* w_bconv2 = (const float*)d_in[11]; const float* b_bconv2 = (const float*)d_in[12];
  const float* w_bconv3 = (const float*)d_in[13]; const float* b_bconv3 = (const float*)d_in[14];
  const float* w_bconv4 = (const float*)d_in[15]; const float* b_bconv4 = (const float*)d_in[16];
  const float* w_conv13 = (const float*)d_in[17]; const float* b_conv13 = (const float*)d_in[18];
  const float* w_conv14 = (const float*)d_in[19]; const float* b_conv14 = (const float*)d_in[20];
  const float* w_conv15 = (const float*)d_in[21]; const float* b_conv15 = (const float*)d_in[22];
  const float* w_conv16 = (const float*)d_in[23]; const float* b_conv16 = (const float*)d_in[24];
  const float* w_conv16_2 = (const float*)d_in[25]; const float* b_conv16_2 = (const float*)d_in[26];
  const float* w_conv17 = (const float*)d_in[27]; const float* b_conv17 = (const float*)d_in[28];
  float* out = (float*)d_out;
  float* ws = (float*)d_ws;

  // workspace layout (float offsets), sequential slot reuse (same as round 3)
  const size_t o_xnow  = 0;         // 786432
  const size_t o_masks = 786432;    // 16384
  const size_t o_mm    = 802816;    // 4096
  const size_t o_scale = 806912;    // 4096
  const size_t o_xs    = 811008;    // 1572864
  const size_t o_xsim  = 2383872;   // 1572864
  const size_t o_Phi   = 3956736;   // 3145728 float-slots (bf16 x 6291456)
  const size_t o_Plo   = 7102464;   // 3145728
  const size_t o_S     = 10248192;  // 4194304
  const size_t o_Shi   = 14442496;  // 2097152 (bf16 x 4194304)
  const size_t o_Slo   = 16539648;  // 2097152
  const size_t o_skip1 = 18636800;  // 6291456  (later: cp2out)
  const size_t o_t2    = 24928256;  // 3145728  (later: t14)
  const size_t o_skip2 = 28073984;  // 3145728
  const size_t o_t4    = 31219712;  // 1572864
  const size_t o_t13   = 32792576;  // 3145728
  const size_t o_t16   = 35938304;  // 6291456
  const size_t o_t15   = 3956736;   // reuses Phi+Plo (free after gemm_qk)
  const size_t o_contrib = 3956736; // reuses again (after conv16 consumed t15)
  const size_t o_t16_2 = 3956736;   // reuses after fold loop
  (void)in_sizes; (void)n_in; (void)out_size; (void)ws_size;

  ushort* Phi = (ushort*)(ws + o_Phi);
  ushort* Plo = (ushort*)(ws + o_Plo);
  ushort* Shi = (ushort*)(ws + o_Shi);
  ushort* Slo = (ushort*)(ws + o_Slo);

  // outputs 0,1: pass-through copies
  hipMemcpyAsync(out, x_st1, (size_t)786432 * 4, hipMemcpyDeviceToDevice, stream);
  hipMemcpyAsync(out + 786432, x_st2, (size_t)786432 * 4, hipMemcpyDeviceToDevice, stream);

  k_xnow<<<3072, 256, 0, stream>>>(x, x_st2, mask, ws + o_xnow);

  // similarity branch
  conv_mfma<5, 1, 0, 8, 16, 16, 28><<<dim3(16, 6, BB), 256, 0, stream>>>(
      pm, nullptr, 96, 0, w_sconv1, b_sconv1, ws + o_xs, 64, 64, 64, 64, 96, 0, 4);
  conv_mfma<3, 1, 0, 16, 16, 16, 10><<<dim3(16, 6, BB), 256, 0, stream>>>(
      ws + o_xs, nullptr, 96, 0, w_sconv2, b_sconv2, ws + o_xsim, 64, 64, 64, 64, 96, 1, 4);
  k_mask_s<<<64, 256, 0, stream>>>(mask, ws + o_masks);
  k_mm<<<16, 256, 0, stream>>>(ws + o_masks, ws + o_mm);
  extract_patches_bf<<<24576, 256, 0, stream>>>(ws + o_xsim, Phi, Plo);
  k_scale_bf<<<4096, 256, 0, stream>>>(Phi, Plo, ws + o_mm, ws + o_scale);
  gemm_qk_mfma<<<dim3(8, 8, BB), 256, 0, stream>>>(Phi, Plo, ws + o_scale, ws + o_S);
  softmax_rows_bf<<<dim3(1024, BB), 256, 0, stream>>>(ws + o_S, ws + o_mm, Shi, Slo);

  // main branch
  conv_mfma<5, 1, 0, 8, 16, 16, 28><<<dim3(256, 2, BB), 256, 0, stream>>>(
      ws + o_xnow, nullptr, 3, 0, w_bconv1, b_bconv1, ws + o_skip1, 256, 256, 256, 256, 24, 0, 16);
  conv_mfma<3, 2, 0, 8, 8, 16, 12><<<dim3(128, 3, BB), 256, 0, stream>>>(
      ws + o_skip1, nullptr, 24, 0, w_bconv2, b_bconv2, ws + o_t2, 256, 256, 128, 128, 48, 0, 8);
  conv_mfma<3, 1, 0, 16, 16, 16, 10><<<dim3(64, 3, BB), 256, 0, stream>>>(
      ws + o_t2, nullptr, 48, 0, w_bconv3, b_bconv3, ws + o_skip2, 128, 128, 128, 128, 48, 0, 8);
  conv_mfma<3, 2, 0, 8, 8, 16, 12><<<dim3(32, 6, BB), 256, 0, stream>>>(
      ws + o_skip2, nullptr, 48, 0, w_bconv4, b_bconv4, ws + o_t4, 128, 128, 64, 64, 96, 0, 4);
  conv_mfma<3, 1, 1, 16, 16, 16, 10><<<dim3(64, 3, BB), 256, 0, stream>>>(
      ws + o_t4, nullptr, 96, 0, w_conv13, b_conv13, ws + o_t13, 64, 64, 128, 128, 48, 0, 8);
  conv_mfma<3, 1, 0, 16, 16, 16, 10><<<dim3(64, 3, BB), 256, 0, stream>>>(
      ws + o_t13, ws + o_skip2, 48, 48, w_conv14, b_conv14, ws + o_t2, 128, 128, 128, 128, 48, 0, 8);
  conv_mfma<3, 1, 1, 16, 16, 16, 10><<<dim3(256, 2, BB), 256, 0, stream>>>(
      ws + o_t2, nullptr, 48, 0, w_conv15, b_conv15, ws + o_t15, 128, 128, 256, 256, 24, 0, 16);
  conv_mfma<3, 1, 0, 16, 16, 16, 10><<<dim3(256, 2, BB), 256, 0, stream>>>(
      ws + o_t15, ws + o_skip1, 24, 24, w_conv16, b_conv16, ws + o_t16, 256, 256, 256, 256, 24, 0, 16);

  // cp2: per-batch MFMA GEMM + fold
  for (int b = 0; b < BB; b++) {
    gemm_cp2_mfma<<<dim3(48, 8), 256, 0, stream>>>(Shi, Slo, ws + o_t16, ws + o_contrib, b);
    k_fold<<<6144, 256, 0, stream>>>(ws + o_contrib, ws + o_t16, mask, ws + o_skip1, b);
  }

  // tail convs
  conv_mfma<3, 1, 0, 16, 16, 16, 10><<<dim3(256, 2, BB), 256, 0, stream>>>(
      ws + o_skip1, nullptr, 24, 0, w_conv16_2, b_conv16_2, ws + o_t16_2, 256, 256, 256, 256, 24, 0, 16);
  conv_mfma<3, 1, 0, 16, 16, 16, 10><<<dim3(256, 1, BB), 256, 0, stream>>>(
      ws + o_t16_2, nullptr, 24, 0, w_conv17, b_conv17, out + 2 * 786432, 256, 256, 256, 256, 3, 2, 16);
}

// Round 5
// 1481.526 us; speedup vs baseline: 7.6845x; 1.2879x over previous
//
#include <hip/hip_runtime.h>
#include <math.h>

#define BB 4

typedef __bf16 bf16x8 __attribute__((ext_vector_type(8)));
typedef float f32x4 __attribute__((ext_vector_type(4)));

__device__ inline ushort f2bf(float x) {
  uint u = __float_as_uint(x);
  uint r = (u + 0x7fffu + ((u >> 16) & 1u)) >> 16;
  return (ushort)r;
}
__device__ inline float bf2f(ushort h) { return __uint_as_float(((uint)h) << 16); }
__device__ inline bf16x8 as_bf(uint4 u) {
  union { uint4 u; bf16x8 b; } c;
  c.u = u;
  return c.b;
}

// ---------------- elementwise: xnow = x2*m + x*(1-m) ----------------
__global__ void k_xnow(const float* __restrict__ x, const float* __restrict__ x2,
                       const float* __restrict__ mask, float* __restrict__ xnow) {
  int idx = blockIdx.x * 256 + threadIdx.x;
  if (idx >= BB * 3 * 65536) return;
  int b = idx / (3 * 65536);
  int r = idx % 65536;
  float m = mask[b * 65536 + r];
  xnow[idx] = x2[idx] * m + x[idx] * (1.f - m);
}

// ---------------- MFMA implicit-GEMM conv (unchanged from round 4) ----------------
template <int K, int STRIDE, int UP, int CC, int TH, int TW, int SPAD>
__global__ __launch_bounds__(256) void conv_mfma(
    const float* __restrict__ in1, const float* __restrict__ in2,
    int c1, int c2,
    const float* __restrict__ wgt, const float* __restrict__ bias,
    float* __restrict__ outp,
    int Hin, int Win, int Hout, int Wout,
    int coutEff, int act, int tilesX) {
  constexpr int CH = CC / 8;
  constexpr int GS = 4 / CH;
  constexpr int CCp = (CC == 16) ? 24 : 8;
  constexpr int IH = (TH - 1) * STRIDE + K;
  constexpr int IW = (TW - 1) * STRIDE + K;
  constexpr int NF = (TH * TW) / 64;
  constexpr int NSC = SPAD / GS;

  __shared__ ushort sInH[IH * IW * CCp];
  __shared__ ushort sInL[IH * IW * CCp];
  __shared__ uint4 sWH[SPAD * CH * 32];
  __shared__ uint4 sWL[SPAD * CH * 32];

  const int tid = threadIdx.x;
  const int lane = tid & 63, wv = tid >> 6;
  const int m = lane & 15, gg = lane >> 4;
  const int b = blockIdx.z;
  const int yb = blockIdx.y;
  const int tX = blockIdx.x % tilesX, tY = blockIdx.x / tilesX;
  const int cin = c1 + c2;
  const int pad = (K - 1) / 2;
  const int HinU = Hin << UP, WinU = Win << UP;
  const int oy0 = tY * TH * STRIDE - pad;
  const int ox0 = tX * TW * STRIDE - pad;
  const int gated = (act != 2);
  const size_t HWin = (size_t)Hin * Win;

  f32x4 acc[2][NF];
#pragma unroll
  for (int i = 0; i < 2; i++)
#pragma unroll
    for (int j = 0; j < NF; j++) acc[i][j] = (f32x4){0.f, 0.f, 0.f, 0.f};

  for (int ci0 = 0; ci0 < cin; ci0 += CC) {
    __syncthreads();
    for (int p = tid; p < IH * IW; p += 256) {
      int iy = p / IW, ix = p % IW;
      int gy = oy0 + iy, gx = ox0 + ix;
      bool inb = (gy >= 0 && gy < HinU && gx >= 0 && gx < WinU);
      int sy = gy >> UP, sx = gx >> UP;
      size_t poff = (size_t)sy * Win + sx;
      int base = p * CCp;
#pragma unroll
      for (int c = 0; c < CC; c += 2) {
        float v0 = 0.f, v1 = 0.f;
        int cg = ci0 + c;
        if (inb) {
          if (cg < c1) v0 = in1[(size_t)(b * c1 + cg) * HWin + poff];
          else if (cg < cin) v0 = in2[(size_t)(b * c2 + cg - c1) * HWin + poff];
          if (cg + 1 < c1) v1 = in1[(size_t)(b * c1 + cg + 1) * HWin + poff];
          else if (cg + 1 < cin) v1 = in2[(size_t)(b * c2 + cg + 1 - c1) * HWin + poff];
        }
        ushort h0 = f2bf(v0), h1 = f2bf(v1);
        ushort l0 = f2bf(v0 - bf2f(h0)), l1 = f2bf(v1 - bf2f(h1));
        *(uint*)&sInH[base + c] = (uint)h0 | ((uint)h1 << 16);
        *(uint*)&sInL[base + c] = (uint)l0 | ((uint)l1 << 16);
      }
    }
    for (int t = tid; t < SPAD * CH * 32; t += 256) {
      int co32 = t & 31;
      int sh = t >> 5;
      int s = sh / CH, hh = sh - s * CH;
      int fr;
      bool ok;
      if (gated) {
        int coL = yb * 16 + (co32 & 15);
        ok = coL < coutEff;
        fr = (co32 < 16) ? coL : coutEff + coL;
      } else {
        fr = yb * 32 + co32;
        ok = fr < coutEff;
      }
      ok = ok && (s < K * K);
      union { ushort u[8]; uint4 v; } th, tl;
#pragma unroll
      for (int j = 0; j < 8; j++) {
        int ci = ci0 + hh * 8 + j;
        float v = 0.f;
        if (ok && ci < cin) v = wgt[((size_t)fr * cin + ci) * (K * K) + s];
        ushort h = f2bf(v);
        th.u[j] = h;
        tl.u[j] = f2bf(v - bf2f(h));
      }
      sWH[t] = th.v;
      sWL[t] = tl.v;
    }
    __syncthreads();
#pragma unroll
    for (int sc = 0; sc < NSC; sc++) {
      int sg = sc * GS + gg / CH;
      int hh = gg - (gg / CH) * CH;
      int s = (sg < K * K) ? sg : 0;
      int kh = s / K, kw = s - kh * K;
      bf16x8 ah[2], al[2], bh[NF], bl[NF];
#pragma unroll
      for (int mi = 0; mi < 2; mi++) {
        int ai = (sc * 4 + gg) * 32 + mi * 16 + m;
        ah[mi] = as_bf(sWH[ai]);
        al[mi] = as_bf(sWL[ai]);
      }
#pragma unroll
      for (int ni = 0; ni < NF; ni++) {
        int pix = wv * (NF * 16) + ni * 16 + m;
        int py = pix >> 4, px = pix & 15;
        int li = ((py * STRIDE + kh) * IW + px * STRIDE + kw) * CCp + hh * 8;
        bh[ni] = as_bf(*(const uint4*)&sInH[li]);
        bl[ni] = as_bf(*(const uint4*)&sInL[li]);
      }
#pragma unroll
      for (int mi = 0; mi < 2; mi++)
#pragma unroll
        for (int ni = 0; ni < NF; ni++) {
          acc[mi][ni] = __builtin_amdgcn_mfma_f32_16x16x32_bf16(ah[mi], bh[ni], acc[mi][ni], 0, 0, 0);
          acc[mi][ni] = __builtin_amdgcn_mfma_f32_16x16x32_bf16(ah[mi], bl[ni], acc[mi][ni], 0, 0, 0);
          acc[mi][ni] = __builtin_amdgcn_mfma_f32_16x16x32_bf16(al[mi], bh[ni], acc[mi][ni], 0, 0, 0);
        }
    }
  }
  const size_t HWout = (size_t)Hout * Wout;
  if (gated) {
    float bA[4], bG[4];
#pragma unroll
    for (int r = 0; r < 4; r++) {
      int co = yb * 16 + gg * 4 + r;
      bA[r] = (co < coutEff) ? bias[co] : 0.f;
      bG[r] = (co < coutEff) ? bias[coutEff + co] : 0.f;
    }
#pragma unroll
    for (int ni = 0; ni < NF; ni++) {
      int pix = wv * (NF * 16) + ni * 16 + m;
      int py = pix >> 4, px = pix & 15;
      int gy = tY * TH + py, gx = tX * TW + px;
#pragma unroll
      for (int r = 0; r < 4; r++) {
        int co = yb * 16 + gg * 4 + r;
        if (co >= coutEff) continue;
        float a = acc[0][ni][r] + bA[r];
        float g = acc[1][ni][r] + bG[r];
        float aa = (act == 1) ? fmaxf(a, 0.f) : (a > 0.f ? a : expm1f(a));
        float o = aa * (1.f / (1.f + expf(-g)));
        outp[(size_t)(b * coutEff + co) * HWout + (size_t)gy * Wout + gx] = o;
      }
    }
  } else {
#pragma unroll
    for (int mi = 0; mi < 2; mi++)
#pragma unroll
      for (int ni = 0; ni < NF; ni++) {
        int pix = wv * (NF * 16) + ni * 16 + m;
        int py = pix >> 4, px = pix & 15;
        int gy = tY * TH + py, gx = tX * TW + px;
#pragma unroll
        for (int r = 0; r < 4; r++) {
          int co = yb * 32 + mi * 16 + gg * 4 + r;
          if (co >= coutEff) continue;
          float o = tanhf(acc[mi][ni][r] + bias[co]);
          outp[(size_t)(b * coutEff + co) * HWout + (size_t)gy * Wout + gx] = o;
        }
      }
  }
}

// ---------------- cp1 helpers ----------------
__global__ void k_mask_s(const float* __restrict__ mask, float* __restrict__ mask_s) {
  int idx = blockIdx.x * 256 + threadIdx.x;
  if (idx >= BB * 4096) return;
  int b = idx >> 12, r = idx & 4095;
  int i = r >> 6, j = r & 63;
  float s = 0.f;
  for (int u = 0; u < 4; u++)
    for (int v = 0; v < 4; v++)
      s += mask[(size_t)b * 65536 + (i * 4 + u) * 256 + (j * 4 + v)];
  mask_s[idx] = s * (1.f / 16.f);
}

__global__ void k_mm(const float* __restrict__ mask_s, float* __restrict__ mm) {
  int idx = blockIdx.x * 256 + threadIdx.x;
  if (idx >= BB * 1024) return;
  int b = idx >> 10, l = idx & 1023;
  int li = l >> 5, lj = l & 31;
  float s = 0.f;
  for (int dy = 0; dy < 4; dy++) {
    int row = 2 * li + dy - 1;
    if (row < 0 || row >= 64) continue;
    for (int dx = 0; dx < 4; dx++) {
      int col = 2 * lj + dx - 1;
      if (col < 0 || col >= 64) continue;
      s += mask_s[((size_t)b << 12) + row * 64 + col];
    }
  }
  mm[idx] = (s == 0.f) ? 1.f : 0.f;
}

__global__ void extract_patches_bf(const float* __restrict__ xsim,
                                   ushort* __restrict__ Phi, ushort* __restrict__ Plo) {
  size_t idx = (size_t)blockIdx.x * 256 + threadIdx.x;
  if (idx >= (size_t)BB * 1024 * 1536) return;
  int p = (int)(idx % 1536);
  size_t t = idx / 1536;
  int l = (int)(t % 1024);
  int b = (int)(t / 1024);
  int c = p >> 4, r = p & 15, dy = r >> 2, dx = r & 3;
  int li = l >> 5, lj = l & 31;
  int row = 2 * li + dy - 1, col = 2 * lj + dx - 1;
  float v = 0.f;
  if (row >= 0 && row < 64 && col >= 0 && col < 64)
    v = xsim[(((size_t)b * 96 + c) * 64 + row) * 64 + col];
  ushort h = f2bf(v);
  Phi[idx] = h;
  Plo[idx] = f2bf(v - bf2f(h));
}

__global__ void k_scale_bf(const ushort* __restrict__ Phi, const ushort* __restrict__ Plo,
                           const float* __restrict__ mm, float* __restrict__ scale) {
  int bl = blockIdx.x;
  const ushort* rh = Phi + (size_t)bl * 1536;
  const ushort* rl = Plo + (size_t)bl * 1536;
  int tid = threadIdx.x;
  float s = 0.f;
  for (int i = 0; i < 6; i++) {
    float v = bf2f(rh[tid + i * 256]) + bf2f(rl[tid + i * 256]);
    s += v * v;
  }
  __shared__ float red[256];
  red[tid] = s; __syncthreads();
  for (int t = 128; t > 0; t >>= 1) { if (tid < t) red[tid] += red[tid + t]; __syncthreads(); }
  if (tid == 0) scale[bl] = mm[bl] / fmaxf(sqrtf(red[0]), 1e-4f);
}

// ---------------- MFMA GEMM: S[b][q][l] = scale[l] * P[q].P[l] ----------------
__global__ __launch_bounds__(256) void gemm_qk_mfma(
    const ushort* __restrict__ Phi, const ushort* __restrict__ Plo,
    const float* __restrict__ scale, float* __restrict__ S) {
  int b = blockIdx.z;
  int qTile = blockIdx.y * 128, lTile = blockIdx.x * 128;
  __shared__ uint4 sAh[512], sAl[512], sBh[512], sBl[512];

  int tid = threadIdx.x;
  int lane = tid & 63, w = tid >> 6;
  int wy = w >> 1, wx = w & 1;
  int m = lane & 15, gg = lane >> 4;

  f32x4 acc[4][4];
#pragma unroll
  for (int i = 0; i < 4; i++)
#pragma unroll
    for (int j = 0; j < 4; j++) acc[i][j] = (f32x4){0.f, 0.f, 0.f, 0.f};

  for (int k0 = 0; k0 < 1536; k0 += 32) {
    __syncthreads();
    for (int t = tid; t < 512; t += 256) {
      int r = t >> 2, g = t & 3;
      int slot = (r << 2) + (g ^ ((r >> 1) & 3));
      size_t aoff = ((size_t)(b * 1024 + qTile + r)) * 1536 + k0;
      size_t boff = ((size_t)(b * 1024 + lTile + r)) * 1536 + k0;
      sAh[slot] = ((const uint4*)(Phi + aoff))[g];
      sAl[slot] = ((const uint4*)(Plo + aoff))[g];
      sBh[slot] = ((const uint4*)(Phi + boff))[g];
      sBl[slot] = ((const uint4*)(Plo + boff))[g];
    }
    __syncthreads();
    bf16x8 ah[4], al[4], bh[4], bl[4];
#pragma unroll
    for (int i = 0; i < 4; i++) {
      int ra = wy * 64 + i * 16 + m;
      int rb = wx * 64 + i * 16 + m;
      int sa = (ra << 2) + (gg ^ ((ra >> 1) & 3));
      int sb = (rb << 2) + (gg ^ ((rb >> 1) & 3));
      ah[i] = as_bf(sAh[sa]);
      al[i] = as_bf(sAl[sa]);
      bh[i] = as_bf(sBh[sb]);
      bl[i] = as_bf(sBl[sb]);
    }
#pragma unroll
    for (int mi = 0; mi < 4; mi++)
#pragma unroll
      for (int ni = 0; ni < 4; ni++) {
        acc[mi][ni] = __builtin_amdgcn_mfma_f32_16x16x32_bf16(ah[mi], bh[ni], acc[mi][ni], 0, 0, 0);
        acc[mi][ni] = __builtin_amdgcn_mfma_f32_16x16x32_bf16(ah[mi], bl[ni], acc[mi][ni], 0, 0, 0);
        acc[mi][ni] = __builtin_amdgcn_mfma_f32_16x16x32_bf16(al[mi], bh[ni], acc[mi][ni], 0, 0, 0);
      }
  }

#pragma unroll
  for (int ni = 0; ni < 4; ni++) {
    int l = lTile + wx * 64 + ni * 16 + m;
    float sc = scale[b * 1024 + l];
#pragma unroll
    for (int mi = 0; mi < 4; mi++) {
      int q0 = qTile + wy * 64 + mi * 16 + gg * 4;
#pragma unroll
      for (int r = 0; r < 4; r++)
        S[((size_t)b * 1024 + q0 + r) * 1024 + l] = acc[mi][ni][r] * sc;
    }
  }
}

// softmax over l, *mm, emit hi/lo bf16 probs
__global__ void softmax_rows_bf(const float* __restrict__ S, const float* __restrict__ mm,
                                ushort* __restrict__ Shi, ushort* __restrict__ Slo) {
  int q = blockIdx.x, b = blockIdx.y;
  const float* row = S + ((size_t)b * 1024 + q) * 1024;
  int tid = threadIdx.x;
  float v[4];
  float mx = -1e30f;
  for (int i = 0; i < 4; i++) { v[i] = row[tid + i * 256]; mx = fmaxf(mx, v[i]); }
  __shared__ float red[256];
  red[tid] = mx; __syncthreads();
  for (int s = 128; s > 0; s >>= 1) { if (tid < s) red[tid] = fmaxf(red[tid], red[tid + s]); __syncthreads(); }
  mx = red[0]; __syncthreads();
  float sum = 0.f;
  for (int i = 0; i < 4; i++) { v[i] = expf(10.f * (v[i] - mx)); sum += v[i]; }
  red[tid] = sum; __syncthreads();
  for (int s = 128; s > 0; s >>= 1) { if (tid < s) red[tid] += red[tid + s]; __syncthreads(); }
  sum = red[0];
  float inv = 1.f / sum;
  for (int i = 0; i < 4; i++) {
    int l = tid + i * 256;
    float p = v[i] * inv * mm[b * 1024 + l];
    ushort h = f2bf(p);
    size_t o = ((size_t)b * 1024 + q) * 1024 + l;
    Shi[o] = h;
    Slo[o] = f2bf(p - bf2f(h));
  }
}

// ---------------- cp2: precompute W^T patches as hi/lo bf16 ----------------
// Wt[p][l], p = c*256 + u*16 + v, l = li*32 + lj; value = padded xb
__global__ void k_prepW(const float* __restrict__ xb,
                        ushort* __restrict__ Wthi, ushort* __restrict__ Wtlo, int b) {
  int idx = blockIdx.x * 256 + threadIdx.x;
  if (idx >= 6144 * 1024) return;
  int p = idx >> 10, l = idx & 1023;
  int li = l >> 5, lj = l & 31;
  int c = p >> 8, u = (p >> 4) & 15, v = p & 15;
  int row = 8 * li + u - 4, col = 8 * lj + v - 4;
  float val = 0.f;
  if (row >= 0 && row < 256 && col >= 0 && col < 256)
    val = xb[((size_t)(b * 24 + c) << 16) + (row << 8) + col];
  ushort h = f2bf(val);
  Wthi[idx] = h;
  Wtlo[idx] = f2bf(val - bf2f(h));
}

// ---------------- MFMA GEMM cp2: contrib[q][p] = sum_l sim[q][l]*Wt[p][l] ----------------
__global__ __launch_bounds__(256) void gemm_cp2_mfma(
    const ushort* __restrict__ Shi, const ushort* __restrict__ Slo,
    const ushort* __restrict__ Wthi, const ushort* __restrict__ Wtlo,
    float* __restrict__ contrib, int b) {
  int qTile = blockIdx.y * 128, pTile = blockIdx.x * 128;
  __shared__ uint4 sAh[512], sAl[512], sBh[512], sBl[512];

  int tid = threadIdx.x;
  int lane = tid & 63, w = tid >> 6;
  int wy = w >> 1, wx = w & 1;
  int m = lane & 15, gg = lane >> 4;

  f32x4 acc[4][4];
#pragma unroll
  for (int i = 0; i < 4; i++)
#pragma unroll
    for (int j = 0; j < 4; j++) acc[i][j] = (f32x4){0.f, 0.f, 0.f, 0.f};

  for (int l0 = 0; l0 < 1024; l0 += 32) {
    __syncthreads();
    for (int t = tid; t < 512; t += 256) {
      int r = t >> 2, g = t & 3;
      int slot = (r << 2) + (g ^ ((r >> 1) & 3));
      size_t aoff = ((size_t)(b * 1024 + qTile + r)) * 1024 + l0;
      size_t boff = ((size_t)(pTile + r)) * 1024 + l0;
      sAh[slot] = ((const uint4*)(Shi + aoff))[g];
      sAl[slot] = ((const uint4*)(Slo + aoff))[g];
      sBh[slot] = ((const uint4*)(Wthi + boff))[g];
      sBl[slot] = ((const uint4*)(Wtlo + boff))[g];
    }
    __syncthreads();
    bf16x8 ah[4], al[4], bh[4], bl[4];
#pragma unroll
    for (int i = 0; i < 4; i++) {
      int ra = wy * 64 + i * 16 + m;
      int rb = wx * 64 + i * 16 + m;
      int sa = (ra << 2) + (gg ^ ((ra >> 1) & 3));
      int sb = (rb << 2) + (gg ^ ((rb >> 1) & 3));
      ah[i] = as_bf(sAh[sa]);
      al[i] = as_bf(sAl[sa]);
      bh[i] = as_bf(sBh[sb]);
      bl[i] = as_bf(sBl[sb]);
    }
#pragma unroll
    for (int mi = 0; mi < 4; mi++)
#pragma unroll
      for (int ni = 0; ni < 4; ni++) {
        acc[mi][ni] = __builtin_amdgcn_mfma_f32_16x16x32_bf16(ah[mi], bh[ni], acc[mi][ni], 0, 0, 0);
        acc[mi][ni] = __builtin_amdgcn_mfma_f32_16x16x32_bf16(ah[mi], bl[ni], acc[mi][ni], 0, 0, 0);
        acc[mi][ni] = __builtin_amdgcn_mfma_f32_16x16x32_bf16(al[mi], bh[ni], acc[mi][ni], 0, 0, 0);
      }
  }

#pragma unroll
  for (int ni = 0; ni < 4; ni++) {
    int p = pTile + wx * 64 + ni * 16 + m;
#pragma unroll
    for (int mi = 0; mi < 4; mi++) {
      int q0 = qTile + wy * 64 + mi * 16 + gg * 4;
#pragma unroll
      for (int r = 0; r < 4; r++)
        contrib[(size_t)(q0 + r) * 6144 + p] = acc[mi][ni][r];
    }
  }
}

__global__ void k_fold(const float* __restrict__ contrib, const float* __restrict__ t16,
                       const float* __restrict__ mask, float* __restrict__ out, int b) {
  int idx = blockIdx.x * 256 + threadIdx.x;
  if (idx >= 24 * 65536) return;
  int c = idx >> 16, r = idx & 65535;
  int Y = r >> 8, X = r & 255;
  int yp = Y + 4, xp = X + 4;
  int qis[2], qjs[2];
  int cy = 0, cx = 0;
  int qi1 = yp >> 3;
  if (qi1 - 1 >= 0) qis[cy++] = qi1 - 1;
  if (qi1 < 32) qis[cy++] = qi1;
  int qj1 = xp >> 3;
  if (qj1 - 1 >= 0) qjs[cx++] = qj1 - 1;
  if (qj1 < 32) qjs[cx++] = qj1;
  float sum = 0.f;
  for (int a = 0; a < cy; a++)
    for (int d = 0; d < cx; d++) {
      int qi = qis[a], qj = qjs[d];
      int u = yp - 8 * qi, v = xp - 8 * qj;
      sum += contrib[(size_t)(qi * 32 + qj) * 6144 + c * 256 + u * 16 + v];
    }
  float cnt = (float)(cy * cx);
  float o = sum / fmaxf(cnt, 1e-8f);
  float m = mask[(size_t)b * 65536 + r % 65536];
  size_t srci = (size_t)(b * 24 + c) * 65536 + r;
  out[srci] = o * m + t16[srci] * (1.f - m);
}

// ---------------- launch ----------------
extern "C" void kernel_launch(void* const* d_in, const int* in_sizes, int n_in,
                              void* d_out, int out_size, void* d_ws, size_t ws_size,
                              hipStream_t stream) {
  const float* x      = (const float*)d_in[0];
  const float* mask   = (const float*)d_in[1];
  const float* x_st1  = (const float*)d_in[2];
  const float* x_st2  = (const float*)d_in[3];
  const float* pm     = (const float*)d_in[4];
  const float* w_sconv1 = (const float*)d_in[5];  const float* b_sconv1 = (const float*)d_in[6];
  const float* w_sconv2 = (const float*)d_in[7];  const float* b_sconv2 = (const float*)d_in[8];
  const float* w_bconv1 = (const float*)d_in[9];  const float* b_bconv1 = (const float*)d_in[10];
  const float* w_bconv2 = (const float*)d_in[11]; const float* b_bconv2 = (const float*)d_in[12];
  const float* w_bconv3 = (const float*)d_in[13]; const float* b_bconv3 = (const float*)d_in[14];
  const float* w_bconv4 = (const float*)d_in[15]; const float* b_bconv4 = (const float*)d_in[16];
  const float* w_conv13 = (const float*)d_in[17]; const float* b_conv13 = (const float*)d_in[18];
  const float* w_conv14 = (const float*)d_in[19]; const float* b_conv14 = (const float*)d_in[20];
  const float* w_conv15 = (const float*)d_in[21]; const float* b_conv15 = (const float*)d_in[22];
  const float* w_conv16 = (const float*)d_in[23]; const float* b_conv16 = (const float*)d_in[24];
  const float* w_conv16_2 = (const float*)d_in[25]; const float* b_conv16_2 = (const float*)d_in[26];
  const float* w_conv17 = (const float*)d_in[27]; const float* b_conv17 = (const float*)d_in[28];
  float* out = (float*)d_out;
  float* ws = (float*)d_ws;

  // workspace layout (float offsets), sequential slot reuse
  const size_t o_xnow  = 0;         // 786432
  const size_t o_masks = 786432;    // 16384
  const size_t o_mm    = 802816;    // 4096
  const size_t o_scale = 806912;    // 4096
  const size_t o_xs    = 811008;    // 1572864
  const size_t o_xsim  = 2383872;   // 1572864
  const size_t o_Phi   = 3956736;   // 3145728 float-slots (bf16 x 6291456)
  const size_t o_Plo   = 7102464;   // 3145728
  const size_t o_S     = 10248192;  // 4194304
  const size_t o_Shi   = 14442496;  // 2097152 (bf16 x 4194304)
  const size_t o_Slo   = 16539648;  // 2097152
  const size_t o_skip1 = 18636800;  // 6291456  (later: cp2out)
  const size_t o_t2    = 24928256;  // 3145728  (later: t14, then Wthi)
  const size_t o_skip2 = 28073984;  // 3145728  (later: Wtlo)
  const size_t o_t4    = 31219712;  // 1572864
  const size_t o_t13   = 32792576;  // 3145728
  const size_t o_t16   = 35938304;  // 6291456
  const size_t o_t15   = 3956736;   // reuses Phi+Plo (free after gemm_qk)
  const size_t o_contrib = 3956736; // reuses again (after conv16 consumed t15)
  const size_t o_t16_2 = 3956736;   // reuses after fold loop
  (void)in_sizes; (void)n_in; (void)out_size; (void)ws_size;

  ushort* Phi = (ushort*)(ws + o_Phi);
  ushort* Plo = (ushort*)(ws + o_Plo);
  ushort* Shi = (ushort*)(ws + o_Shi);
  ushort* Slo = (ushort*)(ws + o_Slo);
  ushort* Wthi = (ushort*)(ws + o_t2);
  ushort* Wtlo = (ushort*)(ws + o_skip2);

  // outputs 0,1: pass-through copies
  hipMemcpyAsync(out, x_st1, (size_t)786432 * 4, hipMemcpyDeviceToDevice, stream);
  hipMemcpyAsync(out + 786432, x_st2, (size_t)786432 * 4, hipMemcpyDeviceToDevice, stream);

  k_xnow<<<3072, 256, 0, stream>>>(x, x_st2, mask, ws + o_xnow);

  // similarity branch
  conv_mfma<5, 1, 0, 8, 16, 16, 28><<<dim3(16, 6, BB), 256, 0, stream>>>(
      pm, nullptr, 96, 0, w_sconv1, b_sconv1, ws + o_xs, 64, 64, 64, 64, 96, 0, 4);
  conv_mfma<3, 1, 0, 16, 16, 16, 10><<<dim3(16, 6, BB), 256, 0, stream>>>(
      ws + o_xs, nullptr, 96, 0, w_sconv2, b_sconv2, ws + o_xsim, 64, 64, 64, 64, 96, 1, 4);
  k_mask_s<<<64, 256, 0, stream>>>(mask, ws + o_masks);
  k_mm<<<16, 256, 0, stream>>>(ws + o_masks, ws + o_mm);
  extract_patches_bf<<<24576, 256, 0, stream>>>(ws + o_xsim, Phi, Plo);
  k_scale_bf<<<4096, 256, 0, stream>>>(Phi, Plo, ws + o_mm, ws + o_scale);
  gemm_qk_mfma<<<dim3(8, 8, BB), 256, 0, stream>>>(Phi, Plo, ws + o_scale, ws + o_S);
  softmax_rows_bf<<<dim3(1024, BB), 256, 0, stream>>>(ws + o_S, ws + o_mm, Shi, Slo);

  // main branch
  conv_mfma<5, 1, 0, 8, 16, 16, 28><<<dim3(256, 2, BB), 256, 0, stream>>>(
      ws + o_xnow, nullptr, 3, 0, w_bconv1, b_bconv1, ws + o_skip1, 256, 256, 256, 256, 24, 0, 16);
  conv_mfma<3, 2, 0, 8, 8, 16, 12><<<dim3(128, 3, BB), 256, 0, stream>>>(
      ws + o_skip1, nullptr, 24, 0, w_bconv2, b_bconv2, ws + o_t2, 256, 256, 128, 128, 48, 0, 8);
  conv_mfma<3, 1, 0, 16, 16, 16, 10><<<dim3(64, 3, BB), 256, 0, stream>>>(
      ws + o_t2, nullptr, 48, 0, w_bconv3, b_bconv3, ws + o_skip2, 128, 128, 128, 128, 48, 0, 8);
  conv_mfma<3, 2, 0, 8, 8, 16, 12><<<dim3(32, 6, BB), 256, 0, stream>>>(
      ws + o_skip2, nullptr, 48, 0, w_bconv4, b_bconv4, ws + o_t4, 128, 128, 64, 64, 96, 0, 4);
  conv_mfma<3, 1, 1, 16, 16, 16, 10><<<dim3(64, 3, BB), 256, 0, stream>>>(
      ws + o_t4, nullptr, 96, 0, w_conv13, b_conv13, ws + o_t13, 64, 64, 128, 128, 48, 0, 8);
  conv_mfma<3, 1, 0, 16, 16, 16, 10><<<dim3(64, 3, BB), 256, 0, stream>>>(
      ws + o_t13, ws + o_skip2, 48, 48, w_conv14, b_conv14, ws + o_t2, 128, 128, 128, 128, 48, 0, 8);
  conv_mfma<3, 1, 1, 16, 16, 16, 10><<<dim3(256, 2, BB), 256, 0, stream>>>(
      ws + o_t2, nullptr, 48, 0, w_conv15, b_conv15, ws + o_t15, 128, 128, 256, 256, 24, 0, 16);
  conv_mfma<3, 1, 0, 16, 16, 16, 10><<<dim3(256, 2, BB), 256, 0, stream>>>(
      ws + o_t15, ws + o_skip1, 24, 24, w_conv16, b_conv16, ws + o_t16, 256, 256, 256, 256, 24, 0, 16);

  // cp2: per-batch prepW + MFMA GEMM + fold
  for (int b = 0; b < BB; b++) {
    k_prepW<<<24576, 256, 0, stream>>>(ws + o_t16, Wthi, Wtlo, b);
    gemm_cp2_mfma<<<dim3(48, 8), 256, 0, stream>>>(Shi, Slo, Wthi, Wtlo, ws + o_contrib, b);
    k_fold<<<6144, 256, 0, stream>>>(ws + o_contrib, ws + o_t16, mask, ws + o_skip1, b);
  }

  // tail convs
  conv_mfma<3, 1, 0, 16, 16, 16, 10><<<dim3(256, 2, BB), 256, 0, stream>>>(
      ws + o_skip1, nullptr, 24, 0, w_conv16_2, b_conv16_2, ws + o_t16_2, 256, 256, 256, 256, 24, 0, 16);
  conv_mfma<3, 1, 0, 16, 16, 16, 10><<<dim3(256, 1, BB), 256, 0, stream>>>(
      ws + o_t16_2, nullptr, 24, 0, w_conv17, b_conv17, out + 2 * 786432, 256, 256, 256, 256, 3, 2, 16);
}

// Round 6
// 1339.004 us; speedup vs baseline: 8.5024x; 1.1064x over previous
//
#include <hip/hip_runtime.h>
#include <math.h>

#define BB 4

typedef __bf16 bf16x8 __attribute__((ext_vector_type(8)));
typedef float f32x4 __attribute__((ext_vector_type(4)));

__device__ inline ushort f2bf(float x) {
  uint u = __float_as_uint(x);
  uint r = (u + 0x7fffu + ((u >> 16) & 1u)) >> 16;
  return (ushort)r;
}
__device__ inline float bf2f(ushort h) { return __uint_as_float(((uint)h) << 16); }
__device__ inline bf16x8 as_bf(uint4 u) {
  union { uint4 u; bf16x8 b; } c;
  c.u = u;
  return c.b;
}

// ---------------- xnow -> NHWC8 bf16 hi/lo (3 real + 5 zero channels) -------
__global__ void k_xnow(const float* __restrict__ x, const float* __restrict__ x2,
                       const float* __restrict__ mask,
                       ushort* __restrict__ outH, ushort* __restrict__ outL) {
  int idx = blockIdx.x * 256 + threadIdx.x;
  if (idx >= BB * 65536) return;
  int b = idx >> 16, r = idx & 65535;
  float m = mask[idx];
  union { ushort u[8]; uint4 v; } h, l;
#pragma unroll
  for (int c = 0; c < 8; c++) { h.u[c] = 0; l.u[c] = 0; }
#pragma unroll
  for (int c = 0; c < 3; c++) {
    size_t s = ((size_t)(b * 3 + c) << 16) + r;
    float v = x2[s] * m + x[s] * (1.f - m);
    ushort hh = f2bf(v);
    h.u[c] = hh;
    l.u[c] = f2bf(v - bf2f(hh));
  }
  *(uint4*)&outH[(size_t)idx * 8] = h.v;
  *(uint4*)&outL[(size_t)idx * 8] = l.v;
}

// ---------------- pm (NCHW f32, 96ch 64x64) -> NHWC96 hi/lo ----------------
__global__ void k_tr(const float* __restrict__ pm,
                     ushort* __restrict__ outH, ushort* __restrict__ outL) {
  int idx = blockIdx.x * 256 + threadIdx.x;
  if (idx >= BB * 4096) return;
  int b = idx >> 12, pix = idx & 4095;
#pragma unroll
  for (int g = 0; g < 12; g++) {
    union { ushort u[8]; uint4 v; } h, l;
#pragma unroll
    for (int j = 0; j < 8; j++) {
      float v = pm[(((size_t)b * 96 + g * 8 + j) << 12) + pix];
      ushort hh = f2bf(v);
      h.u[j] = hh;
      l.u[j] = f2bf(v - bf2f(hh));
    }
    *(uint4*)&outH[(size_t)idx * 96 + g * 8] = h.v;
    *(uint4*)&outL[(size_t)idx * 96 + g * 8] = l.v;
  }
}

// ---------------- MFMA implicit-GEMM conv, NHWC bf16 hi/lo in & out ---------
// act: 0 gated ELU, 1 gated ReLU, 2 plain tanh -> fp32 NCHW outF.
template <int K, int STRIDE, int UP, int CC, int TH, int TW, int SPAD>
__global__ __launch_bounds__(256) void conv_mfma(
    const ushort* __restrict__ in1H, const ushort* __restrict__ in1L,
    const ushort* __restrict__ in2H, const ushort* __restrict__ in2L,
    int s1, int s2, int g1, int cinp, int cinR,
    const float* __restrict__ wgt, const float* __restrict__ bias,
    ushort* __restrict__ outH, ushort* __restrict__ outL, float* __restrict__ outF,
    int Hin, int Win, int Hout, int Wout,
    int coutEff, int coutp, int act, int tilesX) {
  constexpr int CH = CC / 8;
  constexpr int GS = 4 / CH;
  constexpr int NGc = CC / 8;
  constexpr int CCp = (CC == 16) ? 24 : 8;
  constexpr int IH = (TH - 1) * STRIDE + K;
  constexpr int IW = (TW - 1) * STRIDE + K;
  constexpr int NF = (TH * TW) / 64;
  constexpr int NSC = SPAD / GS;

  __shared__ ushort sInH[IH * IW * CCp];
  __shared__ ushort sInL[IH * IW * CCp];
  __shared__ uint4 sWH[SPAD * CH * 32];
  __shared__ uint4 sWL[SPAD * CH * 32];

  const int tid = threadIdx.x;
  const int lane = tid & 63, wv = tid >> 6;
  const int m = lane & 15, gg = lane >> 4;
  const int b = blockIdx.z;
  const int yb = blockIdx.y;
  const int tX = blockIdx.x % tilesX, tY = blockIdx.x / tilesX;
  const int pad = (K - 1) / 2;
  const int HinU = Hin << UP, WinU = Win << UP;
  const int oy0 = tY * TH * STRIDE - pad;
  const int ox0 = tX * TW * STRIDE - pad;
  const int gated = (act != 2);
  const int NG = cinp >> 3;
  const size_t HWin = (size_t)Hin * Win;

  f32x4 acc[2][NF];
#pragma unroll
  for (int i = 0; i < 2; i++)
#pragma unroll
    for (int j = 0; j < NF; j++) acc[i][j] = (f32x4){0.f, 0.f, 0.f, 0.f};

  for (int ci0 = 0; ci0 < cinp; ci0 += CC) {
    __syncthreads();
    // ---- stage input tile: pure vector copies ----
    for (int t = tid; t < IH * IW * NGc; t += 256) {
      int p = (NGc == 2) ? (t >> 1) : t;
      int g = (NGc == 2) ? (t & 1) : 0;
      int iy = p / IW, ix = p % IW;
      int gy = oy0 + iy, gx = ox0 + ix;
      int gi = (ci0 >> 3) + g;
      uint4 h = {0u, 0u, 0u, 0u}, l = {0u, 0u, 0u, 0u};
      if (gi < NG && gy >= 0 && gy < HinU && gx >= 0 && gx < WinU) {
        int sy = gy >> UP, sx = gx >> UP;
        size_t poff = (size_t)b * HWin + (size_t)sy * Win + sx;
        if (gi < g1) {
          size_t a = poff * s1 + gi * 8;
          h = *(const uint4*)&in1H[a];
          l = *(const uint4*)&in1L[a];
        } else {
          size_t a = poff * s2 + (gi - g1) * 8;
          h = *(const uint4*)&in2H[a];
          l = *(const uint4*)&in2L[a];
        }
      }
      int d = p * CCp + g * 8;
      *(uint4*)&sInH[d] = h;
      *(uint4*)&sInL[d] = l;
    }
    // ---- stage weights (fp32 -> hi/lo), small ----
    for (int t = tid; t < SPAD * CH * 32; t += 256) {
      int co32 = t & 31;
      int sh = t >> 5;
      int s = sh / CH, hh = sh - s * CH;
      int fr;
      bool ok;
      if (gated) {
        int coL = yb * 16 + (co32 & 15);
        ok = coL < coutEff;
        fr = (co32 < 16) ? coL : coutEff + coL;
      } else {
        fr = yb * 32 + co32;
        ok = fr < coutEff;
      }
      ok = ok && (s < K * K);
      union { ushort u[8]; uint4 v; } th, tl;
#pragma unroll
      for (int j = 0; j < 8; j++) {
        int ci = ci0 + hh * 8 + j;
        float v = 0.f;
        if (ok && ci < cinR) v = wgt[((size_t)fr * cinR + ci) * (K * K) + s];
        ushort h = f2bf(v);
        th.u[j] = h;
        tl.u[j] = f2bf(v - bf2f(h));
      }
      sWH[t] = th.v;
      sWL[t] = tl.v;
    }
    __syncthreads();
    // ---- compute ----
#pragma unroll
    for (int sc = 0; sc < NSC; sc++) {
      int sg = sc * GS + gg / CH;
      int hh = gg - (gg / CH) * CH;
      int s = (sg < K * K) ? sg : 0;
      int kh = s / K, kw = s - kh * K;
      bf16x8 ah[2], al[2], bh[NF], bl[NF];
#pragma unroll
      for (int mi = 0; mi < 2; mi++) {
        int ai = (sc * 4 + gg) * 32 + mi * 16 + m;
        ah[mi] = as_bf(sWH[ai]);
        al[mi] = as_bf(sWL[ai]);
      }
#pragma unroll
      for (int ni = 0; ni < NF; ni++) {
        int pix = wv * (NF * 16) + ni * 16 + m;
        int py = pix >> 4, px = pix & 15;
        int li = ((py * STRIDE + kh) * IW + px * STRIDE + kw) * CCp + hh * 8;
        bh[ni] = as_bf(*(const uint4*)&sInH[li]);
        bl[ni] = as_bf(*(const uint4*)&sInL[li]);
      }
#pragma unroll
      for (int mi = 0; mi < 2; mi++)
#pragma unroll
        for (int ni = 0; ni < NF; ni++) {
          acc[mi][ni] = __builtin_amdgcn_mfma_f32_16x16x32_bf16(ah[mi], bh[ni], acc[mi][ni], 0, 0, 0);
          acc[mi][ni] = __builtin_amdgcn_mfma_f32_16x16x32_bf16(ah[mi], bl[ni], acc[mi][ni], 0, 0, 0);
          acc[mi][ni] = __builtin_amdgcn_mfma_f32_16x16x32_bf16(al[mi], bh[ni], acc[mi][ni], 0, 0, 0);
        }
    }
  }
  // ---- epilogue ----
  const size_t HWout = (size_t)Hout * Wout;
  if (gated) {
    int co0 = yb * 16 + gg * 4;
    bool cov = co0 < coutEff;
    float bA[4], bG[4];
#pragma unroll
    for (int r = 0; r < 4; r++) {
      bA[r] = cov ? bias[co0 + r] : 0.f;
      bG[r] = cov ? bias[coutEff + co0 + r] : 0.f;
    }
#pragma unroll
    for (int ni = 0; ni < NF; ni++) {
      int pix = wv * (NF * 16) + ni * 16 + m;
      int py = pix >> 4, px = pix & 15;
      int gy = tY * TH + py, gx = tX * TW + px;
      if (!cov) continue;
      union { ushort u[4]; uint2 v; } oh, ol;
#pragma unroll
      for (int r = 0; r < 4; r++) {
        float a = acc[0][ni][r] + bA[r];
        float g = acc[1][ni][r] + bG[r];
        float aa = (act == 1) ? fmaxf(a, 0.f) : (a > 0.f ? a : expm1f(a));
        float o = aa * (1.f / (1.f + expf(-g)));
        ushort hh = f2bf(o);
        oh.u[r] = hh;
        ol.u[r] = f2bf(o - bf2f(hh));
      }
      size_t base = ((size_t)b * HWout + (size_t)gy * Wout + gx) * coutp + co0;
      *(uint2*)&outH[base] = oh.v;
      *(uint2*)&outL[base] = ol.v;
    }
  } else {
#pragma unroll
    for (int mi = 0; mi < 2; mi++)
#pragma unroll
      for (int ni = 0; ni < NF; ni++) {
        int pix = wv * (NF * 16) + ni * 16 + m;
        int py = pix >> 4, px = pix & 15;
        int gy = tY * TH + py, gx = tX * TW + px;
#pragma unroll
        for (int r = 0; r < 4; r++) {
          int co = yb * 32 + mi * 16 + gg * 4 + r;
          if (co >= coutEff) continue;
          float o = tanhf(acc[mi][ni][r] + bias[co]);
          outF[(size_t)(b * coutEff + co) * HWout + (size_t)gy * Wout + gx] = o;
        }
      }
  }
}

// ---------------- cp1 helpers ----------------
__global__ void k_mask_s(const float* __restrict__ mask, float* __restrict__ mask_s) {
  int idx = blockIdx.x * 256 + threadIdx.x;
  if (idx >= BB * 4096) return;
  int b = idx >> 12, r = idx & 4095;
  int i = r >> 6, j = r & 63;
  float s = 0.f;
  for (int u = 0; u < 4; u++)
    for (int v = 0; v < 4; v++)
      s += mask[(size_t)b * 65536 + (i * 4 + u) * 256 + (j * 4 + v)];
  mask_s[idx] = s * (1.f / 16.f);
}

__global__ void k_mm(const float* __restrict__ mask_s, float* __restrict__ mm) {
  int idx = blockIdx.x * 256 + threadIdx.x;
  if (idx >= BB * 1024) return;
  int b = idx >> 10, l = idx & 1023;
  int li = l >> 5, lj = l & 31;
  float s = 0.f;
  for (int dy = 0; dy < 4; dy++) {
    int row = 2 * li + dy - 1;
    if (row < 0 || row >= 64) continue;
    for (int dx = 0; dx < 4; dx++) {
      int col = 2 * lj + dx - 1;
      if (col < 0 || col >= 64) continue;
      s += mask_s[((size_t)b << 12) + row * 64 + col];
    }
  }
  mm[idx] = (s == 0.f) ? 1.f : 0.f;
}

// P patches from NHWC xsim; P[b][l][p], p = c*16 + dy*4 + dx
__global__ void extract_patches_bf(const ushort* __restrict__ xsH, const ushort* __restrict__ xsL,
                                   ushort* __restrict__ Phi, ushort* __restrict__ Plo) {
  size_t idx = (size_t)blockIdx.x * 256 + threadIdx.x;
  if (idx >= (size_t)BB * 1024 * 1536) return;
  int p = (int)(idx % 1536);
  size_t t = idx / 1536;
  int l = (int)(t % 1024);
  int b = (int)(t / 1024);
  int c = p >> 4, r = p & 15, dy = r >> 2, dx = r & 3;
  int li = l >> 5, lj = l & 31;
  int row = 2 * li + dy - 1, col = 2 * lj + dx - 1;
  ushort h = 0, lo = 0;
  if (row >= 0 && row < 64 && col >= 0 && col < 64) {
    size_t a = (((size_t)b << 12) + (row << 6) + col) * 96 + c;
    h = xsH[a];
    lo = xsL[a];
  }
  Phi[idx] = h;
  Plo[idx] = lo;
}

__global__ void k_scale_bf(const ushort* __restrict__ Phi, const ushort* __restrict__ Plo,
                           const float* __restrict__ mm, float* __restrict__ scale) {
  int bl = blockIdx.x;
  const ushort* rh = Phi + (size_t)bl * 1536;
  const ushort* rl = Plo + (size_t)bl * 1536;
  int tid = threadIdx.x;
  float s = 0.f;
  for (int i = 0; i < 6; i++) {
    float v = bf2f(rh[tid + i * 256]) + bf2f(rl[tid + i * 256]);
    s += v * v;
  }
  __shared__ float red[256];
  red[tid] = s; __syncthreads();
  for (int t = 128; t > 0; t >>= 1) { if (tid < t) red[tid] += red[tid + t]; __syncthreads(); }
  if (tid == 0) scale[bl] = mm[bl] / fmaxf(sqrtf(red[0]), 1e-4f);
}

// ---------------- MFMA GEMM: S[b][q][l] = scale[l] * P[q].P[l] ----------------
__global__ __launch_bounds__(256) void gemm_qk_mfma(
    const ushort* __restrict__ Phi, const ushort* __restrict__ Plo,
    const float* __restrict__ scale, float* __restrict__ S) {
  int b = blockIdx.z;
  int qTile = blockIdx.y * 128, lTile = blockIdx.x * 128;
  __shared__ uint4 sAh[512], sAl[512], sBh[512], sBl[512];

  int tid = threadIdx.x;
  int lane = tid & 63, w = tid >> 6;
  int wy = w >> 1, wx = w & 1;
  int m = lane & 15, gg = lane >> 4;

  f32x4 acc[4][4];
#pragma unroll
  for (int i = 0; i < 4; i++)
#pragma unroll
    for (int j = 0; j < 4; j++) acc[i][j] = (f32x4){0.f, 0.f, 0.f, 0.f};

  for (int k0 = 0; k0 < 1536; k0 += 32) {
    __syncthreads();
    for (int t = tid; t < 512; t += 256) {
      int r = t >> 2, g = t & 3;
      int slot = (r << 2) + (g ^ ((r >> 1) & 3));
      size_t aoff = ((size_t)(b * 1024 + qTile + r)) * 1536 + k0;
      size_t boff = ((size_t)(b * 1024 + lTile + r)) * 1536 + k0;
      sAh[slot] = ((const uint4*)(Phi + aoff))[g];
      sAl[slot] = ((const uint4*)(Plo + aoff))[g];
      sBh[slot] = ((const uint4*)(Phi + boff))[g];
      sBl[slot] = ((const uint4*)(Plo + boff))[g];
    }
    __syncthreads();
    bf16x8 ah[4], al[4], bh[4], bl[4];
#pragma unroll
    for (int i = 0; i < 4; i++) {
      int ra = wy * 64 + i * 16 + m;
      int rb = wx * 64 + i * 16 + m;
      int sa = (ra << 2) + (gg ^ ((ra >> 1) & 3));
      int sb = (rb << 2) + (gg ^ ((rb >> 1) & 3));
      ah[i] = as_bf(sAh[sa]);
      al[i] = as_bf(sAl[sa]);
      bh[i] = as_bf(sBh[sb]);
      bl[i] = as_bf(sBl[sb]);
    }
#pragma unroll
    for (int mi = 0; mi < 4; mi++)
#pragma unroll
      for (int ni = 0; ni < 4; ni++) {
        acc[mi][ni] = __builtin_amdgcn_mfma_f32_16x16x32_bf16(ah[mi], bh[ni], acc[mi][ni], 0, 0, 0);
        acc[mi][ni] = __builtin_amdgcn_mfma_f32_16x16x32_bf16(ah[mi], bl[ni], acc[mi][ni], 0, 0, 0);
        acc[mi][ni] = __builtin_amdgcn_mfma_f32_16x16x32_bf16(al[mi], bh[ni], acc[mi][ni], 0, 0, 0);
      }
  }

#pragma unroll
  for (int ni = 0; ni < 4; ni++) {
    int l = lTile + wx * 64 + ni * 16 + m;
    float sc = scale[b * 1024 + l];
#pragma unroll
    for (int mi = 0; mi < 4; mi++) {
      int q0 = qTile + wy * 64 + mi * 16 + gg * 4;
#pragma unroll
      for (int r = 0; r < 4; r++)
        S[((size_t)b * 1024 + q0 + r) * 1024 + l] = acc[mi][ni][r] * sc;
    }
  }
}

// softmax over l, *mm, emit hi/lo bf16 probs
__global__ void softmax_rows_bf(const float* __restrict__ S, const float* __restrict__ mm,
                                ushort* __restrict__ Shi, ushort* __restrict__ Slo) {
  int q = blockIdx.x, b = blockIdx.y;
  const float* row = S + ((size_t)b * 1024 + q) * 1024;
  int tid = threadIdx.x;
  float v[4];
  float mx = -1e30f;
  for (int i = 0; i < 4; i++) { v[i] = row[tid + i * 256]; mx = fmaxf(mx, v[i]); }
  __shared__ float red[256];
  red[tid] = mx; __syncthreads();
  for (int s = 128; s > 0; s >>= 1) { if (tid < s) red[tid] = fmaxf(red[tid], red[tid + s]); __syncthreads(); }
  mx = red[0]; __syncthreads();
  float sum = 0.f;
  for (int i = 0; i < 4; i++) { v[i] = expf(10.f * (v[i] - mx)); sum += v[i]; }
  red[tid] = sum; __syncthreads();
  for (int s = 128; s > 0; s >>= 1) { if (tid < s) red[tid] += red[tid + s]; __syncthreads(); }
  sum = red[0];
  float inv = 1.f / sum;
  for (int i = 0; i < 4; i++) {
    int l = tid + i * 256;
    float p = v[i] * inv * mm[b * 1024 + l];
    ushort h = f2bf(p);
    size_t o = ((size_t)b * 1024 + q) * 1024 + l;
    Shi[o] = h;
    Slo[o] = f2bf(p - bf2f(h));
  }
}

// ---------------- cp2: W^T patches from NHWC t16 (pure gather) --------------
__global__ void k_prepW(const ushort* __restrict__ t16H, const ushort* __restrict__ t16L,
                        ushort* __restrict__ Wthi, ushort* __restrict__ Wtlo, int b) {
  int idx = blockIdx.x * 256 + threadIdx.x;
  if (idx >= 6144 * 1024) return;
  int p = idx >> 10, l = idx & 1023;
  int li = l >> 5, lj = l & 31;
  int c = p >> 8, u = (p >> 4) & 15, v = p & 15;
  int row = 8 * li + u - 4, col = 8 * lj + v - 4;
  ushort h = 0, lo = 0;
  if (row >= 0 && row < 256 && col >= 0 && col < 256) {
    size_t a = ((size_t)b * 65536 + (row << 8) + col) * 24 + c;
    h = t16H[a];
    lo = t16L[a];
  }
  Wthi[idx] = h;
  Wtlo[idx] = lo;
}

// ---------------- MFMA GEMM cp2 ----------------
__global__ __launch_bounds__(256) void gemm_cp2_mfma(
    const ushort* __restrict__ Shi, const ushort* __restrict__ Slo,
    const ushort* __restrict__ Wthi, const ushort* __restrict__ Wtlo,
    float* __restrict__ contrib, int b) {
  int qTile = blockIdx.y * 128, pTile = blockIdx.x * 128;
  __shared__ uint4 sAh[512], sAl[512], sBh[512], sBl[512];

  int tid = threadIdx.x;
  int lane = tid & 63, w = tid >> 6;
  int wy = w >> 1, wx = w & 1;
  int m = lane & 15, gg = lane >> 4;

  f32x4 acc[4][4];
#pragma unroll
  for (int i = 0; i < 4; i++)
#pragma unroll
    for (int j = 0; j < 4; j++) acc[i][j] = (f32x4){0.f, 0.f, 0.f, 0.f};

  for (int l0 = 0; l0 < 1024; l0 += 32) {
    __syncthreads();
    for (int t = tid; t < 512; t += 256) {
      int r = t >> 2, g = t & 3;
      int slot = (r << 2) + (g ^ ((r >> 1) & 3));
      size_t aoff = ((size_t)(b * 1024 + qTile + r)) * 1024 + l0;
      size_t boff = ((size_t)(pTile + r)) * 1024 + l0;
      sAh[slot] = ((const uint4*)(Shi + aoff))[g];
      sAl[slot] = ((const uint4*)(Slo + aoff))[g];
      sBh[slot] = ((const uint4*)(Wthi + boff))[g];
      sBl[slot] = ((const uint4*)(Wtlo + boff))[g];
    }
    __syncthreads();
    bf16x8 ah[4], al[4], bh[4], bl[4];
#pragma unroll
    for (int i = 0; i < 4; i++) {
      int ra = wy * 64 + i * 16 + m;
      int rb = wx * 64 + i * 16 + m;
      int sa = (ra << 2) + (gg ^ ((ra >> 1) & 3));
      int sb = (rb << 2) + (gg ^ ((rb >> 1) & 3));
      ah[i] = as_bf(sAh[sa]);
      al[i] = as_bf(sAl[sa]);
      bh[i] = as_bf(sBh[sb]);
      bl[i] = as_bf(sBl[sb]);
    }
#pragma unroll
    for (int mi = 0; mi < 4; mi++)
#pragma unroll
      for (int ni = 0; ni < 4; ni++) {
        acc[mi][ni] = __builtin_amdgcn_mfma_f32_16x16x32_bf16(ah[mi], bh[ni], acc[mi][ni], 0, 0, 0);
        acc[mi][ni] = __builtin_amdgcn_mfma_f32_16x16x32_bf16(ah[mi], bl[ni], acc[mi][ni], 0, 0, 0);
        acc[mi][ni] = __builtin_amdgcn_mfma_f32_16x16x32_bf16(al[mi], bh[ni], acc[mi][ni], 0, 0, 0);
      }
  }

#pragma unroll
  for (int ni = 0; ni < 4; ni++) {
    int p = pTile + wx * 64 + ni * 16 + m;
#pragma unroll
    for (int mi = 0; mi < 4; mi++) {
      int q0 = qTile + wy * 64 + mi * 16 + gg * 4;
#pragma unroll
      for (int r = 0; r < 4; r++)
        contrib[(size_t)(q0 + r) * 6144 + p] = acc[mi][ni][r];
    }
  }
}

// fold + blend; t16 NHWC hi/lo in, cp2out NHWC hi/lo out
__global__ void k_fold(const float* __restrict__ contrib,
                       const ushort* __restrict__ t16H, const ushort* __restrict__ t16L,
                       const float* __restrict__ mask,
                       ushort* __restrict__ outH, ushort* __restrict__ outL, int b) {
  int idx = blockIdx.x * 256 + threadIdx.x;
  if (idx >= 24 * 65536) return;
  int c = idx >> 16, r = idx & 65535;
  int Y = r >> 8, X = r & 255;
  int yp = Y + 4, xp = X + 4;
  int qis[2], qjs[2];
  int cy = 0, cx = 0;
  int qi1 = yp >> 3;
  if (qi1 - 1 >= 0) qis[cy++] = qi1 - 1;
  if (qi1 < 32) qis[cy++] = qi1;
  int qj1 = xp >> 3;
  if (qj1 - 1 >= 0) qjs[cx++] = qj1 - 1;
  if (qj1 < 32) qjs[cx++] = qj1;
  float sum = 0.f;
  for (int a = 0; a < cy; a++)
    for (int d = 0; d < cx; d++) {
      int qi = qis[a], qj = qjs[d];
      int u = yp - 8 * qi, v = xp - 8 * qj;
      sum += contrib[(size_t)(qi * 32 + qj) * 6144 + c * 256 + u * 16 + v];
    }
  float cnt = (float)(cy * cx);
  float o = sum / fmaxf(cnt, 1e-8f);
  float m = mask[(size_t)b * 65536 + r];
  size_t a16 = ((size_t)b * 65536 + r) * 24 + c;
  float base = bf2f(t16H[a16]) + bf2f(t16L[a16]);
  float res = o * m + base * (1.f - m);
  ushort h = f2bf(res);
  outH[a16] = h;
  outL[a16] = f2bf(res - bf2f(h));
}

// ---------------- launch ----------------
extern "C" void kernel_launch(void* const* d_in, const int* in_sizes, int n_in,
                              void* d_out, int out_size, void* d_ws, size_t ws_size,
                              hipStream_t stream) {
  const float* x      = (const float*)d_in[0];
  const float* mask   = (const float*)d_in[1];
  const float* x_st1  = (const float*)d_in[2];
  const float* x_st2  = (const float*)d_in[3];
  const float* pm     = (const float*)d_in[4];
  const float* w_sconv1 = (const float*)d_in[5];  const float* b_sconv1 = (const float*)d_in[6];
  const float* w_sconv2 = (const float*)d_in[7];  const float* b_sconv2 = (const float*)d_in[8];
  const float* w_bconv1 = (const float*)d_in[9];  const float* b_bconv1 = (const float*)d_in[10];
  const float* w_bconv2 = (const float*)d_in[11]; const float* b_bconv2 = (const float*)d_in[12];
  const float* w_bconv3 = (const float*)d_in[13]; const float* b_bconv3 = (const float*)d_in[14];
  const float* w_bconv4 = (const float*)d_in[15]; const float* b_bconv4 = (const float*)d_in[16];
  const float* w_conv13 = (const float*)d_in[17]; const float* b_conv13 = (const float*)d_in[18];
  const float* w_conv14 = (const float*)d_in[19]; const float* b_conv14 = (const float*)d_in[20];
  const float* w_conv15 = (const float*)d_in[21]; const float* b_conv15 = (const float*)d_in[22];
  const float* w_conv16 = (const float*)d_in[23]; const float* b_conv16 = (const float*)d_in[24];
  const float* w_conv16_2 = (const float*)d_in[25]; const float* b_conv16_2 = (const float*)d_in[26];
  const float* w_conv17 = (const float*)d_in[27]; const float* b_conv17 = (const float*)d_in[28];
  float* out = (float*)d_out;
  float* ws = (float*)d_ws;
  (void)in_sizes; (void)n_in; (void)out_size; (void)ws_size;

  // workspace layout (float offsets)
  const size_t o_masks  = 0;         // 16384
  const size_t o_mm     = 16384;     // 4096
  const size_t o_scale  = 20480;     // 4096
  const size_t o_xnowH  = 24576;     // 1048576
  const size_t o_xnowL  = 1073152;   // 1048576
  const size_t o_pmH    = 2121728;   // 786432
  const size_t o_pmL    = 2908160;   // 786432
  const size_t o_xsH    = 3694592;   // 786432
  const size_t o_xsL    = 4481024;   // 786432
  const size_t o_xsimH  = 5267456;   // 786432
  const size_t o_xsimL  = 6053888;   // 786432
  const size_t o_Phi    = 6840320;   // 3145728
  const size_t o_Plo    = 9986048;   // 3145728
  const size_t o_S      = 13131776;  // 4194304
  const size_t o_Shi    = 17326080;  // 2097152
  const size_t o_Slo    = 19423232;  // 2097152
  const size_t o_skip1H = 21520384;  // 3145728
  const size_t o_skip1L = 24666112;  // 3145728
  const size_t o_t2H    = 27811840;  // 1572864
  const size_t o_t2L    = 29384704;  // 1572864
  const size_t o_skip2H = 30957568;  // 1572864
  const size_t o_skip2L = 32530432;  // 1572864
  const size_t o_t4H    = 34103296;  // 786432
  const size_t o_t4L    = 34889728;  // 786432
  const size_t o_t13H   = 35676160;  // 1572864
  const size_t o_t13L   = 37249024;  // 1572864  (peak end 38821888 fl = 155 MB)
  // reuse
  const size_t o_t14H = o_t2H, o_t14L = o_t2L;         // t2 free after bconv3
  const size_t o_t15H = o_Phi, o_t15L = o_Plo;         // free after gemm_qk
  const size_t o_t16H = o_S;                           // free after softmax
  const size_t o_t16L = o_pmH;                         // spans pm+xs (free)
  const size_t o_WtH  = o_t2H;                         // spans t2H+t2L
  const size_t o_WtL  = o_t4H;                         // spans t4+t13H
  const size_t o_contrib = o_Phi;                      // spans Phi+Plo (t15 consumed)
  const size_t o_cp2H = o_skip1H, o_cp2L = o_skip1L;   // skip1 consumed by conv16
  const size_t o_t162H = o_Phi, o_t162L = o_Plo;       // contrib free after folds

  ushort* xnowH = (ushort*)(ws + o_xnowH); ushort* xnowL = (ushort*)(ws + o_xnowL);
  ushort* pmH  = (ushort*)(ws + o_pmH);   ushort* pmL  = (ushort*)(ws + o_pmL);
  ushort* xsH  = (ushort*)(ws + o_xsH);   ushort* xsL  = (ushort*)(ws + o_xsL);
  ushort* xsimH= (ushort*)(ws + o_xsimH); ushort* xsimL= (ushort*)(ws + o_xsimL);
  ushort* Phi  = (ushort*)(ws + o_Phi);   ushort* Plo  = (ushort*)(ws + o_Plo);
  ushort* Shi  = (ushort*)(ws + o_Shi);   ushort* Slo  = (ushort*)(ws + o_Slo);
  ushort* skip1H=(ushort*)(ws + o_skip1H);ushort* skip1L=(ushort*)(ws + o_skip1L);
  ushort* t2H  = (ushort*)(ws + o_t2H);   ushort* t2L  = (ushort*)(ws + o_t2L);
  ushort* skip2H=(ushort*)(ws + o_skip2H);ushort* skip2L=(ushort*)(ws + o_skip2L);
  ushort* t4H  = (ushort*)(ws + o_t4H);   ushort* t4L  = (ushort*)(ws + o_t4L);
  ushort* t13H = (ushort*)(ws + o_t13H);  ushort* t13L = (ushort*)(ws + o_t13L);
  ushort* t14H = (ushort*)(ws + o_t14H);  ushort* t14L = (ushort*)(ws + o_t14L);
  ushort* t15H = (ushort*)(ws + o_t15H);  ushort* t15L = (ushort*)(ws + o_t15L);
  ushort* t16H = (ushort*)(ws + o_t16H);  ushort* t16L = (ushort*)(ws + o_t16L);
  ushort* WtH  = (ushort*)(ws + o_WtH);   ushort* WtL  = (ushort*)(ws + o_WtL);
  ushort* cp2H = (ushort*)(ws + o_cp2H);  ushort* cp2L = (ushort*)(ws + o_cp2L);
  ushort* t162H= (ushort*)(ws + o_t162H); ushort* t162L= (ushort*)(ws + o_t162L);

  // outputs 0,1: pass-through copies
  hipMemcpyAsync(out, x_st1, (size_t)786432 * 4, hipMemcpyDeviceToDevice, stream);
  hipMemcpyAsync(out + 786432, x_st2, (size_t)786432 * 4, hipMemcpyDeviceToDevice, stream);

  k_xnow<<<1024, 256, 0, stream>>>(x, x_st2, mask, xnowH, xnowL);
  k_tr<<<64, 256, 0, stream>>>(pm, pmH, pmL);

  // similarity branch
  conv_mfma<5, 1, 0, 8, 16, 16, 28><<<dim3(16, 6, BB), 256, 0, stream>>>(
      pmH, pmL, nullptr, nullptr, 96, 0, 12, 96, 96, w_sconv1, b_sconv1,
      xsH, xsL, nullptr, 64, 64, 64, 64, 96, 96, 0, 4);
  conv_mfma<3, 1, 0, 16, 16, 16, 10><<<dim3(16, 6, BB), 256, 0, stream>>>(
      xsH, xsL, nullptr, nullptr, 96, 0, 12, 96, 96, w_sconv2, b_sconv2,
      xsimH, xsimL, nullptr, 64, 64, 64, 64, 96, 96, 1, 4);
  k_mask_s<<<64, 256, 0, stream>>>(mask, ws + o_masks);
  k_mm<<<16, 256, 0, stream>>>(ws + o_masks, ws + o_mm);
  extract_patches_bf<<<24576, 256, 0, stream>>>(xsimH, xsimL, Phi, Plo);
  k_scale_bf<<<4096, 256, 0, stream>>>(Phi, Plo, ws + o_mm, ws + o_scale);
  gemm_qk_mfma<<<dim3(8, 8, BB), 256, 0, stream>>>(Phi, Plo, ws + o_scale, ws + o_S);
  softmax_rows_bf<<<dim3(1024, BB), 256, 0, stream>>>(ws + o_S, ws + o_mm, Shi, Slo);

  // main branch
  conv_mfma<5, 1, 0, 8, 16, 16, 28><<<dim3(256, 2, BB), 256, 0, stream>>>(
      xnowH, xnowL, nullptr, nullptr, 8, 0, 1, 8, 3, w_bconv1, b_bconv1,
      skip1H, skip1L, nullptr, 256, 256, 256, 256, 24, 24, 0, 16);
  conv_mfma<3, 2, 0, 8, 8, 16, 12><<<dim3(128, 3, BB), 256, 0, stream>>>(
      skip1H, skip1L, nullptr, nullptr, 24, 0, 3, 24, 24, w_bconv2, b_bconv2,
      t2H, t2L, nullptr, 256, 256, 128, 128, 48, 48, 0, 8);
  conv_mfma<3, 1, 0, 16, 16, 16, 10><<<dim3(64, 3, BB), 256, 0, stream>>>(
      t2H, t2L, nullptr, nullptr, 48, 0, 6, 48, 48, w_bconv3, b_bconv3,
      skip2H, skip2L, nullptr, 128, 128, 128, 128, 48, 48, 0, 8);
  conv_mfma<3, 2, 0, 8, 8, 16, 12><<<dim3(32, 6, BB), 256, 0, stream>>>(
      skip2H, skip2L, nullptr, nullptr, 48, 0, 6, 48, 48, w_bconv4, b_bconv4,
      t4H, t4L, nullptr, 128, 128, 64, 64, 96, 96, 0, 4);
  conv_mfma<3, 1, 1, 16, 16, 16, 10><<<dim3(64, 3, BB), 256, 0, stream>>>(
      t4H, t4L, nullptr, nullptr, 96, 0, 12, 96, 96, w_conv13, b_conv13,
      t13H, t13L, nullptr, 64, 64, 128, 128, 48, 48, 0, 8);
  conv_mfma<3, 1, 0, 16, 16, 16, 10><<<dim3(64, 3, BB), 256, 0, stream>>>(
      t13H, t13L, skip2H, skip2L, 48, 48, 6, 96, 96, w_conv14, b_conv14,
      t14H, t14L, nullptr, 128, 128, 128, 128, 48, 48, 0, 8);
  conv_mfma<3, 1, 1, 16, 16, 16, 10><<<dim3(256, 2, BB), 256, 0, stream>>>(
      t14H, t14L, nullptr, nullptr, 48, 0, 6, 48, 48, w_conv15, b_conv15,
      t15H, t15L, nullptr, 128, 128, 256, 256, 24, 24, 0, 16);
  conv_mfma<3, 1, 0, 16, 16, 16, 10><<<dim3(256, 2, BB), 256, 0, stream>>>(
      t15H, t15L, skip1H, skip1L, 24, 24, 3, 48, 48, w_conv16, b_conv16,
      t16H, t16L, nullptr, 256, 256, 256, 256, 24, 24, 0, 16);

  // cp2: per-batch prepW + MFMA GEMM + fold
  for (int b = 0; b < BB; b++) {
    k_prepW<<<24576, 256, 0, stream>>>(t16H, t16L, WtH, WtL, b);
    gemm_cp2_mfma<<<dim3(48, 8), 256, 0, stream>>>(Shi, Slo, WtH, WtL, ws + o_contrib, b);
    k_fold<<<6144, 256, 0, stream>>>(ws + o_contrib, t16H, t16L, mask, cp2H, cp2L, b);
  }

  // tail convs (cinp=24 -> CC=8 variant)
  conv_mfma<3, 1, 0, 8, 16, 16, 12><<<dim3(256, 2, BB), 256, 0, stream>>>(
      cp2H, cp2L, nullptr, nullptr, 24, 0, 3, 24, 24, w_conv16_2, b_conv16_2,
      t162H, t162L, nullptr, 256, 256, 256, 256, 24, 24, 0, 16);
  conv_mfma<3, 1, 0, 8, 16, 16, 12><<<dim3(256, 1, BB), 256, 0, stream>>>(
      t162H, t162L, nullptr, nullptr, 24, 0, 3, 24, 24, w_conv17, b_conv17,
      nullptr, nullptr, out + 2 * 786432, 256, 256, 256, 256, 3, 24, 2, 16);
}

// Round 7
// 1008.767 us; speedup vs baseline: 11.2859x; 1.3274x over previous
//
#include <hip/hip_runtime.h>
#include <math.h>

#define BB 4

typedef __bf16 bf16x8 __attribute__((ext_vector_type(8)));
typedef float f32x4 __attribute__((ext_vector_type(4)));

__device__ inline ushort f2bf(float x) {
  uint u = __float_as_uint(x);
  uint r = (u + 0x7fffu + ((u >> 16) & 1u)) >> 16;
  return (ushort)r;
}
__device__ inline float bf2f(ushort h) { return __uint_as_float(((uint)h) << 16); }
__device__ inline bf16x8 as_bf(uint4 u) {
  union { uint4 u; bf16x8 b; } c;
  c.u = u;
  return c.b;
}

// ---------------- weight pre-pack: all layers -> hi/lo uint4 in conv-LDS layout
struct WPtrs { const float* w[12]; };

#define WTOTAL 146560

__global__ void prep_w_all(WPtrs wp, uint4* __restrict__ wbH, uint4* __restrict__ wbL) {
  const int tK[12]    = {5,3,5,3,3,3,3,3,3,3,3,3};
  const int tCC[12]   = {8,16,8,8,16,8,16,16,16,16,8,8};
  const int tSP[12]   = {28,10,28,12,10,12,10,10,10,10,12,12};
  const int tcinR[12] = {96,96,3,24,48,48,96,96,48,48,24,24};
  const int tcinp[12] = {96,96,8,24,48,48,96,96,48,48,24,24};
  const int tcout[12] = {96,96,24,48,48,96,48,48,24,24,24,3};
  const int tgat[12]  = {1,1,1,1,1,1,1,1,1,1,1,0};
  const int toff[13]  = {0,64512,87552,89344,92800,98560,112384,123904,135424,139264,143104,145408,146560};
  for (int i = blockIdx.x * 256 + threadIdx.x; i < WTOTAL; i += gridDim.x * 256) {
    int L = 0;
    while (toff[L + 1] <= i) L++;
    int li = i - toff[L];
    int K = tK[L], CC = tCC[L], SPAD = tSP[L];
    int CH = CC >> 3;
    int SZ = SPAD * CH * 32;
    int nch = tcinp[L] / CC;
    int yb = li / (nch * SZ);
    int rem = li - yb * nch * SZ;
    int chunk = rem / SZ;
    int t = rem - chunk * SZ;
    int ci0 = chunk * CC;
    int co32 = t & 31, sh = t >> 5;
    int s = sh / CH, hh = sh - s * CH;
    int fr;
    bool ok;
    if (tgat[L]) {
      int coL = yb * 16 + (co32 & 15);
      ok = coL < tcout[L];
      fr = (co32 < 16) ? coL : tcout[L] + coL;
    } else {
      fr = yb * 32 + co32;
      ok = fr < tcout[L];
    }
    ok = ok && (s < K * K);
    const float* wgt = wp.w[L];
    union { ushort u[8]; uint4 v; } th, tl;
#pragma unroll
    for (int j = 0; j < 8; j++) {
      int ci = ci0 + hh * 8 + j;
      float v = 0.f;
      if (ok && ci < tcinR[L]) v = wgt[((size_t)fr * tcinR[L] + ci) * (K * K) + s];
      ushort h = f2bf(v);
      th.u[j] = h;
      tl.u[j] = f2bf(v - bf2f(h));
    }
    wbH[i] = th.v;
    wbL[i] = tl.v;
  }
}

// ---------------- xnow -> NHWC8 bf16 hi/lo (3 real + 5 zero channels) -------
__global__ void k_xnow(const float* __restrict__ x, const float* __restrict__ x2,
                       const float* __restrict__ mask,
                       ushort* __restrict__ outH, ushort* __restrict__ outL) {
  int idx = blockIdx.x * 256 + threadIdx.x;
  if (idx >= BB * 65536) return;
  int b = idx >> 16, r = idx & 65535;
  float m = mask[idx];
  union { ushort u[8]; uint4 v; } h, l;
#pragma unroll
  for (int c = 0; c < 8; c++) { h.u[c] = 0; l.u[c] = 0; }
#pragma unroll
  for (int c = 0; c < 3; c++) {
    size_t s = ((size_t)(b * 3 + c) << 16) + r;
    float v = x2[s] * m + x[s] * (1.f - m);
    ushort hh = f2bf(v);
    h.u[c] = hh;
    l.u[c] = f2bf(v - bf2f(hh));
  }
  *(uint4*)&outH[(size_t)idx * 8] = h.v;
  *(uint4*)&outL[(size_t)idx * 8] = l.v;
}

// ---------------- pm (NCHW f32, 96ch 64x64) -> NHWC96 hi/lo ----------------
__global__ void k_tr(const float* __restrict__ pm,
                     ushort* __restrict__ outH, ushort* __restrict__ outL) {
  int idx = blockIdx.x * 256 + threadIdx.x;
  if (idx >= BB * 4096) return;
  int b = idx >> 12, pix = idx & 4095;
#pragma unroll
  for (int g = 0; g < 12; g++) {
    union { ushort u[8]; uint4 v; } h, l;
#pragma unroll
    for (int j = 0; j < 8; j++) {
      float v = pm[(((size_t)b * 96 + g * 8 + j) << 12) + pix];
      ushort hh = f2bf(v);
      h.u[j] = hh;
      l.u[j] = f2bf(v - bf2f(hh));
    }
    *(uint4*)&outH[(size_t)idx * 96 + g * 8] = h.v;
    *(uint4*)&outL[(size_t)idx * 96 + g * 8] = l.v;
  }
}

// ---------------- MFMA implicit-GEMM conv, NHWC hi/lo, pre-packed weights ---
template <int K, int STRIDE, int UP, int CC, int TH, int TW, int SPAD>
__global__ __launch_bounds__(256) void conv_mfma(
    const ushort* __restrict__ in1H, const ushort* __restrict__ in1L,
    const ushort* __restrict__ in2H, const ushort* __restrict__ in2L,
    int s1, int s2, int g1, int cinp,
    const uint4* __restrict__ wbH, const uint4* __restrict__ wbL,
    const float* __restrict__ bias,
    ushort* __restrict__ outH, ushort* __restrict__ outL, float* __restrict__ outF,
    int Hin, int Win, int Hout, int Wout,
    int coutEff, int coutp, int act, int tilesX) {
  constexpr int CH = CC / 8;
  constexpr int GS = 4 / CH;
  constexpr int NGc = CC / 8;
  constexpr int CCp = (CC == 16) ? 24 : 8;
  constexpr int IH = (TH - 1) * STRIDE + K;
  constexpr int IW = (TW - 1) * STRIDE + K;
  constexpr int NF = (TH * TW) / 64;
  constexpr int NSC = SPAD / GS;
  constexpr int WSZ = SPAD * CH * 32;

  __shared__ ushort sInH[IH * IW * CCp];
  __shared__ ushort sInL[IH * IW * CCp];
  __shared__ uint4 sWH[WSZ];
  __shared__ uint4 sWL[WSZ];

  const int tid = threadIdx.x;
  const int lane = tid & 63, wv = tid >> 6;
  const int m = lane & 15, gg = lane >> 4;
  const int b = blockIdx.z;
  const int yb = blockIdx.y;
  const int tX = blockIdx.x % tilesX, tY = blockIdx.x / tilesX;
  const int pad = (K - 1) / 2;
  const int HinU = Hin << UP, WinU = Win << UP;
  const int oy0 = tY * TH * STRIDE - pad;
  const int ox0 = tX * TW * STRIDE - pad;
  const int gated = (act != 2);
  const int NG = cinp >> 3;
  const int nch = cinp / CC;
  const size_t HWin = (size_t)Hin * Win;

  f32x4 acc[2][NF];
#pragma unroll
  for (int i = 0; i < 2; i++)
#pragma unroll
    for (int j = 0; j < NF; j++) acc[i][j] = (f32x4){0.f, 0.f, 0.f, 0.f};

  for (int ci0 = 0; ci0 < cinp; ci0 += CC) {
    __syncthreads();
    // ---- stage input tile: pure vector copies ----
    for (int t = tid; t < IH * IW * NGc; t += 256) {
      int p = (NGc == 2) ? (t >> 1) : t;
      int g = (NGc == 2) ? (t & 1) : 0;
      int iy = p / IW, ix = p % IW;
      int gy = oy0 + iy, gx = ox0 + ix;
      int gi = (ci0 >> 3) + g;
      uint4 h = {0u, 0u, 0u, 0u}, l = {0u, 0u, 0u, 0u};
      if (gi < NG && gy >= 0 && gy < HinU && gx >= 0 && gx < WinU) {
        int sy = gy >> UP, sx = gx >> UP;
        size_t poff = (size_t)b * HWin + (size_t)sy * Win + sx;
        if (gi < g1) {
          size_t a = poff * s1 + gi * 8;
          h = *(const uint4*)&in1H[a];
          l = *(const uint4*)&in1L[a];
        } else {
          size_t a = poff * s2 + (gi - g1) * 8;
          h = *(const uint4*)&in2H[a];
          l = *(const uint4*)&in2L[a];
        }
      }
      int d = p * CCp + g * 8;
      *(uint4*)&sInH[d] = h;
      *(uint4*)&sInL[d] = l;
    }
    // ---- stage weights: coalesced copy from pre-packed buffer ----
    {
      const uint4* pH = wbH + ((size_t)yb * nch + (ci0 / CC)) * WSZ;
      const uint4* pL = wbL + ((size_t)yb * nch + (ci0 / CC)) * WSZ;
      for (int t = tid; t < WSZ; t += 256) {
        sWH[t] = pH[t];
        sWL[t] = pL[t];
      }
    }
    __syncthreads();
    // ---- compute ----
#pragma unroll
    for (int sc = 0; sc < NSC; sc++) {
      int sg = sc * GS + gg / CH;
      int hh = gg - (gg / CH) * CH;
      int s = (sg < K * K) ? sg : 0;
      int kh = s / K, kw = s - kh * K;
      bf16x8 ah[2], al[2], bh[NF], bl[NF];
#pragma unroll
      for (int mi = 0; mi < 2; mi++) {
        int ai = (sc * 4 + gg) * 32 + mi * 16 + m;
        ah[mi] = as_bf(sWH[ai]);
        al[mi] = as_bf(sWL[ai]);
      }
#pragma unroll
      for (int ni = 0; ni < NF; ni++) {
        int pix = wv * (NF * 16) + ni * 16 + m;
        int py = pix >> 4, px = pix & 15;
        int li = ((py * STRIDE + kh) * IW + px * STRIDE + kw) * CCp + hh * 8;
        bh[ni] = as_bf(*(const uint4*)&sInH[li]);
        bl[ni] = as_bf(*(const uint4*)&sInL[li]);
      }
#pragma unroll
      for (int mi = 0; mi < 2; mi++)
#pragma unroll
        for (int ni = 0; ni < NF; ni++) {
          acc[mi][ni] = __builtin_amdgcn_mfma_f32_16x16x32_bf16(ah[mi], bh[ni], acc[mi][ni], 0, 0, 0);
          acc[mi][ni] = __builtin_amdgcn_mfma_f32_16x16x32_bf16(ah[mi], bl[ni], acc[mi][ni], 0, 0, 0);
          acc[mi][ni] = __builtin_amdgcn_mfma_f32_16x16x32_bf16(al[mi], bh[ni], acc[mi][ni], 0, 0, 0);
        }
    }
  }
  // ---- epilogue ----
  const size_t HWout = (size_t)Hout * Wout;
  if (gated) {
    int co0 = yb * 16 + gg * 4;
    bool cov = co0 < coutEff;
    float bA[4], bG[4];
#pragma unroll
    for (int r = 0; r < 4; r++) {
      bA[r] = cov ? bias[co0 + r] : 0.f;
      bG[r] = cov ? bias[coutEff + co0 + r] : 0.f;
    }
#pragma unroll
    for (int ni = 0; ni < NF; ni++) {
      int pix = wv * (NF * 16) + ni * 16 + m;
      int py = pix >> 4, px = pix & 15;
      int gy = tY * TH + py, gx = tX * TW + px;
      if (!cov) continue;
      union { ushort u[4]; uint2 v; } oh, ol;
#pragma unroll
      for (int r = 0; r < 4; r++) {
        float a = acc[0][ni][r] + bA[r];
        float g = acc[1][ni][r] + bG[r];
        float aa = (act == 1) ? fmaxf(a, 0.f) : (a > 0.f ? a : expm1f(a));
        float o = aa * (1.f / (1.f + expf(-g)));
        ushort hh = f2bf(o);
        oh.u[r] = hh;
        ol.u[r] = f2bf(o - bf2f(hh));
      }
      size_t base = ((size_t)b * HWout + (size_t)gy * Wout + gx) * coutp + co0;
      *(uint2*)&outH[base] = oh.v;
      *(uint2*)&outL[base] = ol.v;
    }
  } else {
#pragma unroll
    for (int mi = 0; mi < 2; mi++)
#pragma unroll
      for (int ni = 0; ni < NF; ni++) {
        int pix = wv * (NF * 16) + ni * 16 + m;
        int py = pix >> 4, px = pix & 15;
        int gy = tY * TH + py, gx = tX * TW + px;
#pragma unroll
        for (int r = 0; r < 4; r++) {
          int co = yb * 32 + mi * 16 + gg * 4 + r;
          if (co >= coutEff) continue;
          float o = tanhf(acc[mi][ni][r] + bias[co]);
          outF[(size_t)(b * coutEff + co) * HWout + (size_t)gy * Wout + gx] = o;
        }
      }
  }
}

// ---------------- cp1 helpers ----------------
__global__ void k_mask_s(const float* __restrict__ mask, float* __restrict__ mask_s) {
  int idx = blockIdx.x * 256 + threadIdx.x;
  if (idx >= BB * 4096) return;
  int b = idx >> 12, r = idx & 4095;
  int i = r >> 6, j = r & 63;
  float s = 0.f;
  for (int u = 0; u < 4; u++)
    for (int v = 0; v < 4; v++)
      s += mask[(size_t)b * 65536 + (i * 4 + u) * 256 + (j * 4 + v)];
  mask_s[idx] = s * (1.f / 16.f);
}

__global__ void k_mm(const float* __restrict__ mask_s, float* __restrict__ mm) {
  int idx = blockIdx.x * 256 + threadIdx.x;
  if (idx >= BB * 1024) return;
  int b = idx >> 10, l = idx & 1023;
  int li = l >> 5, lj = l & 31;
  float s = 0.f;
  for (int dy = 0; dy < 4; dy++) {
    int row = 2 * li + dy - 1;
    if (row < 0 || row >= 64) continue;
    for (int dx = 0; dx < 4; dx++) {
      int col = 2 * lj + dx - 1;
      if (col < 0 || col >= 64) continue;
      s += mask_s[((size_t)b << 12) + row * 64 + col];
    }
  }
  mm[idx] = (s == 0.f) ? 1.f : 0.f;
}

// block per (b,l): LDS transpose, coalesced in & out. p = c*16 + dy*4 + dx.
__global__ __launch_bounds__(256) void extract_patches_bf(
    const ushort* __restrict__ xsH, const ushort* __restrict__ xsL,
    ushort* __restrict__ Phi, ushort* __restrict__ Plo) {
  int bl = blockIdx.x;
  int b = bl >> 10, l = bl & 1023;
  int li = l >> 5, lj = l & 31;
  __shared__ ushort sH[1536], sL[1536];
  int tid = threadIdx.x;
  for (int t = tid; t < 192; t += 256) {
    ((uint4*)sH)[t] = (uint4){0u, 0u, 0u, 0u};
    ((uint4*)sL)[t] = (uint4){0u, 0u, 0u, 0u};
  }
  __syncthreads();
  if (tid < 192) {
    int px = tid / 12, g = tid % 12;
    int dy = px >> 2, dx = px & 3;
    int row = 2 * li + dy - 1, col = 2 * lj + dx - 1;
    if (row >= 0 && row < 64 && col >= 0 && col < 64) {
      size_t a = ((((size_t)b << 12) + (row << 6) + col) * 96) + g * 8;
      union { uint4 v; ushort u[8]; } h, lo;
      h.v = *(const uint4*)&xsH[a];
      lo.v = *(const uint4*)&xsL[a];
#pragma unroll
      for (int j = 0; j < 8; j++) {
        int c = g * 8 + j;
        sH[c * 16 + px] = h.u[j];
        sL[c * 16 + px] = lo.u[j];
      }
    }
  }
  __syncthreads();
  size_t o = (size_t)bl * 1536;
  for (int t = tid; t < 192; t += 256) {
    ((uint4*)(Phi + o))[t] = ((uint4*)sH)[t];
    ((uint4*)(Plo + o))[t] = ((uint4*)sL)[t];
  }
}

__global__ void k_scale_bf(const ushort* __restrict__ Phi, const ushort* __restrict__ Plo,
                           const float* __restrict__ mm, float* __restrict__ scale) {
  int bl = blockIdx.x;
  const ushort* rh = Phi + (size_t)bl * 1536;
  const ushort* rl = Plo + (size_t)bl * 1536;
  int tid = threadIdx.x;
  float s = 0.f;
  for (int i = 0; i < 6; i++) {
    float v = bf2f(rh[tid + i * 256]) + bf2f(rl[tid + i * 256]);
    s += v * v;
  }
  __shared__ float red[256];
  red[tid] = s; __syncthreads();
  for (int t = 128; t > 0; t >>= 1) { if (tid < t) red[tid] += red[tid + t]; __syncthreads(); }
  if (tid == 0) scale[bl] = mm[bl] / fmaxf(sqrtf(red[0]), 1e-4f);
}

// ---------------- MFMA GEMM: S[b][q][l] = scale[l] * P[q].P[l] ----------------
__global__ __launch_bounds__(256) void gemm_qk_mfma(
    const ushort* __restrict__ Phi, const ushort* __restrict__ Plo,
    const float* __restrict__ scale, float* __restrict__ S) {
  int b = blockIdx.z;
  int qTile = blockIdx.y * 128, lTile = blockIdx.x * 128;
  __shared__ uint4 sAh[512], sAl[512], sBh[512], sBl[512];

  int tid = threadIdx.x;
  int lane = tid & 63, w = tid >> 6;
  int wy = w >> 1, wx = w & 1;
  int m = lane & 15, gg = lane >> 4;

  f32x4 acc[4][4];
#pragma unroll
  for (int i = 0; i < 4; i++)
#pragma unroll
    for (int j = 0; j < 4; j++) acc[i][j] = (f32x4){0.f, 0.f, 0.f, 0.f};

  for (int k0 = 0; k0 < 1536; k0 += 32) {
    __syncthreads();
    for (int t = tid; t < 512; t += 256) {
      int r = t >> 2, g = t & 3;
      int slot = (r << 2) + (g ^ ((r >> 1) & 3));
      size_t aoff = ((size_t)(b * 1024 + qTile + r)) * 1536 + k0;
      size_t boff = ((size_t)(b * 1024 + lTile + r)) * 1536 + k0;
      sAh[slot] = ((const uint4*)(Phi + aoff))[g];
      sAl[slot] = ((const uint4*)(Plo + aoff))[g];
      sBh[slot] = ((const uint4*)(Phi + boff))[g];
      sBl[slot] = ((const uint4*)(Plo + boff))[g];
    }
    __syncthreads();
    bf16x8 ah[4], al[4], bh[4], bl[4];
#pragma unroll
    for (int i = 0; i < 4; i++) {
      int ra = wy * 64 + i * 16 + m;
      int rb = wx * 64 + i * 16 + m;
      int sa = (ra << 2) + (gg ^ ((ra >> 1) & 3));
      int sb = (rb << 2) + (gg ^ ((rb >> 1) & 3));
      ah[i] = as_bf(sAh[sa]);
      al[i] = as_bf(sAl[sa]);
      bh[i] = as_bf(sBh[sb]);
      bl[i] = as_bf(sBl[sb]);
    }
#pragma unroll
    for (int mi = 0; mi < 4; mi++)
#pragma unroll
      for (int ni = 0; ni < 4; ni++) {
        acc[mi][ni] = __builtin_amdgcn_mfma_f32_16x16x32_bf16(ah[mi], bh[ni], acc[mi][ni], 0, 0, 0);
        acc[mi][ni] = __builtin_amdgcn_mfma_f32_16x16x32_bf16(ah[mi], bl[ni], acc[mi][ni], 0, 0, 0);
        acc[mi][ni] = __builtin_amdgcn_mfma_f32_16x16x32_bf16(al[mi], bh[ni], acc[mi][ni], 0, 0, 0);
      }
  }

#pragma unroll
  for (int ni = 0; ni < 4; ni++) {
    int l = lTile + wx * 64 + ni * 16 + m;
    float sc = scale[b * 1024 + l];
#pragma unroll
    for (int mi = 0; mi < 4; mi++) {
      int q0 = qTile + wy * 64 + mi * 16 + gg * 4;
#pragma unroll
      for (int r = 0; r < 4; r++)
        S[((size_t)b * 1024 + q0 + r) * 1024 + l] = acc[mi][ni][r] * sc;
    }
  }
}

// softmax over l, *mm, emit hi/lo bf16 probs
__global__ void softmax_rows_bf(const float* __restrict__ S, const float* __restrict__ mm,
                                ushort* __restrict__ Shi, ushort* __restrict__ Slo) {
  int q = blockIdx.x, b = blockIdx.y;
  const float* row = S + ((size_t)b * 1024 + q) * 1024;
  int tid = threadIdx.x;
  float v[4];
  float mx = -1e30f;
  for (int i = 0; i < 4; i++) { v[i] = row[tid + i * 256]; mx = fmaxf(mx, v[i]); }
  __shared__ float red[256];
  red[tid] = mx; __syncthreads();
  for (int s = 128; s > 0; s >>= 1) { if (tid < s) red[tid] = fmaxf(red[tid], red[tid + s]); __syncthreads(); }
  mx = red[0]; __syncthreads();
  float sum = 0.f;
  for (int i = 0; i < 4; i++) { v[i] = expf(10.f * (v[i] - mx)); sum += v[i]; }
  red[tid] = sum; __syncthreads();
  for (int s = 128; s > 0; s >>= 1) { if (tid < s) red[tid] += red[tid + s]; __syncthreads(); }
  sum = red[0];
  float inv = 1.f / sum;
  for (int i = 0; i < 4; i++) {
    int l = tid + i * 256;
    float p = v[i] * inv * mm[b * 1024 + l];
    ushort h = f2bf(p);
    size_t o = ((size_t)b * 1024 + q) * 1024 + l;
    Shi[o] = h;
    Slo[o] = f2bf(p - bf2f(h));
  }
}

// ---------------- cp2 prepW: block per (u,li); p = (u*16+v)*24 + c ----------
__global__ __launch_bounds__(256) void k_prepW(
    const ushort* __restrict__ t16H, const ushort* __restrict__ t16L,
    ushort* __restrict__ WtH, ushort* __restrict__ WtL, int b) {
  int u = blockIdx.x >> 5, li = blockIdx.x & 31;
  int row = 8 * li + u - 4;
  bool rv = (row >= 0 && row < 256);
  __shared__ ushort sH[256 * 24], sL[256 * 24];
  int tid = threadIdx.x;
  for (int t = tid; t < 768; t += 256) {
    uint4 h = {0u, 0u, 0u, 0u}, l = {0u, 0u, 0u, 0u};
    if (rv) {
      size_t a = ((size_t)b * 65536 + (row << 8)) * 24 + t * 8;
      h = *(const uint4*)&t16H[a];
      l = *(const uint4*)&t16L[a];
    }
    ((uint4*)sH)[t] = h;
    ((uint4*)sL)[t] = l;
  }
  __syncthreads();
  for (int pr = tid; pr < 384; pr += 256) {
    int v = pr / 24, c = pr - (pr / 24) * 24;
    int p = (u * 16 + v) * 24 + c;
    union { ushort us[32]; uint4 q[4]; } oh, ol;
#pragma unroll 8
    for (int lj = 0; lj < 32; lj++) {
      int col = 8 * lj + v - 4;
      ushort hv = 0, lv = 0;
      if (col >= 0 && col < 256) { hv = sH[col * 24 + c]; lv = sL[col * 24 + c]; }
      oh.us[lj] = hv;
      ol.us[lj] = lv;
    }
    size_t o = (size_t)p * 1024 + li * 32;
#pragma unroll
    for (int g = 0; g < 4; g++) {
      *(uint4*)&WtH[o + g * 8] = oh.q[g];
      *(uint4*)&WtL[o + g * 8] = ol.q[g];
    }
  }
}

// ---------------- MFMA GEMM cp2 ----------------
__global__ __launch_bounds__(256) void gemm_cp2_mfma(
    const ushort* __restrict__ Shi, const ushort* __restrict__ Slo,
    const ushort* __restrict__ Wthi, const ushort* __restrict__ Wtlo,
    float* __restrict__ contrib, int b) {
  int qTile = blockIdx.y * 128, pTile = blockIdx.x * 128;
  __shared__ uint4 sAh[512], sAl[512], sBh[512], sBl[512];

  int tid = threadIdx.x;
  int lane = tid & 63, w = tid >> 6;
  int wy = w >> 1, wx = w & 1;
  int m = lane & 15, gg = lane >> 4;

  f32x4 acc[4][4];
#pragma unroll
  for (int i = 0; i < 4; i++)
#pragma unroll
    for (int j = 0; j < 4; j++) acc[i][j] = (f32x4){0.f, 0.f, 0.f, 0.f};

  for (int l0 = 0; l0 < 1024; l0 += 32) {
    __syncthreads();
    for (int t = tid; t < 512; t += 256) {
      int r = t >> 2, g = t & 3;
      int slot = (r << 2) + (g ^ ((r >> 1) & 3));
      size_t aoff = ((size_t)(b * 1024 + qTile + r)) * 1024 + l0;
      size_t boff = ((size_t)(pTile + r)) * 1024 + l0;
      sAh[slot] = ((const uint4*)(Shi + aoff))[g];
      sAl[slot] = ((const uint4*)(Slo + aoff))[g];
      sBh[slot] = ((const uint4*)(Wthi + boff))[g];
      sBl[slot] = ((const uint4*)(Wtlo + boff))[g];
    }
    __syncthreads();
    bf16x8 ah[4], al[4], bh[4], bl[4];
#pragma unroll
    for (int i = 0; i < 4; i++) {
      int ra = wy * 64 + i * 16 + m;
      int rb = wx * 64 + i * 16 + m;
      int sa = (ra << 2) + (gg ^ ((ra >> 1) & 3));
      int sb = (rb << 2) + (gg ^ ((rb >> 1) & 3));
      ah[i] = as_bf(sAh[sa]);
      al[i] = as_bf(sAl[sa]);
      bh[i] = as_bf(sBh[sb]);
      bl[i] = as_bf(sBl[sb]);
    }
#pragma unroll
    for (int mi = 0; mi < 4; mi++)
#pragma unroll
      for (int ni = 0; ni < 4; ni++) {
        acc[mi][ni] = __builtin_amdgcn_mfma_f32_16x16x32_bf16(ah[mi], bh[ni], acc[mi][ni], 0, 0, 0);
        acc[mi][ni] = __builtin_amdgcn_mfma_f32_16x16x32_bf16(ah[mi], bl[ni], acc[mi][ni], 0, 0, 0);
        acc[mi][ni] = __builtin_amdgcn_mfma_f32_16x16x32_bf16(al[mi], bh[ni], acc[mi][ni], 0, 0, 0);
      }
  }

#pragma unroll
  for (int ni = 0; ni < 4; ni++) {
    int p = pTile + wx * 64 + ni * 16 + m;
#pragma unroll
    for (int mi = 0; mi < 4; mi++) {
      int q0 = qTile + wy * 64 + mi * 16 + gg * 4;
#pragma unroll
      for (int r = 0; r < 4; r++)
        contrib[(size_t)(q0 + r) * 6144 + p] = acc[mi][ni][r];
    }
  }
}

// fold + blend; contrib p=(u*16+v)*24+c; thread per pixel, 24ch vectorized
__global__ void k_fold(const float* __restrict__ contrib,
                       const ushort* __restrict__ t16H, const ushort* __restrict__ t16L,
                       const float* __restrict__ mask,
                       ushort* __restrict__ outH, ushort* __restrict__ outL, int b) {
  int r = blockIdx.x * 256 + threadIdx.x;
  if (r >= 65536) return;
  int Y = r >> 8, X = r & 255;
  int yp = Y + 4, xp = X + 4;
  int qis[2], qjs[2];
  int cy = 0, cx = 0;
  int qi1 = yp >> 3;
  if (qi1 - 1 >= 0) qis[cy++] = qi1 - 1;
  if (qi1 < 32) qis[cy++] = qi1;
  int qj1 = xp >> 3;
  if (qj1 - 1 >= 0) qjs[cx++] = qj1 - 1;
  if (qj1 < 32) qjs[cx++] = qj1;
  float sum[24];
#pragma unroll
  for (int c = 0; c < 24; c++) sum[c] = 0.f;
  for (int a = 0; a < cy; a++)
    for (int d = 0; d < cx; d++) {
      int qi = qis[a], qj = qjs[d];
      int u = yp - 8 * qi, v = xp - 8 * qj;
      const float4* cp = (const float4*)&contrib[(size_t)(qi * 32 + qj) * 6144 + (u * 16 + v) * 24];
#pragma unroll
      for (int g = 0; g < 6; g++) {
        float4 f = cp[g];
        sum[g * 4 + 0] += f.x;
        sum[g * 4 + 1] += f.y;
        sum[g * 4 + 2] += f.z;
        sum[g * 4 + 3] += f.w;
      }
    }
  float inv = 1.f / (float)(cy * cx);
  float m = mask[(size_t)b * 65536 + r];
  size_t a16 = ((size_t)b * 65536 + r) * 24;
#pragma unroll
  for (int g = 0; g < 3; g++) {
    union { uint4 v; ushort u[8]; } th, tl, oh, ol;
    th.v = *(const uint4*)&t16H[a16 + g * 8];
    tl.v = *(const uint4*)&t16L[a16 + g * 8];
#pragma unroll
    for (int j = 0; j < 8; j++) {
      float base = bf2f(th.u[j]) + bf2f(tl.u[j]);
      float res = sum[g * 8 + j] * inv * m + base * (1.f - m);
      ushort h = f2bf(res);
      oh.u[j] = h;
      ol.u[j] = f2bf(res - bf2f(h));
    }
    *(uint4*)&outH[a16 + g * 8] = oh.v;
    *(uint4*)&outL[a16 + g * 8] = ol.v;
  }
}

// ---------------- launch ----------------
extern "C" void kernel_launch(void* const* d_in, const int* in_sizes, int n_in,
                              void* d_out, int out_size, void* d_ws, size_t ws_size,
                              hipStream_t stream) {
  const float* x      = (const float*)d_in[0];
  const float* mask   = (const float*)d_in[1];
  const float* x_st1  = (const float*)d_in[2];
  const float* x_st2  = (const float*)d_in[3];
  const float* pm     = (const float*)d_in[4];
  const float* b_sconv1 = (const float*)d_in[6];
  const float* b_sconv2 = (const float*)d_in[8];
  const float* b_bconv1 = (const float*)d_in[10];
  const float* b_bconv2 = (const float*)d_in[12];
  const float* b_bconv3 = (const float*)d_in[14];
  const float* b_bconv4 = (const float*)d_in[16];
  const float* b_conv13 = (const float*)d_in[18];
  const float* b_conv14 = (const float*)d_in[20];
  const float* b_conv15 = (const float*)d_in[22];
  const float* b_conv16 = (const float*)d_in[24];
  const float* b_conv16_2 = (const float*)d_in[26];
  const float* b_conv17 = (const float*)d_in[28];
  float* out = (float*)d_out;
  float* ws = (float*)d_ws;
  (void)in_sizes; (void)n_in; (void)out_size; (void)ws_size;

  // workspace layout (float offsets)
  const size_t o_masks  = 0;         // 16384
  const size_t o_mm     = 16384;     // 4096
  const size_t o_scale  = 20480;     // 4096
  const size_t o_xnowH  = 24576;     // 1048576
  const size_t o_xnowL  = 1073152;   // 1048576
  const size_t o_pmH    = 2121728;   // 786432
  const size_t o_pmL    = 2908160;   // 786432
  const size_t o_xsH    = 3694592;   // 786432
  const size_t o_xsL    = 4481024;   // 786432
  const size_t o_xsimH  = 5267456;   // 786432
  const size_t o_xsimL  = 6053888;   // 786432
  const size_t o_Phi    = 6840320;   // 3145728
  const size_t o_Plo    = 9986048;   // 3145728
  const size_t o_S      = 13131776;  // 4194304
  const size_t o_Shi    = 17326080;  // 2097152
  const size_t o_Slo    = 19423232;  // 2097152
  const size_t o_skip1H = 21520384;  // 3145728
  const size_t o_skip1L = 24666112;  // 3145728
  const size_t o_t2H    = 27811840;  // 1572864
  const size_t o_t2L    = 29384704;  // 1572864
  const size_t o_skip2H = 30957568;  // 1572864
  const size_t o_skip2L = 32530432;  // 1572864
  const size_t o_t4H    = 34103296;  // 786432
  const size_t o_t4L    = 34889728;  // 786432
  const size_t o_t13H   = 35676160;  // 1572864
  const size_t o_t13L   = 37249024;  // 1572864
  const size_t o_wbH    = 38821888;  // 586240 (WTOTAL uint4)
  const size_t o_wbL    = 39408128;  // 586240 -> end 39994368 floats (160 MB)
  // reuse
  const size_t o_t14H = o_t2H, o_t14L = o_t2L;
  const size_t o_t15H = o_Phi, o_t15L = o_Plo;
  const size_t o_t16H = o_S;
  const size_t o_t16L = o_pmH;
  const size_t o_WtH  = o_t2H;
  const size_t o_WtL  = o_t4H;
  const size_t o_contrib = o_Phi;
  const size_t o_cp2H = o_skip1H, o_cp2L = o_skip1L;
  const size_t o_t162H = o_Phi, o_t162L = o_Plo;

  ushort* xnowH = (ushort*)(ws + o_xnowH); ushort* xnowL = (ushort*)(ws + o_xnowL);
  ushort* pmH  = (ushort*)(ws + o_pmH);   ushort* pmL  = (ushort*)(ws + o_pmL);
  ushort* xsH  = (ushort*)(ws + o_xsH);   ushort* xsL  = (ushort*)(ws + o_xsL);
  ushort* xsimH= (ushort*)(ws + o_xsimH); ushort* xsimL= (ushort*)(ws + o_xsimL);
  ushort* Phi  = (ushort*)(ws + o_Phi);   ushort* Plo  = (ushort*)(ws + o_Plo);
  ushort* Shi  = (ushort*)(ws + o_Shi);   ushort* Slo  = (ushort*)(ws + o_Slo);
  ushort* skip1H=(ushort*)(ws + o_skip1H);ushort* skip1L=(ushort*)(ws + o_skip1L);
  ushort* t2H  = (ushort*)(ws + o_t2H);   ushort* t2L  = (ushort*)(ws + o_t2L);
  ushort* skip2H=(ushort*)(ws + o_skip2H);ushort* skip2L=(ushort*)(ws + o_skip2L);
  ushort* t4H  = (ushort*)(ws + o_t4H);   ushort* t4L  = (ushort*)(ws + o_t4L);
  ushort* t13H = (ushort*)(ws + o_t13H);  ushort* t13L = (ushort*)(ws + o_t13L);
  ushort* t14H = (ushort*)(ws + o_t14H);  ushort* t14L = (ushort*)(ws + o_t14L);
  ushort* t15H = (ushort*)(ws + o_t15H);  ushort* t15L = (ushort*)(ws + o_t15L);
  ushort* t16H = (ushort*)(ws + o_t16H);  ushort* t16L = (ushort*)(ws + o_t16L);
  ushort* WtH  = (ushort*)(ws + o_WtH);   ushort* WtL  = (ushort*)(ws + o_WtL);
  ushort* cp2H = (ushort*)(ws + o_cp2H);  ushort* cp2L = (ushort*)(ws + o_cp2L);
  ushort* t162H= (ushort*)(ws + o_t162H); ushort* t162L= (ushort*)(ws + o_t162L);
  uint4* wbH = (uint4*)(ws + o_wbH);
  uint4* wbL = (uint4*)(ws + o_wbL);

  // layer offsets in uint4 units (order: sconv1,sconv2,bconv1..4,conv13..17)
  const size_t LOFF[12] = {0, 64512, 87552, 89344, 92800, 98560,
                           112384, 123904, 135424, 139264, 143104, 145408};

  // weight pre-pack (one launch, all layers)
  WPtrs wp;
  wp.w[0] = (const float*)d_in[5];   wp.w[1] = (const float*)d_in[7];
  wp.w[2] = (const float*)d_in[9];   wp.w[3] = (const float*)d_in[11];
  wp.w[4] = (const float*)d_in[13];  wp.w[5] = (const float*)d_in[15];
  wp.w[6] = (const float*)d_in[17];  wp.w[7] = (const float*)d_in[19];
  wp.w[8] = (const float*)d_in[21];  wp.w[9] = (const float*)d_in[23];
  wp.w[10] = (const float*)d_in[25]; wp.w[11] = (const float*)d_in[27];
  prep_w_all<<<128, 256, 0, stream>>>(wp, wbH, wbL);

  // outputs 0,1: pass-through copies
  hipMemcpyAsync(out, x_st1, (size_t)786432 * 4, hipMemcpyDeviceToDevice, stream);
  hipMemcpyAsync(out + 786432, x_st2, (size_t)786432 * 4, hipMemcpyDeviceToDevice, stream);

  k_xnow<<<1024, 256, 0, stream>>>(x, x_st2, mask, xnowH, xnowL);
  k_tr<<<64, 256, 0, stream>>>(pm, pmH, pmL);

  // similarity branch
  conv_mfma<5, 1, 0, 8, 16, 16, 28><<<dim3(16, 6, BB), 256, 0, stream>>>(
      pmH, pmL, nullptr, nullptr, 96, 0, 12, 96, wbH + LOFF[0], wbL + LOFF[0], b_sconv1,
      xsH, xsL, nullptr, 64, 64, 64, 64, 96, 96, 0, 4);
  conv_mfma<3, 1, 0, 16, 16, 16, 10><<<dim3(16, 6, BB), 256, 0, stream>>>(
      xsH, xsL, nullptr, nullptr, 96, 0, 12, 96, wbH + LOFF[1], wbL + LOFF[1], b_sconv2,
      xsimH, xsimL, nullptr, 64, 64, 64, 64, 96, 96, 1, 4);
  k_mask_s<<<64, 256, 0, stream>>>(mask, ws + o_masks);
  k_mm<<<16, 256, 0, stream>>>(ws + o_masks, ws + o_mm);
  extract_patches_bf<<<4096, 256, 0, stream>>>(xsimH, xsimL, Phi, Plo);
  k_scale_bf<<<4096, 256, 0, stream>>>(Phi, Plo, ws + o_mm, ws + o_scale);
  gemm_qk_mfma<<<dim3(8, 8, BB), 256, 0, stream>>>(Phi, Plo, ws + o_scale, ws + o_S);
  softmax_rows_bf<<<dim3(1024, BB), 256, 0, stream>>>(ws + o_S, ws + o_mm, Shi, Slo);

  // main branch
  conv_mfma<5, 1, 0, 8, 16, 16, 28><<<dim3(256, 2, BB), 256, 0, stream>>>(
      xnowH, xnowL, nullptr, nullptr, 8, 0, 1, 8, wbH + LOFF[2], wbL + LOFF[2], b_bconv1,
      skip1H, skip1L, nullptr, 256, 256, 256, 256, 24, 24, 0, 16);
  conv_mfma<3, 2, 0, 8, 8, 16, 12><<<dim3(128, 3, BB), 256, 0, stream>>>(
      skip1H, skip1L, nullptr, nullptr, 24, 0, 3, 24, wbH + LOFF[3], wbL + LOFF[3], b_bconv2,
      t2H, t2L, nullptr, 256, 256, 128, 128, 48, 48, 0, 8);
  conv_mfma<3, 1, 0, 16, 16, 16, 10><<<dim3(64, 3, BB), 256, 0, stream>>>(
      t2H, t2L, nullptr, nullptr, 48, 0, 6, 48, wbH + LOFF[4], wbL + LOFF[4], b_bconv3,
      skip2H, skip2L, nullptr, 128, 128, 128, 128, 48, 48, 0, 8);
  conv_mfma<3, 2, 0, 8, 8, 16, 12><<<dim3(32, 6, BB), 256, 0, stream>>>(
      skip2H, skip2L, nullptr, nullptr, 48, 0, 6, 48, wbH + LOFF[5], wbL + LOFF[5], b_bconv4,
      t4H, t4L, nullptr, 128, 128, 64, 64, 96, 96, 0, 4);
  conv_mfma<3, 1, 1, 16, 16, 16, 10><<<dim3(64, 3, BB), 256, 0, stream>>>(
      t4H, t4L, nullptr, nullptr, 96, 0, 12, 96, wbH + LOFF[6], wbL + LOFF[6], b_conv13,
      t13H, t13L, nullptr, 64, 64, 128, 128, 48, 48, 0, 8);
  conv_mfma<3, 1, 0, 16, 16, 16, 10><<<dim3(64, 3, BB), 256, 0, stream>>>(
      t13H, t13L, skip2H, skip2L, 48, 48, 6, 96, wbH + LOFF[7], wbL + LOFF[7], b_conv14,
      t14H, t14L, nullptr, 128, 128, 128, 128, 48, 48, 0, 8);
  conv_mfma<3, 1, 1, 16, 16, 16, 10><<<dim3(256, 2, BB), 256, 0, stream>>>(
      t14H, t14L, nullptr, nullptr, 48, 0, 6, 48, wbH + LOFF[8], wbL + LOFF[8], b_conv15,
      t15H, t15L, nullptr, 128, 128, 256, 256, 24, 24, 0, 16);
  conv_mfma<3, 1, 0, 16, 16, 16, 10><<<dim3(256, 2, BB), 256, 0, stream>>>(
      t15H, t15L, skip1H, skip1L, 24, 24, 3, 48, wbH + LOFF[9], wbL + LOFF[9], b_conv16,
      t16H, t16L, nullptr, 256, 256, 256, 256, 24, 24, 0, 16);

  // cp2: per-batch prepW + MFMA GEMM + fold
  for (int b = 0; b < BB; b++) {
    k_prepW<<<512, 256, 0, stream>>>(t16H, t16L, WtH, WtL, b);
    gemm_cp2_mfma<<<dim3(48, 8), 256, 0, stream>>>(Shi, Slo, WtH, WtL, ws + o_contrib, b);
    k_fold<<<256, 256, 0, stream>>>(ws + o_contrib, t16H, t16L, mask, cp2H, cp2L, b);
  }

  // tail convs (cinp=24 -> CC=8 variant)
  conv_mfma<3, 1, 0, 8, 16, 16, 12><<<dim3(256, 2, BB), 256, 0, stream>>>(
      cp2H, cp2L, nullptr, nullptr, 24, 0, 3, 24, wbH + LOFF[10], wbL + LOFF[10], b_conv16_2,
      t162H, t162L, nullptr, 256, 256, 256, 256, 24, 24, 0, 16);
  conv_mfma<3, 1, 0, 8, 16, 16, 12><<<dim3(256, 1, BB), 256, 0, stream>>>(
      t162H, t162L, nullptr, nullptr, 24, 0, 3, 24, wbH + LOFF[11], wbL + LOFF[11], b_conv17,
      nullptr, nullptr, out + 2 * 786432, 256, 256, 256, 256, 3, 24, 2, 16);
}

// Round 8
// 860.661 us; speedup vs baseline: 13.2280x; 1.1721x over previous
//
#include <hip/hip_runtime.h>
#include <math.h>

#define BB 4

typedef __bf16 bf16x8 __attribute__((ext_vector_type(8)));
typedef float f32x4 __attribute__((ext_vector_type(4)));

__device__ inline ushort f2bf(float x) {
  uint u = __float_as_uint(x);
  uint r = (u + 0x7fffu + ((u >> 16) & 1u)) >> 16;
  return (ushort)r;
}
__device__ inline float bf2f(ushort h) { return __uint_as_float(((uint)h) << 16); }
__device__ inline bf16x8 as_bf(uint4 u) {
  union { uint4 u; bf16x8 b; } c;
  c.u = u;
  return c.b;
}

// ---------------- weight pre-pack: all layers -> bf16 uint4 in conv-LDS layout
struct WPtrs { const float* w[12]; };

#define WTOTAL 146560

__global__ void prep_w_all(WPtrs wp, uint4* __restrict__ wbH) {
  const int tK[12]    = {5,3,5,3,3,3,3,3,3,3,3,3};
  const int tCC[12]   = {8,16,8,8,16,8,16,16,16,16,8,8};
  const int tSP[12]   = {28,10,28,12,10,12,10,10,10,10,12,12};
  const int tcinR[12] = {96,96,3,24,48,48,96,96,48,48,24,24};
  const int tcinp[12] = {96,96,8,24,48,48,96,96,48,48,24,24};
  const int tcout[12] = {96,96,24,48,48,96,48,48,24,24,24,3};
  const int tgat[12]  = {1,1,1,1,1,1,1,1,1,1,1,0};
  const int toff[13]  = {0,64512,87552,89344,92800,98560,112384,123904,135424,139264,143104,145408,146560};
  for (int i = blockIdx.x * 256 + threadIdx.x; i < WTOTAL; i += gridDim.x * 256) {
    int L = 0;
    while (toff[L + 1] <= i) L++;
    int li = i - toff[L];
    int K = tK[L], CC = tCC[L], SPAD = tSP[L];
    int CH = CC >> 3;
    int SZ = SPAD * CH * 32;
    int nch = tcinp[L] / CC;
    int yb = li / (nch * SZ);
    int rem = li - yb * nch * SZ;
    int chunk = rem / SZ;
    int t = rem - chunk * SZ;
    int ci0 = chunk * CC;
    int co32 = t & 31, sh = t >> 5;
    int s = sh / CH, hh = sh - s * CH;
    int fr;
    bool ok;
    if (tgat[L]) {
      int coL = yb * 16 + (co32 & 15);
      ok = coL < tcout[L];
      fr = (co32 < 16) ? coL : tcout[L] + coL;
    } else {
      fr = yb * 32 + co32;
      ok = fr < tcout[L];
    }
    ok = ok && (s < K * K);
    const float* wgt = wp.w[L];
    union { ushort u[8]; uint4 v; } th;
#pragma unroll
    for (int j = 0; j < 8; j++) {
      int ci = ci0 + hh * 8 + j;
      float v = 0.f;
      if (ok && ci < tcinR[L]) v = wgt[((size_t)fr * tcinR[L] + ci) * (K * K) + s];
      th.u[j] = f2bf(v);
    }
    wbH[i] = th.v;
  }
}

// ---------------- xnow -> NHWC8 bf16 hi/lo (3 real + 5 zero channels) -------
__global__ void k_xnow(const float* __restrict__ x, const float* __restrict__ x2,
                       const float* __restrict__ mask,
                       ushort* __restrict__ outH, ushort* __restrict__ outL) {
  int idx = blockIdx.x * 256 + threadIdx.x;
  if (idx >= BB * 65536) return;
  int b = idx >> 16, r = idx & 65535;
  float m = mask[idx];
  union { ushort u[8]; uint4 v; } h, l;
#pragma unroll
  for (int c = 0; c < 8; c++) { h.u[c] = 0; l.u[c] = 0; }
#pragma unroll
  for (int c = 0; c < 3; c++) {
    size_t s = ((size_t)(b * 3 + c) << 16) + r;
    float v = x2[s] * m + x[s] * (1.f - m);
    ushort hh = f2bf(v);
    h.u[c] = hh;
    l.u[c] = f2bf(v - bf2f(hh));
  }
  *(uint4*)&outH[(size_t)idx * 8] = h.v;
  *(uint4*)&outL[(size_t)idx * 8] = l.v;
}

// ---------------- pm (NCHW f32, 96ch 64x64) -> NHWC96 hi/lo ----------------
__global__ void k_tr(const float* __restrict__ pm,
                     ushort* __restrict__ outH, ushort* __restrict__ outL) {
  int idx = blockIdx.x * 256 + threadIdx.x;
  if (idx >= BB * 4096) return;
  int b = idx >> 12, pix = idx & 4095;
#pragma unroll
  for (int g = 0; g < 12; g++) {
    union { ushort u[8]; uint4 v; } h, l;
#pragma unroll
    for (int j = 0; j < 8; j++) {
      float v = pm[(((size_t)b * 96 + g * 8 + j) << 12) + pix];
      ushort hh = f2bf(v);
      h.u[j] = hh;
      l.u[j] = f2bf(v - bf2f(hh));
    }
    *(uint4*)&outH[(size_t)idx * 96 + g * 8] = h.v;
    *(uint4*)&outL[(size_t)idx * 96 + g * 8] = l.v;
  }
}

// ---------------- MFMA implicit-GEMM conv, NHWC hi/lo acts, bf16 weights ----
template <int K, int STRIDE, int UP, int CC, int TH, int TW, int SPAD>
__global__ __launch_bounds__(256) void conv_mfma(
    const ushort* __restrict__ in1H, const ushort* __restrict__ in1L,
    const ushort* __restrict__ in2H, const ushort* __restrict__ in2L,
    int s1, int s2, int g1, int cinp,
    const uint4* __restrict__ wbH,
    const float* __restrict__ bias,
    ushort* __restrict__ outH, ushort* __restrict__ outL, float* __restrict__ outF,
    int Hin, int Win, int Hout, int Wout,
    int coutEff, int coutp, int act, int tilesX) {
  constexpr int CH = CC / 8;
  constexpr int GS = 4 / CH;
  constexpr int NGc = CC / 8;
  constexpr int CCp = (CC == 16) ? 24 : 8;
  constexpr int IH = (TH - 1) * STRIDE + K;
  constexpr int IW = (TW - 1) * STRIDE + K;
  constexpr int NF = (TH * TW) / 64;
  constexpr int NSC = SPAD / GS;
  constexpr int WSZ = SPAD * CH * 32;

  __shared__ ushort sInH[IH * IW * CCp];
  __shared__ ushort sInL[IH * IW * CCp];
  __shared__ uint4 sWH[WSZ];

  const int tid = threadIdx.x;
  const int lane = tid & 63, wv = tid >> 6;
  const int m = lane & 15, gg = lane >> 4;
  const int b = blockIdx.z;
  const int yb = blockIdx.y;
  const int tX = blockIdx.x % tilesX, tY = blockIdx.x / tilesX;
  const int pad = (K - 1) / 2;
  const int HinU = Hin << UP, WinU = Win << UP;
  const int oy0 = tY * TH * STRIDE - pad;
  const int ox0 = tX * TW * STRIDE - pad;
  const int gated = (act != 2);
  const int NG = cinp >> 3;
  const int nch = cinp / CC;
  const size_t HWin = (size_t)Hin * Win;

  f32x4 acc[2][NF];
#pragma unroll
  for (int i = 0; i < 2; i++)
#pragma unroll
    for (int j = 0; j < NF; j++) acc[i][j] = (f32x4){0.f, 0.f, 0.f, 0.f};

  for (int ci0 = 0; ci0 < cinp; ci0 += CC) {
    __syncthreads();
    // ---- stage input tile: pure vector copies ----
    for (int t = tid; t < IH * IW * NGc; t += 256) {
      int p = (NGc == 2) ? (t >> 1) : t;
      int g = (NGc == 2) ? (t & 1) : 0;
      int iy = p / IW, ix = p % IW;
      int gy = oy0 + iy, gx = ox0 + ix;
      int gi = (ci0 >> 3) + g;
      uint4 h = {0u, 0u, 0u, 0u}, l = {0u, 0u, 0u, 0u};
      if (gi < NG && gy >= 0 && gy < HinU && gx >= 0 && gx < WinU) {
        int sy = gy >> UP, sx = gx >> UP;
        size_t poff = (size_t)b * HWin + (size_t)sy * Win + sx;
        if (gi < g1) {
          size_t a = poff * s1 + gi * 8;
          h = *(const uint4*)&in1H[a];
          l = *(const uint4*)&in1L[a];
        } else {
          size_t a = poff * s2 + (gi - g1) * 8;
          h = *(const uint4*)&in2H[a];
          l = *(const uint4*)&in2L[a];
        }
      }
      int d = p * CCp + g * 8;
      *(uint4*)&sInH[d] = h;
      *(uint4*)&sInL[d] = l;
    }
    // ---- stage weights: coalesced copy from pre-packed buffer ----
    {
      const uint4* pH = wbH + ((size_t)yb * nch + (ci0 / CC)) * WSZ;
      for (int t = tid; t < WSZ; t += 256) sWH[t] = pH[t];
    }
    __syncthreads();
    // ---- compute ----
#pragma unroll
    for (int sc = 0; sc < NSC; sc++) {
      int sg = sc * GS + gg / CH;
      int hh = gg - (gg / CH) * CH;
      int s = (sg < K * K) ? sg : 0;
      int kh = s / K, kw = s - kh * K;
      bf16x8 ah[2], bh[NF], bl[NF];
#pragma unroll
      for (int mi = 0; mi < 2; mi++) {
        int ai = (sc * 4 + gg) * 32 + mi * 16 + m;
        ah[mi] = as_bf(sWH[ai]);
      }
#pragma unroll
      for (int ni = 0; ni < NF; ni++) {
        int pix = wv * (NF * 16) + ni * 16 + m;
        int py = pix >> 4, px = pix & 15;
        int li = ((py * STRIDE + kh) * IW + px * STRIDE + kw) * CCp + hh * 8;
        bh[ni] = as_bf(*(const uint4*)&sInH[li]);
        bl[ni] = as_bf(*(const uint4*)&sInL[li]);
      }
#pragma unroll
      for (int mi = 0; mi < 2; mi++)
#pragma unroll
        for (int ni = 0; ni < NF; ni++) {
          acc[mi][ni] = __builtin_amdgcn_mfma_f32_16x16x32_bf16(ah[mi], bh[ni], acc[mi][ni], 0, 0, 0);
          acc[mi][ni] = __builtin_amdgcn_mfma_f32_16x16x32_bf16(ah[mi], bl[ni], acc[mi][ni], 0, 0, 0);
        }
    }
  }
  // ---- epilogue ----
  const size_t HWout = (size_t)Hout * Wout;
  if (gated) {
    int co0 = yb * 16 + gg * 4;
    bool cov = co0 < coutEff;
    float bA[4], bG[4];
#pragma unroll
    for (int r = 0; r < 4; r++) {
      bA[r] = cov ? bias[co0 + r] : 0.f;
      bG[r] = cov ? bias[coutEff + co0 + r] : 0.f;
    }
#pragma unroll
    for (int ni = 0; ni < NF; ni++) {
      int pix = wv * (NF * 16) + ni * 16 + m;
      int py = pix >> 4, px = pix & 15;
      int gy = tY * TH + py, gx = tX * TW + px;
      if (!cov) continue;
      union { ushort u[4]; uint2 v; } oh, ol;
#pragma unroll
      for (int r = 0; r < 4; r++) {
        float a = acc[0][ni][r] + bA[r];
        float g = acc[1][ni][r] + bG[r];
        float aa = (act == 1) ? fmaxf(a, 0.f) : (a > 0.f ? a : expm1f(a));
        float o = aa * (1.f / (1.f + expf(-g)));
        ushort hh = f2bf(o);
        oh.u[r] = hh;
        ol.u[r] = f2bf(o - bf2f(hh));
      }
      size_t base = ((size_t)b * HWout + (size_t)gy * Wout + gx) * coutp + co0;
      *(uint2*)&outH[base] = oh.v;
      *(uint2*)&outL[base] = ol.v;
    }
  } else {
#pragma unroll
    for (int mi = 0; mi < 2; mi++)
#pragma unroll
      for (int ni = 0; ni < NF; ni++) {
        int pix = wv * (NF * 16) + ni * 16 + m;
        int py = pix >> 4, px = pix & 15;
        int gy = tY * TH + py, gx = tX * TW + px;
#pragma unroll
        for (int r = 0; r < 4; r++) {
          int co = yb * 32 + mi * 16 + gg * 4 + r;
          if (co >= coutEff) continue;
          float o = tanhf(acc[mi][ni][r] + bias[co]);
          outF[(size_t)(b * coutEff + co) * HWout + (size_t)gy * Wout + gx] = o;
        }
      }
  }
}

// ---------------- cp1 helpers ----------------
__global__ void k_mask_s(const float* __restrict__ mask, float* __restrict__ mask_s) {
  int idx = blockIdx.x * 256 + threadIdx.x;
  if (idx >= BB * 4096) return;
  int b = idx >> 12, r = idx & 4095;
  int i = r >> 6, j = r & 63;
  float s = 0.f;
  for (int u = 0; u < 4; u++)
    for (int v = 0; v < 4; v++)
      s += mask[(size_t)b * 65536 + (i * 4 + u) * 256 + (j * 4 + v)];
  mask_s[idx] = s * (1.f / 16.f);
}

__global__ void k_mm(const float* __restrict__ mask_s, float* __restrict__ mm) {
  int idx = blockIdx.x * 256 + threadIdx.x;
  if (idx >= BB * 1024) return;
  int b = idx >> 10, l = idx & 1023;
  int li = l >> 5, lj = l & 31;
  float s = 0.f;
  for (int dy = 0; dy < 4; dy++) {
    int row = 2 * li + dy - 1;
    if (row < 0 || row >= 64) continue;
    for (int dx = 0; dx < 4; dx++) {
      int col = 2 * lj + dx - 1;
      if (col < 0 || col >= 64) continue;
      s += mask_s[((size_t)b << 12) + row * 64 + col];
    }
  }
  mm[idx] = (s == 0.f) ? 1.f : 0.f;
}

// block per (b,l): LDS transpose, coalesced in & out. p = c*16 + dy*4 + dx.
__global__ __launch_bounds__(256) void extract_patches_bf(
    const ushort* __restrict__ xsH, const ushort* __restrict__ xsL,
    ushort* __restrict__ Phi, ushort* __restrict__ Plo) {
  int bl = blockIdx.x;
  int b = bl >> 10, l = bl & 1023;
  int li = l >> 5, lj = l & 31;
  __shared__ ushort sH[1536], sL[1536];
  int tid = threadIdx.x;
  for (int t = tid; t < 192; t += 256) {
    ((uint4*)sH)[t] = (uint4){0u, 0u, 0u, 0u};
    ((uint4*)sL)[t] = (uint4){0u, 0u, 0u, 0u};
  }
  __syncthreads();
  if (tid < 192) {
    int px = tid / 12, g = tid % 12;
    int dy = px >> 2, dx = px & 3;
    int row = 2 * li + dy - 1, col = 2 * lj + dx - 1;
    if (row >= 0 && row < 64 && col >= 0 && col < 64) {
      size_t a = ((((size_t)b << 12) + (row << 6) + col) * 96) + g * 8;
      union { uint4 v; ushort u[8]; } h, lo;
      h.v = *(const uint4*)&xsH[a];
      lo.v = *(const uint4*)&xsL[a];
#pragma unroll
      for (int j = 0; j < 8; j++) {
        int c = g * 8 + j;
        sH[c * 16 + px] = h.u[j];
        sL[c * 16 + px] = lo.u[j];
      }
    }
  }
  __syncthreads();
  size_t o = (size_t)bl * 1536;
  for (int t = tid; t < 192; t += 256) {
    ((uint4*)(Phi + o))[t] = ((uint4*)sH)[t];
    ((uint4*)(Plo + o))[t] = ((uint4*)sL)[t];
  }
}

__global__ void k_scale_bf(const ushort* __restrict__ Phi, const ushort* __restrict__ Plo,
                           const float* __restrict__ mm, float* __restrict__ scale) {
  int bl = blockIdx.x;
  const ushort* rh = Phi + (size_t)bl * 1536;
  const ushort* rl = Plo + (size_t)bl * 1536;
  int tid = threadIdx.x;
  float s = 0.f;
  for (int i = 0; i < 6; i++) {
    float v = bf2f(rh[tid + i * 256]) + bf2f(rl[tid + i * 256]);
    s += v * v;
  }
  __shared__ float red[256];
  red[tid] = s; __syncthreads();
  for (int t = 128; t > 0; t >>= 1) { if (tid < t) red[tid] += red[tid + t]; __syncthreads(); }
  if (tid == 0) scale[bl] = mm[bl] / fmaxf(sqrtf(red[0]), 1e-4f);
}

// ---------------- MFMA GEMM qk: 512 threads, 8 waves (2x4), tile 128x128 ----
__global__ __launch_bounds__(512) void gemm_qk_mfma(
    const ushort* __restrict__ Phi, const ushort* __restrict__ Plo,
    const float* __restrict__ scale, float* __restrict__ S) {
  int b = blockIdx.z;
  int qTile = blockIdx.y * 128, lTile = blockIdx.x * 128;
  __shared__ uint4 sAh[512], sAl[512], sBh[512], sBl[512];

  int tid = threadIdx.x;
  int lane = tid & 63, w = tid >> 6;
  int wy = w >> 2, wx = w & 3;
  int m = lane & 15, gg = lane >> 4;

  f32x4 acc[4][2];
#pragma unroll
  for (int i = 0; i < 4; i++)
#pragma unroll
    for (int j = 0; j < 2; j++) acc[i][j] = (f32x4){0.f, 0.f, 0.f, 0.f};

  for (int k0 = 0; k0 < 1536; k0 += 32) {
    __syncthreads();
    {
      int r = tid >> 2, g = tid & 3;
      int slot = (r << 2) + (g ^ ((r >> 1) & 3));
      size_t aoff = ((size_t)(b * 1024 + qTile + r)) * 1536 + k0;
      size_t boff = ((size_t)(b * 1024 + lTile + r)) * 1536 + k0;
      sAh[slot] = ((const uint4*)(Phi + aoff))[g];
      sAl[slot] = ((const uint4*)(Plo + aoff))[g];
      sBh[slot] = ((const uint4*)(Phi + boff))[g];
      sBl[slot] = ((const uint4*)(Plo + boff))[g];
    }
    __syncthreads();
    bf16x8 ah[4], al[4], bh[2], bl[2];
#pragma unroll
    for (int i = 0; i < 4; i++) {
      int ra = wy * 64 + i * 16 + m;
      int sa = (ra << 2) + (gg ^ ((ra >> 1) & 3));
      ah[i] = as_bf(sAh[sa]);
      al[i] = as_bf(sAl[sa]);
    }
#pragma unroll
    for (int j = 0; j < 2; j++) {
      int rb = wx * 32 + j * 16 + m;
      int sb = (rb << 2) + (gg ^ ((rb >> 1) & 3));
      bh[j] = as_bf(sBh[sb]);
      bl[j] = as_bf(sBl[sb]);
    }
#pragma unroll
    for (int mi = 0; mi < 4; mi++)
#pragma unroll
      for (int ni = 0; ni < 2; ni++) {
        acc[mi][ni] = __builtin_amdgcn_mfma_f32_16x16x32_bf16(ah[mi], bh[ni], acc[mi][ni], 0, 0, 0);
        acc[mi][ni] = __builtin_amdgcn_mfma_f32_16x16x32_bf16(ah[mi], bl[ni], acc[mi][ni], 0, 0, 0);
        acc[mi][ni] = __builtin_amdgcn_mfma_f32_16x16x32_bf16(al[mi], bh[ni], acc[mi][ni], 0, 0, 0);
      }
  }

#pragma unroll
  for (int ni = 0; ni < 2; ni++) {
    int l = lTile + wx * 32 + ni * 16 + m;
    float sc = scale[b * 1024 + l];
#pragma unroll
    for (int mi = 0; mi < 4; mi++) {
      int q0 = qTile + wy * 64 + mi * 16 + gg * 4;
#pragma unroll
      for (int r = 0; r < 4; r++)
        S[((size_t)b * 1024 + q0 + r) * 1024 + l] = acc[mi][ni][r] * sc;
    }
  }
}

// softmax over l, *mm, emit hi/lo bf16 probs
__global__ void softmax_rows_bf(const float* __restrict__ S, const float* __restrict__ mm,
                                ushort* __restrict__ Shi, ushort* __restrict__ Slo) {
  int q = blockIdx.x, b = blockIdx.y;
  const float* row = S + ((size_t)b * 1024 + q) * 1024;
  int tid = threadIdx.x;
  float v[4];
  float mx = -1e30f;
  for (int i = 0; i < 4; i++) { v[i] = row[tid + i * 256]; mx = fmaxf(mx, v[i]); }
  __shared__ float red[256];
  red[tid] = mx; __syncthreads();
  for (int s = 128; s > 0; s >>= 1) { if (tid < s) red[tid] = fmaxf(red[tid], red[tid + s]); __syncthreads(); }
  mx = red[0]; __syncthreads();
  float sum = 0.f;
  for (int i = 0; i < 4; i++) { v[i] = expf(10.f * (v[i] - mx)); sum += v[i]; }
  red[tid] = sum; __syncthreads();
  for (int s = 128; s > 0; s >>= 1) { if (tid < s) red[tid] += red[tid + s]; __syncthreads(); }
  sum = red[0];
  float inv = 1.f / sum;
  for (int i = 0; i < 4; i++) {
    int l = tid + i * 256;
    float p = v[i] * inv * mm[b * 1024 + l];
    ushort h = f2bf(p);
    size_t o = ((size_t)b * 1024 + q) * 1024 + l;
    Shi[o] = h;
    Slo[o] = f2bf(p - bf2f(h));
  }
}

// ---------------- cp2 prepW: block per (u,li); p = (u*16+v)*24 + c ----------
// Wt = bf16 (t16H already round-nearest of fp32 value).
__global__ __launch_bounds__(256) void k_prepW(
    const ushort* __restrict__ t16H,
    ushort* __restrict__ WtH, int b) {
  int u = blockIdx.x >> 5, li = blockIdx.x & 31;
  int row = 8 * li + u - 4;
  bool rv = (row >= 0 && row < 256);
  __shared__ ushort sH[256 * 24];
  int tid = threadIdx.x;
  for (int t = tid; t < 768; t += 256) {
    uint4 h = {0u, 0u, 0u, 0u};
    if (rv) h = *(const uint4*)&t16H[((size_t)b * 65536 + (row << 8)) * 24 + t * 8];
    ((uint4*)sH)[t] = h;
  }
  __syncthreads();
  for (int pr = tid; pr < 384; pr += 256) {
    int v = pr / 24, c = pr - (pr / 24) * 24;
    int p = (u * 16 + v) * 24 + c;
    union { ushort us[32]; uint4 q[4]; } oh;
#pragma unroll 8
    for (int lj = 0; lj < 32; lj++) {
      int col = 8 * lj + v - 4;
      oh.us[lj] = (col >= 0 && col < 256) ? sH[col * 24 + c] : (ushort)0;
    }
    size_t o = (size_t)p * 1024 + li * 32;
#pragma unroll
    for (int g = 0; g < 4; g++) *(uint4*)&WtH[o + g * 8] = oh.q[g];
  }
}

// ---------------- MFMA GEMM cp2: 512 threads, 8 waves; B single bf16 --------
__global__ __launch_bounds__(512) void gemm_cp2_mfma(
    const ushort* __restrict__ Shi, const ushort* __restrict__ Slo,
    const ushort* __restrict__ Wthi,
    float* __restrict__ contrib, int b) {
  int qTile = blockIdx.y * 128, pTile = blockIdx.x * 128;
  __shared__ uint4 sAh[512], sAl[512], sBh[512];

  int tid = threadIdx.x;
  int lane = tid & 63, w = tid >> 6;
  int wy = w >> 2, wx = w & 3;
  int m = lane & 15, gg = lane >> 4;

  f32x4 acc[4][2];
#pragma unroll
  for (int i = 0; i < 4; i++)
#pragma unroll
    for (int j = 0; j < 2; j++) acc[i][j] = (f32x4){0.f, 0.f, 0.f, 0.f};

  for (int l0 = 0; l0 < 1024; l0 += 32) {
    __syncthreads();
    {
      int r = tid >> 2, g = tid & 3;
      int slot = (r << 2) + (g ^ ((r >> 1) & 3));
      size_t aoff = ((size_t)(b * 1024 + qTile + r)) * 1024 + l0;
      size_t boff = ((size_t)(pTile + r)) * 1024 + l0;
      sAh[slot] = ((const uint4*)(Shi + aoff))[g];
      sAl[slot] = ((const uint4*)(Slo + aoff))[g];
      sBh[slot] = ((const uint4*)(Wthi + boff))[g];
    }
    __syncthreads();
    bf16x8 ah[4], al[4], bh[2];
#pragma unroll
    for (int i = 0; i < 4; i++) {
      int ra = wy * 64 + i * 16 + m;
      int sa = (ra << 2) + (gg ^ ((ra >> 1) & 3));
      ah[i] = as_bf(sAh[sa]);
      al[i] = as_bf(sAl[sa]);
    }
#pragma unroll
    for (int j = 0; j < 2; j++) {
      int rb = wx * 32 + j * 16 + m;
      int sb = (rb << 2) + (gg ^ ((rb >> 1) & 3));
      bh[j] = as_bf(sBh[sb]);
    }
#pragma unroll
    for (int mi = 0; mi < 4; mi++)
#pragma unroll
      for (int ni = 0; ni < 2; ni++) {
        acc[mi][ni] = __builtin_amdgcn_mfma_f32_16x16x32_bf16(ah[mi], bh[ni], acc[mi][ni], 0, 0, 0);
        acc[mi][ni] = __builtin_amdgcn_mfma_f32_16x16x32_bf16(al[mi], bh[ni], acc[mi][ni], 0, 0, 0);
      }
  }

#pragma unroll
  for (int ni = 0; ni < 2; ni++) {
    int p = pTile + wx * 32 + ni * 16 + m;
#pragma unroll
    for (int mi = 0; mi < 4; mi++) {
      int q0 = qTile + wy * 64 + mi * 16 + gg * 4;
#pragma unroll
      for (int r = 0; r < 4; r++)
        contrib[(size_t)(q0 + r) * 6144 + p] = acc[mi][ni][r];
    }
  }
}

// fold + blend; contrib p=(u*16+v)*24+c; thread per pixel, 24ch vectorized
__global__ void k_fold(const float* __restrict__ contrib,
                       const ushort* __restrict__ t16H, const ushort* __restrict__ t16L,
                       const float* __restrict__ mask,
                       ushort* __restrict__ outH, ushort* __restrict__ outL, int b) {
  int r = blockIdx.x * 256 + threadIdx.x;
  if (r >= 65536) return;
  int Y = r >> 8, X = r & 255;
  int yp = Y + 4, xp = X + 4;
  int qis[2], qjs[2];
  int cy = 0, cx = 0;
  int qi1 = yp >> 3;
  if (qi1 - 1 >= 0) qis[cy++] = qi1 - 1;
  if (qi1 < 32) qis[cy++] = qi1;
  int qj1 = xp >> 3;
  if (qj1 - 1 >= 0) qjs[cx++] = qj1 - 1;
  if (qj1 < 32) qjs[cx++] = qj1;
  float sum[24];
#pragma unroll
  for (int c = 0; c < 24; c++) sum[c] = 0.f;
  for (int a = 0; a < cy; a++)
    for (int d = 0; d < cx; d++) {
      int qi = qis[a], qj = qjs[d];
      int u = yp - 8 * qi, v = xp - 8 * qj;
      const float4* cp = (const float4*)&contrib[(size_t)(qi * 32 + qj) * 6144 + (u * 16 + v) * 24];
#pragma unroll
      for (int g = 0; g < 6; g++) {
        float4 f = cp[g];
        sum[g * 4 + 0] += f.x;
        sum[g * 4 + 1] += f.y;
        sum[g * 4 + 2] += f.z;
        sum[g * 4 + 3] += f.w;
      }
    }
  float inv = 1.f / (float)(cy * cx);
  float m = mask[(size_t)b * 65536 + r];
  size_t a16 = ((size_t)b * 65536 + r) * 24;
#pragma unroll
  for (int g = 0; g < 3; g++) {
    union { uint4 v; ushort u[8]; } th, tl, oh, ol;
    th.v = *(const uint4*)&t16H[a16 + g * 8];
    tl.v = *(const uint4*)&t16L[a16 + g * 8];
#pragma unroll
    for (int j = 0; j < 8; j++) {
      float base = bf2f(th.u[j]) + bf2f(tl.u[j]);
      float res = sum[g * 8 + j] * inv * m + base * (1.f - m);
      ushort h = f2bf(res);
      oh.u[j] = h;
      ol.u[j] = f2bf(res - bf2f(h));
    }
    *(uint4*)&outH[a16 + g * 8] = oh.v;
    *(uint4*)&outL[a16 + g * 8] = ol.v;
  }
}

// ---------------- launch ----------------
extern "C" void kernel_launch(void* const* d_in, const int* in_sizes, int n_in,
                              void* d_out, int out_size, void* d_ws, size_t ws_size,
                              hipStream_t stream) {
  const float* x      = (const float*)d_in[0];
  const float* mask   = (const float*)d_in[1];
  const float* x_st1  = (const float*)d_in[2];
  const float* x_st2  = (const float*)d_in[3];
  const float* pm     = (const float*)d_in[4];
  const float* b_sconv1 = (const float*)d_in[6];
  const float* b_sconv2 = (const float*)d_in[8];
  const float* b_bconv1 = (const float*)d_in[10];
  const float* b_bconv2 = (const float*)d_in[12];
  const float* b_bconv3 = (const float*)d_in[14];
  const float* b_bconv4 = (const float*)d_in[16];
  const float* b_conv13 = (const float*)d_in[18];
  const float* b_conv14 = (const float*)d_in[20];
  const float* b_conv15 = (const float*)d_in[22];
  const float* b_conv16 = (const float*)d_in[24];
  const float* b_conv16_2 = (const float*)d_in[26];
  const float* b_conv17 = (const float*)d_in[28];
  float* out = (float*)d_out;
  float* ws = (float*)d_ws;
  (void)in_sizes; (void)n_in; (void)out_size; (void)ws_size;

  // workspace layout (float offsets)
  const size_t o_masks  = 0;         // 16384
  const size_t o_mm     = 16384;     // 4096
  const size_t o_scale  = 20480;     // 4096
  const size_t o_xnowH  = 24576;     // 1048576
  const size_t o_xnowL  = 1073152;   // 1048576
  const size_t o_pmH    = 2121728;   // 786432
  const size_t o_pmL    = 2908160;   // 786432
  const size_t o_xsH    = 3694592;   // 786432
  const size_t o_xsL    = 4481024;   // 786432
  const size_t o_xsimH  = 5267456;   // 786432
  const size_t o_xsimL  = 6053888;   // 786432
  const size_t o_Phi    = 6840320;   // 3145728
  const size_t o_Plo    = 9986048;   // 3145728
  const size_t o_S      = 13131776;  // 4194304
  const size_t o_Shi    = 17326080;  // 2097152
  const size_t o_Slo    = 19423232;  // 2097152
  const size_t o_skip1H = 21520384;  // 3145728
  const size_t o_skip1L = 24666112;  // 3145728
  const size_t o_t2H    = 27811840;  // 1572864
  const size_t o_t2L    = 29384704;  // 1572864
  const size_t o_skip2H = 30957568;  // 1572864
  const size_t o_skip2L = 32530432;  // 1572864
  const size_t o_t4H    = 34103296;  // 786432
  const size_t o_t4L    = 34889728;  // 786432
  const size_t o_t13H   = 35676160;  // 1572864
  const size_t o_t13L   = 37249024;  // 1572864
  const size_t o_wbH    = 38821888;  // 586240 (WTOTAL uint4)
  // reuse
  const size_t o_t14H = o_t2H, o_t14L = o_t2L;
  const size_t o_t15H = o_Phi, o_t15L = o_Plo;
  const size_t o_t16H = o_S;
  const size_t o_t16L = o_pmH;
  const size_t o_WtH  = o_t2H;              // spans t2H+t2L (12.6 MB need, 12.6 avail)
  const size_t o_contrib = o_Phi;           // spans Phi+Plo (t15 consumed)
  const size_t o_cp2H = o_skip1H, o_cp2L = o_skip1L;
  const size_t o_t162H = o_Phi, o_t162L = o_Plo;

  ushort* xnowH = (ushort*)(ws + o_xnowH); ushort* xnowL = (ushort*)(ws + o_xnowL);
  ushort* pmH  = (ushort*)(ws + o_pmH);   ushort* pmL  = (ushort*)(ws + o_pmL);
  ushort* xsH  = (ushort*)(ws + o_xsH);   ushort* xsL  = (ushort*)(ws + o_xsL);
  ushort* xsimH= (ushort*)(ws + o_xsimH); ushort* xsimL= (ushort*)(ws + o_xsimL);
  ushort* Phi  = (ushort*)(ws + o_Phi);   ushort* Plo  = (ushort*)(ws + o_Plo);
  ushort* Shi  = (ushort*)(ws + o_Shi);   ushort* Slo  = (ushort*)(ws + o_Slo);
  ushort* skip1H=(ushort*)(ws + o_skip1H);ushort* skip1L=(ushort*)(ws + o_skip1L);
  ushort* t2H  = (ushort*)(ws + o_t2H);   ushort* t2L  = (ushort*)(ws + o_t2L);
  ushort* skip2H=(ushort*)(ws + o_skip2H);ushort* skip2L=(ushort*)(ws + o_skip2L);
  ushort* t4H  = (ushort*)(ws + o_t4H);   ushort* t4L  = (ushort*)(ws + o_t4L);
  ushort* t13H = (ushort*)(ws + o_t13H);  ushort* t13L = (ushort*)(ws + o_t13L);
  ushort* t14H = (ushort*)(ws + o_t14H);  ushort* t14L = (ushort*)(ws + o_t14L);
  ushort* t15H = (ushort*)(ws + o_t15H);  ushort* t15L = (ushort*)(ws + o_t15L);
  ushort* t16H = (ushort*)(ws + o_t16H);  ushort* t16L = (ushort*)(ws + o_t16L);
  ushort* WtH  = (ushort*)(ws + o_WtH);
  ushort* cp2H = (ushort*)(ws + o_cp2H);  ushort* cp2L = (ushort*)(ws + o_cp2L);
  ushort* t162H= (ushort*)(ws + o_t162H); ushort* t162L= (ushort*)(ws + o_t162L);
  uint4* wbH = (uint4*)(ws + o_wbH);

  // layer offsets in uint4 units (order: sconv1,sconv2,bconv1..4,conv13..17)
  const size_t LOFF[12] = {0, 64512, 87552, 89344, 92800, 98560,
                           112384, 123904, 135424, 139264, 143104, 145408};

  WPtrs wp;
  wp.w[0] = (const float*)d_in[5];   wp.w[1] = (const float*)d_in[7];
  wp.w[2] = (const float*)d_in[9];   wp.w[3] = (const float*)d_in[11];
  wp.w[4] = (const float*)d_in[13];  wp.w[5] = (const float*)d_in[15];
  wp.w[6] = (const float*)d_in[17];  wp.w[7] = (const float*)d_in[19];
  wp.w[8] = (const float*)d_in[21];  wp.w[9] = (const float*)d_in[23];
  wp.w[10] = (const float*)d_in[25]; wp.w[11] = (const float*)d_in[27];
  prep_w_all<<<128, 256, 0, stream>>>(wp, wbH);

  // outputs 0,1: pass-through copies
  hipMemcpyAsync(out, x_st1, (size_t)786432 * 4, hipMemcpyDeviceToDevice, stream);
  hipMemcpyAsync(out + 786432, x_st2, (size_t)786432 * 4, hipMemcpyDeviceToDevice, stream);

  k_xnow<<<1024, 256, 0, stream>>>(x, x_st2, mask, xnowH, xnowL);
  k_tr<<<64, 256, 0, stream>>>(pm, pmH, pmL);

  // similarity branch
  conv_mfma<5, 1, 0, 8, 16, 16, 28><<<dim3(16, 6, BB), 256, 0, stream>>>(
      pmH, pmL, nullptr, nullptr, 96, 0, 12, 96, wbH + LOFF[0], b_sconv1,
      xsH, xsL, nullptr, 64, 64, 64, 64, 96, 96, 0, 4);
  conv_mfma<3, 1, 0, 16, 16, 16, 10><<<dim3(16, 6, BB), 256, 0, stream>>>(
      xsH, xsL, nullptr, nullptr, 96, 0, 12, 96, wbH + LOFF[1], b_sconv2,
      xsimH, xsimL, nullptr, 64, 64, 64, 64, 96, 96, 1, 4);
  k_mask_s<<<64, 256, 0, stream>>>(mask, ws + o_masks);
  k_mm<<<16, 256, 0, stream>>>(ws + o_masks, ws + o_mm);
  extract_patches_bf<<<4096, 256, 0, stream>>>(xsimH, xsimL, Phi, Plo);
  k_scale_bf<<<4096, 256, 0, stream>>>(Phi, Plo, ws + o_mm, ws + o_scale);
  gemm_qk_mfma<<<dim3(8, 8, BB), 512, 0, stream>>>(Phi, Plo, ws + o_scale, ws + o_S);
  softmax_rows_bf<<<dim3(1024, BB), 256, 0, stream>>>(ws + o_S, ws + o_mm, Shi, Slo);

  // main branch
  conv_mfma<5, 1, 0, 8, 16, 16, 28><<<dim3(256, 2, BB), 256, 0, stream>>>(
      xnowH, xnowL, nullptr, nullptr, 8, 0, 1, 8, wbH + LOFF[2], b_bconv1,
      skip1H, skip1L, nullptr, 256, 256, 256, 256, 24, 24, 0, 16);
  conv_mfma<3, 2, 0, 8, 8, 16, 12><<<dim3(128, 3, BB), 256, 0, stream>>>(
      skip1H, skip1L, nullptr, nullptr, 24, 0, 3, 24, wbH + LOFF[3], b_bconv2,
      t2H, t2L, nullptr, 256, 256, 128, 128, 48, 48, 0, 8);
  conv_mfma<3, 1, 0, 16, 16, 16, 10><<<dim3(64, 3, BB), 256, 0, stream>>>(
      t2H, t2L, nullptr, nullptr, 48, 0, 6, 48, wbH + LOFF[4], b_bconv3,
      skip2H, skip2L, nullptr, 128, 128, 128, 128, 48, 48, 0, 8);
  conv_mfma<3, 2, 0, 8, 8, 16, 12><<<dim3(32, 6, BB), 256, 0, stream>>>(
      skip2H, skip2L, nullptr, nullptr, 48, 0, 6, 48, wbH + LOFF[5], b_bconv4,
      t4H, t4L, nullptr, 128, 128, 64, 64, 96, 96, 0, 4);
  conv_mfma<3, 1, 1, 16, 16, 16, 10><<<dim3(64, 3, BB), 256, 0, stream>>>(
      t4H, t4L, nullptr, nullptr, 96, 0, 12, 96, wbH + LOFF[6], b_conv13,
      t13H, t13L, nullptr, 64, 64, 128, 128, 48, 48, 0, 8);
  conv_mfma<3, 1, 0, 16, 16, 16, 10><<<dim3(64, 3, BB), 256, 0, stream>>>(
      t13H, t13L, skip2H, skip2L, 48, 48, 6, 96, wbH + LOFF[7], b_conv14,
      t14H, t14L, nullptr, 128, 128, 128, 128, 48, 48, 0, 8);
  conv_mfma<3, 1, 1, 16, 16, 16, 10><<<dim3(256, 2, BB), 256, 0, stream>>>(
      t14H, t14L, nullptr, nullptr, 48, 0, 6, 48, wbH + LOFF[8], b_conv15,
      t15H, t15L, nullptr, 128, 128, 256, 256, 24, 24, 0, 16);
  conv_mfma<3, 1, 0, 16, 16, 16, 10><<<dim3(256, 2, BB), 256, 0, stream>>>(
      t15H, t15L, skip1H, skip1L, 24, 24, 3, 48, wbH + LOFF[9], b_conv16,
      t16H, t16L, nullptr, 256, 256, 256, 256, 24, 24, 0, 16);

  // cp2: per-batch prepW + MFMA GEMM + fold
  for (int b = 0; b < BB; b++) {
    k_prepW<<<512, 256, 0, stream>>>(t16H, WtH, b);
    gemm_cp2_mfma<<<dim3(48, 8), 512, 0, stream>>>(Shi, Slo, WtH, ws + o_contrib, b);
    k_fold<<<256, 256, 0, stream>>>(ws + o_contrib, t16H, t16L, mask, cp2H, cp2L, b);
  }

  // tail convs (cinp=24 -> CC=8 variant)
  conv_mfma<3, 1, 0, 8, 16, 16, 12><<<dim3(256, 2, BB), 256, 0, stream>>>(
      cp2H, cp2L, nullptr, nullptr, 24, 0, 3, 24, wbH + LOFF[10], b_conv16_2,
      t162H, t162L, nullptr, 256, 256, 256, 256, 24, 24, 0, 16);
  conv_mfma<3, 1, 0, 8, 16, 16, 12><<<dim3(256, 1, BB), 256, 0, stream>>>(
      t162H, t162L, nullptr, nullptr, 24, 0, 3, 24, wbH + LOFF[11], b_conv17,
      nullptr, nullptr, out + 2 * 786432, 256, 256, 256, 256, 3, 24, 2, 16);
}